// Round 1
// baseline (666.160 us; speedup 1.0000x reference)
//
#include <hip/hip_runtime.h>
#include <math.h>

#define NFEAT  128
#define HC     256     // HEADS*NHID
#define HEADS  8
#define NHID   32
#define NCLASS 40

// ---------------- CSR build (dst-sorted, shared by both layers) ----------------

__global__ void k_deg_init(int* deg, int n) {
    int i = blockIdx.x * 256 + threadIdx.x;
    if (i < n) deg[i] = 1;              // self-loop contributes 1 to every node
}

__global__ void k_hist(const int* __restrict__ dst, int E, int* deg) {
    int i = blockIdx.x * 256 + threadIdx.x;
    if (i < E) atomicAdd(&deg[dst[i]], 1);
}

// single-block exclusive scan over deg[0..n) -> ptr[0..n], cur = copy of ptr
__global__ void k_scan(const int* __restrict__ deg, int n, int* ptr, int* cur) {
    __shared__ int lds[1024];
    int t = threadIdx.x;
    const int CH = (n + 1023) / 1024;
    int base = t * CH;
    int p = 0;
    for (int j = 0; j < CH; ++j) {
        int i = base + j;
        if (i < n) p += deg[i];
    }
    lds[t] = p;
    __syncthreads();
    for (int off = 1; off < 1024; off <<= 1) {
        int v = (t >= off) ? lds[t - off] : 0;
        __syncthreads();
        lds[t] += v;
        __syncthreads();
    }
    int run = lds[t] - p;               // exclusive prefix for this chunk
    for (int j = 0; j < CH; ++j) {
        int i = base + j;
        if (i < n) {
            ptr[i] = run;
            cur[i] = run;
            run += deg[i];
        }
    }
    if (t == 0) ptr[n] = lds[1023];
}

__global__ void k_scatter(const int* __restrict__ srcE, const int* __restrict__ dstE,
                          int E, int n, int* cur, int* __restrict__ srcs) {
    int i = blockIdx.x * 256 + threadIdx.x;
    int tot = E + n;
    if (i >= tot) return;
    int s, d;
    if (i < E) { s = srcE[i]; d = dstE[i]; }
    else       { s = d = i - E; }       // self-loop
    int pos = atomicAdd(&cur[d], 1);
    srcs[pos] = s;
}

// ---------------- GEMM1: h1 = x @ W1  [N,128]x[128,256], fused a1_src/a1_dst ----------------
// block = 512 threads (8 waves), 64 nodes/block (8 nodes/wave), K tiled by 32.
// lane l owns output cols 4l..4l+3 (head = l/8).
__global__ __launch_bounds__(512)
void k_gemm1(const float* __restrict__ x, const float* __restrict__ W1,
             const float* __restrict__ attS, const float* __restrict__ attD,
             int n, float* __restrict__ h1,
             float* __restrict__ a1s, float* __restrict__ a1d) {
    __shared__ float Ws[32 * 256];      // 32 KB
    __shared__ float Xs[64 * 32];       // 8 KB
    int t = threadIdx.x;
    int lane = t & 63;
    int w = t >> 6;                     // wave 0..7
    int n0 = blockIdx.x * 64;

    float4 acc[8];
#pragma unroll
    for (int i = 0; i < 8; ++i) acc[i] = make_float4(0.f, 0.f, 0.f, 0.f);

    for (int kt = 0; kt < 4; ++kt) {
        __syncthreads();
        // stage W rows [kt*32, kt*32+32) x 256 cols = 8192 floats (2048 float4)
        const float4* Wg = (const float4*)(W1 + (size_t)kt * 32 * 256);
        float4* Ws4 = (float4*)Ws;
#pragma unroll
        for (int j = 0; j < 4; ++j) Ws4[t + j * 512] = Wg[t + j * 512];
        // stage x tile: 64 nodes x 32 k = 512 float4, 1 per thread
        {
            int node = t >> 3;
            int kk4 = (t & 7) * 4;
            int gn = n0 + node;
            float4 v = make_float4(0.f, 0.f, 0.f, 0.f);
            if (gn < n) v = *(const float4*)(x + (size_t)gn * NFEAT + kt * 32 + kk4);
            *(float4*)(Xs + node * 32 + kk4) = v;
        }
        __syncthreads();
#pragma unroll
        for (int kk = 0; kk < 32; ++kk) {
            float4 wr = *(const float4*)(Ws + kk * 256 + lane * 4);
#pragma unroll
            for (int nn = 0; nn < 8; ++nn) {
                float xv = Xs[(w * 8 + nn) * 32 + kk];
                acc[nn].x += xv * wr.x;
                acc[nn].y += xv * wr.y;
                acc[nn].z += xv * wr.z;
                acc[nn].w += xv * wr.w;
            }
        }
    }

    // epilogue: store h1, fused attention dots (8-lane tree per head)
    float4 s4 = *(const float4*)(attS + lane * 4);
    float4 d4 = *(const float4*)(attD + lane * 4);
#pragma unroll
    for (int nn = 0; nn < 8; ++nn) {
        int gn = n0 + w * 8 + nn;
        if (gn >= n) break;             // uniform across the wave
        *(float4*)(h1 + (size_t)gn * HC + lane * 4) = acc[nn];
        float as = acc[nn].x * s4.x + acc[nn].y * s4.y + acc[nn].z * s4.z + acc[nn].w * s4.w;
        float ad = acc[nn].x * d4.x + acc[nn].y * d4.y + acc[nn].z * d4.z + acc[nn].w * d4.w;
        as += __shfl_xor(as, 1, 64); as += __shfl_xor(as, 2, 64); as += __shfl_xor(as, 4, 64);
        ad += __shfl_xor(ad, 1, 64); ad += __shfl_xor(ad, 2, 64); ad += __shfl_xor(ad, 4, 64);
        if ((lane & 7) == 0) {
            a1s[gn * HEADS + (lane >> 3)] = as;
            a1d[gn * HEADS + (lane >> 3)] = ad;
        }
    }
}

// ---------------- Layer-1 aggregation: one wave per dst node, online softmax ----------------
__global__ __launch_bounds__(256)
void k_agg1(const float* __restrict__ h1, const float* __restrict__ a1s,
            const float* __restrict__ a1d, const float* __restrict__ b1,
            const int* __restrict__ ptr, const int* __restrict__ srcs,
            int n, float* __restrict__ hg) {
    int wid = blockIdx.x * 4 + (threadIdx.x >> 6);
    if (wid >= n) return;
    int lane = threadIdx.x & 63;
    int h = lane >> 3;                  // lane owns cols 4l..4l+3 -> head l/8
    float adn = a1d[wid * HEADS + h];
    int beg = ptr[wid], end = ptr[wid + 1];
    float m = -INFINITY, s = 0.f;
    float4 acc = make_float4(0.f, 0.f, 0.f, 0.f);
    for (int i = beg; i < end; ++i) {
        int sn = srcs[i];
        float a = a1s[sn * HEADS + h] + adn;
        float e = (a > 0.f) ? a : 0.2f * a;           // leaky_relu 0.2
        float mn = fmaxf(m, e);
        float corr = __expf(m - mn);                  // exp(-inf)=0 on first edge
        float p = __expf(e - mn);
        float4 hv = *(const float4*)(h1 + (size_t)sn * HC + lane * 4);
        s = s * corr + p;
        acc.x = acc.x * corr + p * hv.x;
        acc.y = acc.y * corr + p * hv.y;
        acc.z = acc.z * corr + p * hv.z;
        acc.w = acc.w * corr + p * hv.w;
        m = mn;
    }
    float inv = 1.f / (s + 1e-16f);
    float4 bv = *(const float4*)(b1 + lane * 4);
    float4 o;
    o.x = acc.x * inv + bv.x;
    o.y = acc.y * inv + bv.y;
    o.z = acc.z * inv + bv.z;
    o.w = acc.w * inv + bv.w;
    // ELU
    o.x = (o.x > 0.f) ? o.x : (__expf(o.x) - 1.f);
    o.y = (o.y > 0.f) ? o.y : (__expf(o.y) - 1.f);
    o.z = (o.z > 0.f) ? o.z : (__expf(o.z) - 1.f);
    o.w = (o.w > 0.f) ? o.w : (__expf(o.w) - 1.f);
    *(float4*)(hg + (size_t)wid * HC + lane * 4) = o;
}

// ---------------- GEMM2: h2 = hg @ W2  [N,256]x[256,40], fused a2_src/a2_dst ----------------
// block = 256 threads (4 waves), 32 nodes/block (8/wave), K tiled by 64, cols padded to 64.
__global__ __launch_bounds__(256)
void k_gemm2(const float* __restrict__ hg, const float* __restrict__ W2,
             const float* __restrict__ a2sw, const float* __restrict__ a2dw,
             int n, float* __restrict__ h2,
             float* __restrict__ a2s, float* __restrict__ a2d) {
    __shared__ float Ws[64 * 64];       // 16 KB (cols padded 40->64 with zeros)
    __shared__ float Xs[32 * 64];       // 8 KB
    int t = threadIdx.x;
    int lane = t & 63;
    int w = t >> 6;                     // 0..3
    int n0 = blockIdx.x * 32;
    float acc[8];
#pragma unroll
    for (int i = 0; i < 8; ++i) acc[i] = 0.f;

    for (int kt = 0; kt < 4; ++kt) {
        __syncthreads();
#pragma unroll
        for (int j = 0; j < 16; ++j) {
            int idx = t + j * 256;
            int r = idx >> 6, c = idx & 63;
            Ws[idx] = (c < NCLASS) ? W2[(size_t)(kt * 64 + r) * NCLASS + c] : 0.f;
        }
#pragma unroll
        for (int j = 0; j < 2; ++j) {
            int f4 = t + j * 256;
            int node = f4 >> 4;
            int kk4 = (f4 & 15) * 4;
            int gn = n0 + node;
            float4 v = make_float4(0.f, 0.f, 0.f, 0.f);
            if (gn < n) v = *(const float4*)(hg + (size_t)gn * HC + kt * 64 + kk4);
            *(float4*)(Xs + node * 64 + kk4) = v;
        }
        __syncthreads();
#pragma unroll
        for (int kk = 0; kk < 64; ++kk) {
            float wv = Ws[kk * 64 + lane];
#pragma unroll
            for (int nn = 0; nn < 8; ++nn) {
                acc[nn] += Xs[(w * 8 + nn) * 64 + kk] * wv;
            }
        }
    }

    float aws = (lane < NCLASS) ? a2sw[lane] : 0.f;
    float awd = (lane < NCLASS) ? a2dw[lane] : 0.f;
#pragma unroll
    for (int nn = 0; nn < 8; ++nn) {
        int gn = n0 + w * 8 + nn;
        if (gn >= n) break;
        float v = acc[nn];
        if (lane < NCLASS) h2[(size_t)gn * NCLASS + lane] = v;
        float vs = v * aws, vd = v * awd;
#pragma unroll
        for (int msk = 1; msk < 64; msk <<= 1) {
            vs += __shfl_xor(vs, msk, 64);
            vd += __shfl_xor(vd, msk, 64);
        }
        if (lane == 0) { a2s[gn] = vs; a2d[gn] = vd; }
    }
}

// ---------------- Layer-2 aggregation + bias + log_softmax: one wave per node ----------------
__global__ __launch_bounds__(256)
void k_agg2(const float* __restrict__ h2, const float* __restrict__ a2s,
            const float* __restrict__ a2d, const float* __restrict__ b2,
            const int* __restrict__ ptr, const int* __restrict__ srcs,
            int n, float* __restrict__ out) {
    int wid = blockIdx.x * 4 + (threadIdx.x >> 6);
    if (wid >= n) return;
    int lane = threadIdx.x & 63;
    bool live = lane < NCLASS;
    float adn = a2d[wid];
    int beg = ptr[wid], end = ptr[wid + 1];
    float m = -INFINITY, s = 0.f, acc = 0.f;
    for (int i = beg; i < end; ++i) {
        int sn = srcs[i];
        float a = a2s[sn] + adn;
        float e = (a > 0.f) ? a : 0.2f * a;
        float mn = fmaxf(m, e);
        float corr = __expf(m - mn);
        float p = __expf(e - mn);
        float hv = live ? h2[(size_t)sn * NCLASS + lane] : 0.f;
        s = s * corr + p;
        acc = acc * corr + p * hv;
        m = mn;
    }
    float val = acc / (s + 1e-16f) + (live ? b2[lane] : 0.f);
    // log_softmax across the 40 live lanes
    float vmax = live ? val : -INFINITY;
#pragma unroll
    for (int msk = 1; msk < 64; msk <<= 1) vmax = fmaxf(vmax, __shfl_xor(vmax, msk, 64));
    float ex = live ? __expf(val - vmax) : 0.f;
#pragma unroll
    for (int msk = 1; msk < 64; msk <<= 1) ex += __shfl_xor(ex, msk, 64);
    float res = val - vmax - __logf(ex);
    if (live) out[(size_t)wid * NCLASS + lane] = res;
}

// ---------------- launch ----------------
extern "C" void kernel_launch(void* const* d_in, const int* in_sizes, int n_in,
                              void* d_out, int out_size, void* d_ws, size_t ws_size,
                              hipStream_t stream) {
    const float* x    = (const float*)d_in[0];
    const int*   ei   = (const int*)  d_in[1];
    const float* W1   = (const float*)d_in[2];
    const float* attS = (const float*)d_in[3];
    const float* attD = (const float*)d_in[4];
    const float* b1   = (const float*)d_in[5];
    const float* W2   = (const float*)d_in[6];
    const float* a2sw = (const float*)d_in[7];
    const float* a2dw = (const float*)d_in[8];
    const float* b2   = (const float*)d_in[9];

    int n = in_sizes[0] / NFEAT;
    int E = in_sizes[1] / 2;
    const int* srcE = ei;
    const int* dstE = ei + E;

    char* p = (char*)d_ws;
    auto alloc = [&](size_t bytes) {
        char* r = p;
        p += (bytes + 255) & ~(size_t)255;
        return r;
    };
    float* h1  = (float*)alloc((size_t)n * HC * 4);
    float* hg  = (float*)alloc((size_t)n * HC * 4);
    float* h2  = (float*)alloc((size_t)n * NCLASS * 4);
    float* a1s = (float*)alloc((size_t)n * HEADS * 4);
    float* a1d = (float*)alloc((size_t)n * HEADS * 4);
    float* a2s = (float*)alloc((size_t)n * 4);
    float* a2d = (float*)alloc((size_t)n * 4);
    int* deg  = (int*)alloc((size_t)n * 4);
    int* ptr  = (int*)alloc((size_t)(n + 1) * 4);
    int* cur  = (int*)alloc((size_t)n * 4);
    int* srcs = (int*)alloc((size_t)(E + n) * 4);

    k_deg_init<<<(n + 255) / 256, 256, 0, stream>>>(deg, n);
    k_hist<<<(E + 255) / 256, 256, 0, stream>>>(dstE, E, deg);
    k_scan<<<1, 1024, 0, stream>>>(deg, n, ptr, cur);
    k_scatter<<<(E + n + 255) / 256, 256, 0, stream>>>(srcE, dstE, E, n, cur, srcs);

    k_gemm1<<<(n + 63) / 64, 512, 0, stream>>>(x, W1, attS, attD, n, h1, a1s, a1d);
    k_agg1<<<(n + 3) / 4, 256, 0, stream>>>(h1, a1s, a1d, b1, ptr, srcs, n, hg);
    k_gemm2<<<(n + 31) / 32, 256, 0, stream>>>(hg, W2, a2sw, a2dw, n, h2, a2s, a2d);
    k_agg2<<<(n + 3) / 4, 256, 0, stream>>>(h2, a2s, a2d, b2, ptr, srcs, n, (float*)d_out);
}

// Round 2
// 469.603 us; speedup vs baseline: 1.4186x; 1.4186x over previous
//
#include <hip/hip_runtime.h>
#include <math.h>

#define NFEAT  128
#define HC     256     // HEADS*NHID
#define HEADS  8
#define NHID   32
#define NCLASS 40

// ---------------- CSR build (dst-sorted, shared by both layers) ----------------

__global__ void k_deg_init(int* deg, int n) {
    int i = blockIdx.x * 256 + threadIdx.x;
    if (i < n) deg[i] = 1;              // self-loop contributes 1 to every node
}

__global__ void k_hist(const int* __restrict__ dst, int E, int* deg) {
    int i = blockIdx.x * 256 + threadIdx.x;
    if (i < E) atomicAdd(&deg[dst[i]], 1);
}

// multi-block scan: per-block sums
__global__ void k_blocksum(const int* __restrict__ deg, int n, int* bsum) {
    __shared__ int lds[256];
    int b = blockIdx.x, t = threadIdx.x;
    int i = b * 256 + t;
    lds[t] = (i < n) ? deg[i] : 0;
    __syncthreads();
    for (int off = 128; off >= 1; off >>= 1) {
        if (t < off) lds[t] += lds[t + off];
        __syncthreads();
    }
    if (t == 0) bsum[b] = lds[0];
}

// exclusive scan of block sums (nb <= 1024)
__global__ void k_bscan(int* bsum, int nb) {
    __shared__ int lds[1024];
    int t = threadIdx.x;
    int v = (t < nb) ? bsum[t] : 0;
    lds[t] = v;
    __syncthreads();
    for (int off = 1; off < 1024; off <<= 1) {
        int u = (t >= off) ? lds[t - off] : 0;
        __syncthreads();
        lds[t] += u;
        __syncthreads();
    }
    if (t < nb) bsum[t] = lds[t] - v;   // exclusive
}

__global__ void k_mkptr(const int* __restrict__ deg, const int* __restrict__ bsum,
                        int n, int* ptr, int* cur) {
    __shared__ int lds[256];
    int b = blockIdx.x, t = threadIdx.x;
    int i = b * 256 + t;
    int v = (i < n) ? deg[i] : 0;
    lds[t] = v;
    __syncthreads();
    for (int off = 1; off < 256; off <<= 1) {
        int u = (t >= off) ? lds[t - off] : 0;
        __syncthreads();
        lds[t] += u;
        __syncthreads();
    }
    int excl = lds[t] - v + bsum[b];
    if (i < n) {
        ptr[i] = excl;
        cur[i] = excl;
        if (i == n - 1) ptr[n] = excl + v;
    }
}

__global__ void k_scatter(const int* __restrict__ srcE, const int* __restrict__ dstE,
                          int E, int n, int* cur, int* __restrict__ srcs) {
    int i = blockIdx.x * 256 + threadIdx.x;
    int tot = E + n;
    if (i >= tot) return;
    int s, d;
    if (i < E) { s = srcE[i]; d = dstE[i]; }
    else       { s = d = i - E; }       // self-loop
    int pos = atomicAdd(&cur[d], 1);
    srcs[pos] = s;
}

// ---------------- GEMM1: h1 = x @ W1  [N,128]x[128,256] ----------------
// lane = node (64 nodes/block), wave w owns cols [64w,64w+64). W1 rows are
// wave-uniform -> scalar loads (SGPR operand FMAs). x tile staged transposed-
// free in LDS row-major with pad 132 (stride-128 bank alias broken).
// Attention dots (heads 2w,2w+1) computed in-register, no shuffles.
__global__ __launch_bounds__(256)
void k_gemm1(const float* __restrict__ x, const float* __restrict__ W1,
             const float* __restrict__ attS, const float* __restrict__ attD,
             int n, float* __restrict__ h1,
             float* __restrict__ a1s, float* __restrict__ a1d) {
    __shared__ float Xs[64 * 132];      // 33 KB
    int t = threadIdx.x;
    int lane = t & 63;
    int n0 = blockIdx.x * 64;

    // stage: 64 nodes x 128 feats = 2048 float4, 8 per thread, coalesced
#pragma unroll
    for (int j = 0; j < 8; ++j) {
        int f4 = t + j * 256;
        int node = f4 >> 5;             // 32 float4 per node row
        int k4 = (f4 & 31) * 4;
        int gn = n0 + node;
        float4 v = make_float4(0.f, 0.f, 0.f, 0.f);
        if (gn < n) v = *(const float4*)(x + (size_t)gn * NFEAT + k4);
        *(float4*)(Xs + node * 132 + k4) = v;
    }
    __syncthreads();

    int wu = __builtin_amdgcn_readfirstlane(t >> 6);   // force SGPR -> uniform W path
    const float* Wc = W1 + wu * 64;

    float acc[64];
#pragma unroll
    for (int c = 0; c < 64; ++c) acc[c] = 0.f;

#pragma unroll 2
    for (int k4 = 0; k4 < 32; ++k4) {
        float4 xv = *(const float4*)(Xs + lane * 132 + k4 * 4);
#pragma unroll
        for (int i = 0; i < 4; ++i) {
            float xi = (i == 0) ? xv.x : (i == 1) ? xv.y : (i == 2) ? xv.z : xv.w;
            const float* Wr = Wc + (size_t)(k4 * 4 + i) * HC;
#pragma unroll
            for (int c4 = 0; c4 < 16; ++c4) {
                float4 wv = *(const float4*)(Wr + c4 * 4);   // uniform -> s_load
                acc[c4 * 4 + 0] += xi * wv.x;
                acc[c4 * 4 + 1] += xi * wv.y;
                acc[c4 * 4 + 2] += xi * wv.z;
                acc[c4 * 4 + 3] += xi * wv.w;
            }
        }
    }

    int gn = n0 + lane;
    if (gn < n) {
        float* hp = h1 + (size_t)gn * HC + wu * 64;
#pragma unroll
        for (int c4 = 0; c4 < 16; ++c4)
            *(float4*)(hp + c4 * 4) = make_float4(acc[c4 * 4], acc[c4 * 4 + 1],
                                                  acc[c4 * 4 + 2], acc[c4 * 4 + 3]);
        // heads 2*wu (cols 0..31 of this slice) and 2*wu+1 (cols 32..63)
        float as0 = 0.f, ad0 = 0.f, as1 = 0.f, ad1 = 0.f;
#pragma unroll
        for (int c = 0; c < 32; ++c) {
            as0 += acc[c] * attS[wu * 64 + c];
            ad0 += acc[c] * attD[wu * 64 + c];
            as1 += acc[32 + c] * attS[wu * 64 + 32 + c];
            ad1 += acc[32 + c] * attD[wu * 64 + 32 + c];
        }
        a1s[(size_t)gn * HEADS + wu * 2]     = as0;
        a1s[(size_t)gn * HEADS + wu * 2 + 1] = as1;
        a1d[(size_t)gn * HEADS + wu * 2]     = ad0;
        a1d[(size_t)gn * HEADS + wu * 2 + 1] = ad1;
    }
}

// ---------------- Layer-1 aggregation: one wave per dst node, online softmax ----------------
// Edge loop unrolled x4: 4 independent 16B/lane gathers in flight (MLP).
__global__ __launch_bounds__(256)
void k_agg1(const float* __restrict__ h1, const float* __restrict__ a1s,
            const float* __restrict__ a1d, const float* __restrict__ b1,
            const int* __restrict__ ptr, const int* __restrict__ srcs,
            int n, float* __restrict__ hg) {
    int wid = blockIdx.x * 4 + (threadIdx.x >> 6);
    if (wid >= n) return;
    int lane = threadIdx.x & 63;
    int h = lane >> 3;
    float adn = a1d[wid * HEADS + h];
    int beg = ptr[wid], end = ptr[wid + 1];
    float m = -INFINITY, s = 0.f;
    float4 acc = make_float4(0.f, 0.f, 0.f, 0.f);
    int i = beg;
    for (; i + 4 <= end; i += 4) {
        int sn0 = srcs[i], sn1 = srcs[i + 1], sn2 = srcs[i + 2], sn3 = srcs[i + 3];
        float a0 = a1s[sn0 * HEADS + h] + adn;
        float a1 = a1s[sn1 * HEADS + h] + adn;
        float a2 = a1s[sn2 * HEADS + h] + adn;
        float a3 = a1s[sn3 * HEADS + h] + adn;
        float4 hv0 = *(const float4*)(h1 + (size_t)sn0 * HC + lane * 4);
        float4 hv1 = *(const float4*)(h1 + (size_t)sn1 * HC + lane * 4);
        float4 hv2 = *(const float4*)(h1 + (size_t)sn2 * HC + lane * 4);
        float4 hv3 = *(const float4*)(h1 + (size_t)sn3 * HC + lane * 4);
        float e0 = (a0 > 0.f) ? a0 : 0.2f * a0;
        float e1 = (a1 > 0.f) ? a1 : 0.2f * a1;
        float e2 = (a2 > 0.f) ? a2 : 0.2f * a2;
        float e3 = (a3 > 0.f) ? a3 : 0.2f * a3;
        float mn = fmaxf(m, fmaxf(fmaxf(e0, e1), fmaxf(e2, e3)));
        float corr = __expf(m - mn);
        float p0 = __expf(e0 - mn), p1 = __expf(e1 - mn);
        float p2 = __expf(e2 - mn), p3 = __expf(e3 - mn);
        s = s * corr + ((p0 + p1) + (p2 + p3));
        acc.x = acc.x * corr + p0 * hv0.x + p1 * hv1.x + p2 * hv2.x + p3 * hv3.x;
        acc.y = acc.y * corr + p0 * hv0.y + p1 * hv1.y + p2 * hv2.y + p3 * hv3.y;
        acc.z = acc.z * corr + p0 * hv0.z + p1 * hv1.z + p2 * hv2.z + p3 * hv3.z;
        acc.w = acc.w * corr + p0 * hv0.w + p1 * hv1.w + p2 * hv2.w + p3 * hv3.w;
        m = mn;
    }
    for (; i < end; ++i) {
        int sn = srcs[i];
        float a = a1s[sn * HEADS + h] + adn;
        float e = (a > 0.f) ? a : 0.2f * a;
        float mn = fmaxf(m, e);
        float corr = __expf(m - mn);
        float p = __expf(e - mn);
        float4 hv = *(const float4*)(h1 + (size_t)sn * HC + lane * 4);
        s = s * corr + p;
        acc.x = acc.x * corr + p * hv.x;
        acc.y = acc.y * corr + p * hv.y;
        acc.z = acc.z * corr + p * hv.z;
        acc.w = acc.w * corr + p * hv.w;
        m = mn;
    }
    float inv = 1.f / (s + 1e-16f);
    float4 bv = *(const float4*)(b1 + lane * 4);
    float4 o;
    o.x = acc.x * inv + bv.x;
    o.y = acc.y * inv + bv.y;
    o.z = acc.z * inv + bv.z;
    o.w = acc.w * inv + bv.w;
    o.x = (o.x > 0.f) ? o.x : (__expf(o.x) - 1.f);
    o.y = (o.y > 0.f) ? o.y : (__expf(o.y) - 1.f);
    o.z = (o.z > 0.f) ? o.z : (__expf(o.z) - 1.f);
    o.w = (o.w > 0.f) ? o.w : (__expf(o.w) - 1.f);
    *(float4*)(hg + (size_t)wid * HC + lane * 4) = o;
}

// ---------------- GEMM2: h2 = hg @ W2  [N,256]x[256,40] ----------------
// lane = node, 4 waves x 64 nodes = 256 nodes/block. W2 rows wave-uniform ->
// scalar loads. X read direct from global (per-wave footprint 64KB, L1/L2-hot).
// acc[40]/lane; a2 dots in-register; no LDS.
__global__ __launch_bounds__(256)
void k_gemm2(const float* __restrict__ hg, const float* __restrict__ W2,
             const float* __restrict__ a2sw, const float* __restrict__ a2dw,
             int n, float* __restrict__ h2,
             float* __restrict__ a2s, float* __restrict__ a2d) {
    int t = threadIdx.x;
    int lane = t & 63;
    int w = t >> 6;
    int gn = blockIdx.x * 256 + w * 64 + lane;
    bool live = gn < n;
    const float* xr = hg + (live ? (size_t)gn * HC : 0);

    float acc[NCLASS];
#pragma unroll
    for (int c = 0; c < NCLASS; ++c) acc[c] = 0.f;

#pragma unroll 2
    for (int k4 = 0; k4 < 64; ++k4) {
        float4 xv = *(const float4*)(xr + k4 * 4);
#pragma unroll
        for (int i = 0; i < 4; ++i) {
            float xi = (i == 0) ? xv.x : (i == 1) ? xv.y : (i == 2) ? xv.z : xv.w;
            const float* Wr = W2 + (size_t)(k4 * 4 + i) * NCLASS;
#pragma unroll
            for (int c4 = 0; c4 < 10; ++c4) {
                float4 wv = *(const float4*)(Wr + c4 * 4);   // uniform -> s_load
                acc[c4 * 4 + 0] += xi * wv.x;
                acc[c4 * 4 + 1] += xi * wv.y;
                acc[c4 * 4 + 2] += xi * wv.z;
                acc[c4 * 4 + 3] += xi * wv.w;
            }
        }
    }

    if (live) {
        float as = 0.f, ad = 0.f;
#pragma unroll
        for (int c4 = 0; c4 < 10; ++c4) {
            float4 sv = *(const float4*)(a2sw + c4 * 4);
            float4 dv = *(const float4*)(a2dw + c4 * 4);
            as += acc[c4 * 4] * sv.x + acc[c4 * 4 + 1] * sv.y
                + acc[c4 * 4 + 2] * sv.z + acc[c4 * 4 + 3] * sv.w;
            ad += acc[c4 * 4] * dv.x + acc[c4 * 4 + 1] * dv.y
                + acc[c4 * 4 + 2] * dv.z + acc[c4 * 4 + 3] * dv.w;
            *(float4*)(h2 + (size_t)gn * NCLASS + c4 * 4) =
                make_float4(acc[c4 * 4], acc[c4 * 4 + 1], acc[c4 * 4 + 2], acc[c4 * 4 + 3]);
        }
        a2s[gn] = as;
        a2d[gn] = ad;
    }
}

// ---------------- Layer-2 aggregation + bias + log_softmax ----------------
__global__ __launch_bounds__(256)
void k_agg2(const float* __restrict__ h2, const float* __restrict__ a2s,
            const float* __restrict__ a2d, const float* __restrict__ b2,
            const int* __restrict__ ptr, const int* __restrict__ srcs,
            int n, float* __restrict__ out) {
    int wid = blockIdx.x * 4 + (threadIdx.x >> 6);
    if (wid >= n) return;
    int lane = threadIdx.x & 63;
    bool live = lane < NCLASS;
    int col = live ? lane : 0;
    float adn = a2d[wid];
    int beg = ptr[wid], end = ptr[wid + 1];
    float m = -INFINITY, s = 0.f, acc = 0.f;
    int i = beg;
    for (; i + 4 <= end; i += 4) {
        int sn0 = srcs[i], sn1 = srcs[i + 1], sn2 = srcs[i + 2], sn3 = srcs[i + 3];
        float a0 = a2s[sn0] + adn;
        float a1 = a2s[sn1] + adn;
        float a2 = a2s[sn2] + adn;
        float a3 = a2s[sn3] + adn;
        float hv0 = h2[(size_t)sn0 * NCLASS + col];
        float hv1 = h2[(size_t)sn1 * NCLASS + col];
        float hv2 = h2[(size_t)sn2 * NCLASS + col];
        float hv3 = h2[(size_t)sn3 * NCLASS + col];
        float e0 = (a0 > 0.f) ? a0 : 0.2f * a0;
        float e1 = (a1 > 0.f) ? a1 : 0.2f * a1;
        float e2 = (a2 > 0.f) ? a2 : 0.2f * a2;
        float e3 = (a3 > 0.f) ? a3 : 0.2f * a3;
        float mn = fmaxf(m, fmaxf(fmaxf(e0, e1), fmaxf(e2, e3)));
        float corr = __expf(m - mn);
        float p0 = __expf(e0 - mn), p1 = __expf(e1 - mn);
        float p2 = __expf(e2 - mn), p3 = __expf(e3 - mn);
        s = s * corr + ((p0 + p1) + (p2 + p3));
        acc = acc * corr + p0 * hv0 + p1 * hv1 + p2 * hv2 + p3 * hv3;
        m = mn;
    }
    for (; i < end; ++i) {
        int sn = srcs[i];
        float a = a2s[sn] + adn;
        float e = (a > 0.f) ? a : 0.2f * a;
        float mn = fmaxf(m, e);
        float corr = __expf(m - mn);
        float p = __expf(e - mn);
        float hv = h2[(size_t)sn * NCLASS + col];
        s = s * corr + p;
        acc = acc * corr + p * hv;
        m = mn;
    }
    float val = acc / (s + 1e-16f) + (live ? b2[lane] : 0.f);
    float vmax = live ? val : -INFINITY;
#pragma unroll
    for (int msk = 1; msk < 64; msk <<= 1) vmax = fmaxf(vmax, __shfl_xor(vmax, msk, 64));
    float ex = live ? __expf(val - vmax) : 0.f;
#pragma unroll
    for (int msk = 1; msk < 64; msk <<= 1) ex += __shfl_xor(ex, msk, 64);
    float res = val - vmax - __logf(ex);
    if (live) out[(size_t)wid * NCLASS + lane] = res;
}

// ---------------- launch ----------------
extern "C" void kernel_launch(void* const* d_in, const int* in_sizes, int n_in,
                              void* d_out, int out_size, void* d_ws, size_t ws_size,
                              hipStream_t stream) {
    const float* x    = (const float*)d_in[0];
    const int*   ei   = (const int*)  d_in[1];
    const float* W1   = (const float*)d_in[2];
    const float* attS = (const float*)d_in[3];
    const float* attD = (const float*)d_in[4];
    const float* b1   = (const float*)d_in[5];
    const float* W2   = (const float*)d_in[6];
    const float* a2sw = (const float*)d_in[7];
    const float* a2dw = (const float*)d_in[8];
    const float* b2   = (const float*)d_in[9];

    int n = in_sizes[0] / NFEAT;
    int E = in_sizes[1] / 2;
    const int* srcE = ei;
    const int* dstE = ei + E;
    int nb = (n + 255) / 256;

    char* p = (char*)d_ws;
    auto alloc = [&](size_t bytes) {
        char* r = p;
        p += (bytes + 255) & ~(size_t)255;
        return r;
    };
    float* h1  = (float*)alloc((size_t)n * HC * 4);
    float* hg  = (float*)alloc((size_t)n * HC * 4);
    float* h2  = (float*)alloc((size_t)n * NCLASS * 4);
    float* a1s = (float*)alloc((size_t)n * HEADS * 4);
    float* a1d = (float*)alloc((size_t)n * HEADS * 4);
    float* a2s = (float*)alloc((size_t)n * 4);
    float* a2d = (float*)alloc((size_t)n * 4);
    int* deg  = (int*)alloc((size_t)n * 4);
    int* bsum = (int*)alloc((size_t)nb * 4);
    int* ptr  = (int*)alloc((size_t)(n + 1) * 4);
    int* cur  = (int*)alloc((size_t)n * 4);
    int* srcs = (int*)alloc((size_t)(E + n) * 4);

    k_deg_init<<<(n + 255) / 256, 256, 0, stream>>>(deg, n);
    k_hist<<<(E + 255) / 256, 256, 0, stream>>>(dstE, E, deg);
    k_blocksum<<<nb, 256, 0, stream>>>(deg, n, bsum);
    k_bscan<<<1, 1024, 0, stream>>>(bsum, nb);
    k_mkptr<<<nb, 256, 0, stream>>>(deg, bsum, n, ptr, cur);
    k_scatter<<<(E + n + 255) / 256, 256, 0, stream>>>(srcE, dstE, E, n, cur, srcs);

    k_gemm1<<<(n + 63) / 64, 256, 0, stream>>>(x, W1, attS, attD, n, h1, a1s, a1d);
    k_agg1<<<(n + 3) / 4, 256, 0, stream>>>(h1, a1s, a1d, b1, ptr, srcs, n, hg);
    k_gemm2<<<(n + 255) / 256, 256, 0, stream>>>(hg, W2, a2sw, a2dw, n, h2, a2s, a2d);
    k_agg2<<<(n + 3) / 4, 256, 0, stream>>>(h2, a2s, a2d, b2, ptr, srcs, n, (float*)d_out);
}

// Round 3
// 462.406 us; speedup vs baseline: 1.4406x; 1.0156x over previous
//
#include <hip/hip_runtime.h>
#include <math.h>

#define NFEAT  128
#define HC     256     // HEADS*NHID
#define HEADS  8
#define NHID   32
#define NCLASS 40

typedef unsigned int  uint;
typedef unsigned short ushort;

// bf16 helpers (RNE pack, cheap unpack)
__device__ __forceinline__ uint f2bf1(float f) {
    uint b = __float_as_uint(f);
    b += 0x7FFFu + ((b >> 16) & 1u);
    return b >> 16;
}
__device__ __forceinline__ uint packbf(float lo, float hi) {
    return f2bf1(lo) | (f2bf1(hi) << 16);
}
__device__ __forceinline__ float bflo(uint u) { return __uint_as_float(u << 16); }
__device__ __forceinline__ float bfhi(uint u) { return __uint_as_float(u & 0xFFFF0000u); }

// ---------------- CSR build (dst-sorted, shared by both layers) ----------------

__global__ void k_deg_init(int* deg, int n) {
    int i = blockIdx.x * 256 + threadIdx.x;
    if (i < n) deg[i] = 1;              // self-loop contributes 1 to every node
}

__global__ void k_hist(const int* __restrict__ dst, int E, int* deg) {
    int i = blockIdx.x * 256 + threadIdx.x;
    if (i < E) atomicAdd(&deg[dst[i]], 1);
}

__global__ void k_blocksum(const int* __restrict__ deg, int n, int* bsum) {
    __shared__ int lds[256];
    int b = blockIdx.x, t = threadIdx.x;
    int i = b * 256 + t;
    lds[t] = (i < n) ? deg[i] : 0;
    __syncthreads();
    for (int off = 128; off >= 1; off >>= 1) {
        if (t < off) lds[t] += lds[t + off];
        __syncthreads();
    }
    if (t == 0) bsum[b] = lds[0];
}

__global__ void k_bscan(int* bsum, int nb) {
    __shared__ int lds[1024];
    int t = threadIdx.x;
    int v = (t < nb) ? bsum[t] : 0;
    lds[t] = v;
    __syncthreads();
    for (int off = 1; off < 1024; off <<= 1) {
        int u = (t >= off) ? lds[t - off] : 0;
        __syncthreads();
        lds[t] += u;
        __syncthreads();
    }
    if (t < nb) bsum[t] = lds[t] - v;   // exclusive
}

__global__ void k_mkptr(const int* __restrict__ deg, const int* __restrict__ bsum,
                        int n, int* ptr, int* cur) {
    __shared__ int lds[256];
    int b = blockIdx.x, t = threadIdx.x;
    int i = b * 256 + t;
    int v = (i < n) ? deg[i] : 0;
    lds[t] = v;
    __syncthreads();
    for (int off = 1; off < 256; off <<= 1) {
        int u = (t >= off) ? lds[t - off] : 0;
        __syncthreads();
        lds[t] += u;
        __syncthreads();
    }
    int excl = lds[t] - v + bsum[b];
    if (i < n) {
        ptr[i] = excl;
        cur[i] = excl;
        if (i == n - 1) ptr[n] = excl + v;
    }
}

__global__ void k_scatter(const int* __restrict__ srcE, const int* __restrict__ dstE,
                          int E, int n, int* cur, int* __restrict__ srcs) {
    int i = blockIdx.x * 256 + threadIdx.x;
    int tot = E + n;
    if (i >= tot) return;
    int s, d;
    if (i < E) { s = srcE[i]; d = dstE[i]; }
    else       { s = d = i - E; }       // self-loop
    int pos = atomicAdd(&cur[d], 1);
    srcs[pos] = s;
}

// ---------------- GEMM1: h1 = x @ W1  [N,128]x[128,256], bf16 output ----------------
__global__ __launch_bounds__(256)
void k_gemm1(const float* __restrict__ x, const float* __restrict__ W1,
             const float* __restrict__ attS, const float* __restrict__ attD,
             int n, ushort* __restrict__ h1b,
             float* __restrict__ a1s, float* __restrict__ a1d) {
    __shared__ float Xs[64 * 132];      // 33 KB, pad 132 breaks stride-128 alias
    int t = threadIdx.x;
    int lane = t & 63;
    int n0 = blockIdx.x * 64;

#pragma unroll
    for (int j = 0; j < 8; ++j) {
        int f4 = t + j * 256;
        int node = f4 >> 5;
        int k4 = (f4 & 31) * 4;
        int gn = n0 + node;
        float4 v = make_float4(0.f, 0.f, 0.f, 0.f);
        if (gn < n) v = *(const float4*)(x + (size_t)gn * NFEAT + k4);
        *(float4*)(Xs + node * 132 + k4) = v;
    }
    __syncthreads();

    int wu = __builtin_amdgcn_readfirstlane(t >> 6);   // wave-uniform col slice
    const float* Wc = W1 + wu * 64;

    float acc[64];
#pragma unroll
    for (int c = 0; c < 64; ++c) acc[c] = 0.f;

#pragma unroll 2
    for (int k4 = 0; k4 < 32; ++k4) {
        float4 xv = *(const float4*)(Xs + lane * 132 + k4 * 4);
#pragma unroll
        for (int i = 0; i < 4; ++i) {
            float xi = (i == 0) ? xv.x : (i == 1) ? xv.y : (i == 2) ? xv.z : xv.w;
            const float* Wr = Wc + (size_t)(k4 * 4 + i) * HC;
#pragma unroll
            for (int c4 = 0; c4 < 16; ++c4) {
                float4 wv = *(const float4*)(Wr + c4 * 4);   // uniform -> scalar loads
                acc[c4 * 4 + 0] += xi * wv.x;
                acc[c4 * 4 + 1] += xi * wv.y;
                acc[c4 * 4 + 2] += xi * wv.z;
                acc[c4 * 4 + 3] += xi * wv.w;
            }
        }
    }

    int gn = n0 + lane;
    if (gn < n) {
        ushort* hp = h1b + (size_t)gn * HC + wu * 64;
#pragma unroll
        for (int q = 0; q < 8; ++q) {
            uint4 v;
            v.x = packbf(acc[q * 8 + 0], acc[q * 8 + 1]);
            v.y = packbf(acc[q * 8 + 2], acc[q * 8 + 3]);
            v.z = packbf(acc[q * 8 + 4], acc[q * 8 + 5]);
            v.w = packbf(acc[q * 8 + 6], acc[q * 8 + 7]);
            *(uint4*)(hp + q * 8) = v;
        }
        float as0 = 0.f, ad0 = 0.f, as1 = 0.f, ad1 = 0.f;
#pragma unroll
        for (int c = 0; c < 32; ++c) {
            as0 += acc[c] * attS[wu * 64 + c];
            ad0 += acc[c] * attD[wu * 64 + c];
            as1 += acc[32 + c] * attS[wu * 64 + 32 + c];
            ad1 += acc[32 + c] * attD[wu * 64 + 32 + c];
        }
        a1s[(size_t)gn * HEADS + wu * 2]     = as0;
        a1s[(size_t)gn * HEADS + wu * 2 + 1] = as1;
        a1d[(size_t)gn * HEADS + wu * 2]     = ad0;
        a1d[(size_t)gn * HEADS + wu * 2 + 1] = ad1;
    }
}

// ---------------- Layer-1 aggregation: one wave per dst node, online softmax ----------------
// bf16 h1 gather (512B/edge), 8-wide unroll + masked tail, scalarized edge indices.
__global__ __launch_bounds__(256)
void k_agg1(const ushort* __restrict__ h1b, const float* __restrict__ a1s,
            const float* __restrict__ a1d, const float* __restrict__ b1,
            const int* __restrict__ ptr, const int* __restrict__ srcs,
            int n, ushort* __restrict__ hgb) {
    int wid = blockIdx.x * 4 + (threadIdx.x >> 6);
    if (wid >= n) return;
    int lane = threadIdx.x & 63;
    int h = lane >> 3;
    float adn = a1d[wid * HEADS + h];
    int beg = __builtin_amdgcn_readfirstlane(ptr[wid]);
    int end = __builtin_amdgcn_readfirstlane(ptr[wid + 1]);
    float m = -INFINITY, s = 0.f;
    float4 acc = make_float4(0.f, 0.f, 0.f, 0.f);

    int i = beg;
    for (; i + 8 <= end; i += 8) {
        int sn[8];
#pragma unroll
        for (int j = 0; j < 8; ++j) sn[j] = __builtin_amdgcn_readfirstlane(srcs[i + j]);
        float av[8];
        uint2 hv[8];
#pragma unroll
        for (int j = 0; j < 8; ++j) av[j] = a1s[sn[j] * HEADS + h];
#pragma unroll
        for (int j = 0; j < 8; ++j)
            hv[j] = *(const uint2*)(h1b + (size_t)sn[j] * HC + lane * 4);
        float e[8];
#pragma unroll
        for (int j = 0; j < 8; ++j) {
            float a = av[j] + adn;
            e[j] = (a > 0.f) ? a : 0.2f * a;
        }
        float mn = m;
#pragma unroll
        for (int j = 0; j < 8; ++j) mn = fmaxf(mn, e[j]);
        float corr = __expf(m - mn);
        float p[8];
#pragma unroll
        for (int j = 0; j < 8; ++j) p[j] = __expf(e[j] - mn);
        float ps = 0.f;
#pragma unroll
        for (int j = 0; j < 8; ++j) ps += p[j];
        s = s * corr + ps;
        float cx = acc.x * corr, cy = acc.y * corr, cz = acc.z * corr, cw = acc.w * corr;
#pragma unroll
        for (int j = 0; j < 8; ++j) {
            cx += p[j] * bflo(hv[j].x);
            cy += p[j] * bfhi(hv[j].x);
            cz += p[j] * bflo(hv[j].y);
            cw += p[j] * bfhi(hv[j].y);
        }
        acc = make_float4(cx, cy, cz, cw);
        m = mn;
    }
    if (i < end) {                       // masked final iteration
        int sn[8];
        bool val[8];
#pragma unroll
        for (int j = 0; j < 8; ++j) {
            int idx = i + j;
            val[j] = idx < end;
            sn[j] = __builtin_amdgcn_readfirstlane(srcs[val[j] ? idx : end - 1]);
        }
        float av[8];
        uint2 hv[8];
#pragma unroll
        for (int j = 0; j < 8; ++j) av[j] = a1s[sn[j] * HEADS + h];
#pragma unroll
        for (int j = 0; j < 8; ++j)
            hv[j] = *(const uint2*)(h1b + (size_t)sn[j] * HC + lane * 4);
        float e[8];
#pragma unroll
        for (int j = 0; j < 8; ++j) {
            float a = av[j] + adn;
            e[j] = val[j] ? ((a > 0.f) ? a : 0.2f * a) : -INFINITY;
        }
        float mn = m;
#pragma unroll
        for (int j = 0; j < 8; ++j) mn = fmaxf(mn, e[j]);
        float corr = __expf(m - mn);
        float p[8];
#pragma unroll
        for (int j = 0; j < 8; ++j) p[j] = __expf(e[j] - mn);
        float ps = 0.f;
#pragma unroll
        for (int j = 0; j < 8; ++j) ps += p[j];
        s = s * corr + ps;
        float cx = acc.x * corr, cy = acc.y * corr, cz = acc.z * corr, cw = acc.w * corr;
#pragma unroll
        for (int j = 0; j < 8; ++j) {
            cx += p[j] * bflo(hv[j].x);
            cy += p[j] * bfhi(hv[j].x);
            cz += p[j] * bflo(hv[j].y);
            cw += p[j] * bfhi(hv[j].y);
        }
        acc = make_float4(cx, cy, cz, cw);
        m = mn;
    }

    float inv = 1.f / (s + 1e-16f);
    float4 bv = *(const float4*)(b1 + lane * 4);
    float4 o;
    o.x = acc.x * inv + bv.x;
    o.y = acc.y * inv + bv.y;
    o.z = acc.z * inv + bv.z;
    o.w = acc.w * inv + bv.w;
    o.x = (o.x > 0.f) ? o.x : (__expf(o.x) - 1.f);
    o.y = (o.y > 0.f) ? o.y : (__expf(o.y) - 1.f);
    o.z = (o.z > 0.f) ? o.z : (__expf(o.z) - 1.f);
    o.w = (o.w > 0.f) ? o.w : (__expf(o.w) - 1.f);
    uint2 ov;
    ov.x = packbf(o.x, o.y);
    ov.y = packbf(o.z, o.w);
    *(uint2*)(hgb + (size_t)wid * HC + lane * 4) = ov;
}

// ---------------- GEMM2: h2 = hg @ W2  [N,256]x[256,40], bf16 in/out ----------------
__global__ __launch_bounds__(256)
void k_gemm2(const ushort* __restrict__ hgb, const float* __restrict__ W2,
             const float* __restrict__ a2sw, const float* __restrict__ a2dw,
             int n, ushort* __restrict__ h2b,
             float* __restrict__ a2s, float* __restrict__ a2d) {
    int t = threadIdx.x;
    int lane = t & 63;
    int w = t >> 6;
    int gn = blockIdx.x * 256 + w * 64 + lane;
    bool live = gn < n;
    const ushort* xr = hgb + (live ? (size_t)gn * HC : 0);

    float acc[NCLASS];
#pragma unroll
    for (int c = 0; c < NCLASS; ++c) acc[c] = 0.f;

#pragma unroll 2
    for (int k8 = 0; k8 < 32; ++k8) {
        uint4 xv = *(const uint4*)(xr + k8 * 8);
        float xf[8];
        xf[0] = bflo(xv.x); xf[1] = bfhi(xv.x);
        xf[2] = bflo(xv.y); xf[3] = bfhi(xv.y);
        xf[4] = bflo(xv.z); xf[5] = bfhi(xv.z);
        xf[6] = bflo(xv.w); xf[7] = bfhi(xv.w);
#pragma unroll
        for (int j = 0; j < 8; ++j) {
            const float* Wr = W2 + (size_t)(k8 * 8 + j) * NCLASS;
#pragma unroll
            for (int c4 = 0; c4 < 10; ++c4) {
                float4 wv = *(const float4*)(Wr + c4 * 4);   // uniform -> scalar loads
                acc[c4 * 4 + 0] += xf[j] * wv.x;
                acc[c4 * 4 + 1] += xf[j] * wv.y;
                acc[c4 * 4 + 2] += xf[j] * wv.z;
                acc[c4 * 4 + 3] += xf[j] * wv.w;
            }
        }
    }

    if (live) {
        float as = 0.f, ad = 0.f;
#pragma unroll
        for (int c4 = 0; c4 < 10; ++c4) {
            float4 sv = *(const float4*)(a2sw + c4 * 4);
            float4 dv = *(const float4*)(a2dw + c4 * 4);
            as += acc[c4 * 4] * sv.x + acc[c4 * 4 + 1] * sv.y
                + acc[c4 * 4 + 2] * sv.z + acc[c4 * 4 + 3] * sv.w;
            ad += acc[c4 * 4] * dv.x + acc[c4 * 4 + 1] * dv.y
                + acc[c4 * 4 + 2] * dv.z + acc[c4 * 4 + 3] * dv.w;
        }
#pragma unroll
        for (int q = 0; q < 5; ++q) {
            uint4 v;
            v.x = packbf(acc[q * 8 + 0], acc[q * 8 + 1]);
            v.y = packbf(acc[q * 8 + 2], acc[q * 8 + 3]);
            v.z = packbf(acc[q * 8 + 4], acc[q * 8 + 5]);
            v.w = packbf(acc[q * 8 + 6], acc[q * 8 + 7]);
            *(uint4*)(h2b + (size_t)gn * NCLASS + q * 8) = v;
        }
        a2s[gn] = as;
        a2d[gn] = ad;
    }
}

// ---------------- Layer-2 aggregation + bias + log_softmax ----------------
__global__ __launch_bounds__(256)
void k_agg2(const ushort* __restrict__ h2b, const float* __restrict__ a2s,
            const float* __restrict__ a2d, const float* __restrict__ b2,
            const int* __restrict__ ptr, const int* __restrict__ srcs,
            int n, float* __restrict__ out) {
    int wid = blockIdx.x * 4 + (threadIdx.x >> 6);
    if (wid >= n) return;
    int lane = threadIdx.x & 63;
    bool live = lane < NCLASS;
    int col = live ? lane : 0;
    float adn = a2d[wid];
    int beg = __builtin_amdgcn_readfirstlane(ptr[wid]);
    int end = __builtin_amdgcn_readfirstlane(ptr[wid + 1]);
    float m = -INFINITY, s = 0.f, acc = 0.f;

    int i = beg;
    for (; i + 8 <= end; i += 8) {
        int sn[8];
#pragma unroll
        for (int j = 0; j < 8; ++j) sn[j] = __builtin_amdgcn_readfirstlane(srcs[i + j]);
        float av[8];
        float hv[8];
#pragma unroll
        for (int j = 0; j < 8; ++j) av[j] = a2s[sn[j]];
#pragma unroll
        for (int j = 0; j < 8; ++j)
            hv[j] = __uint_as_float((uint)h2b[(size_t)sn[j] * NCLASS + col] << 16);
        float e[8];
#pragma unroll
        for (int j = 0; j < 8; ++j) {
            float a = av[j] + adn;
            e[j] = (a > 0.f) ? a : 0.2f * a;
        }
        float mn = m;
#pragma unroll
        for (int j = 0; j < 8; ++j) mn = fmaxf(mn, e[j]);
        float corr = __expf(m - mn);
        float p[8];
#pragma unroll
        for (int j = 0; j < 8; ++j) p[j] = __expf(e[j] - mn);
        float ps = 0.f, pa = 0.f;
#pragma unroll
        for (int j = 0; j < 8; ++j) { ps += p[j]; pa += p[j] * hv[j]; }
        s = s * corr + ps;
        acc = acc * corr + pa;
        m = mn;
    }
    if (i < end) {
        int sn[8];
        bool val[8];
#pragma unroll
        for (int j = 0; j < 8; ++j) {
            int idx = i + j;
            val[j] = idx < end;
            sn[j] = __builtin_amdgcn_readfirstlane(srcs[val[j] ? idx : end - 1]);
        }
        float av[8];
        float hv[8];
#pragma unroll
        for (int j = 0; j < 8; ++j) av[j] = a2s[sn[j]];
#pragma unroll
        for (int j = 0; j < 8; ++j)
            hv[j] = __uint_as_float((uint)h2b[(size_t)sn[j] * NCLASS + col] << 16);
        float e[8];
#pragma unroll
        for (int j = 0; j < 8; ++j) {
            float a = av[j] + adn;
            e[j] = val[j] ? ((a > 0.f) ? a : 0.2f * a) : -INFINITY;
        }
        float mn = m;
#pragma unroll
        for (int j = 0; j < 8; ++j) mn = fmaxf(mn, e[j]);
        float corr = __expf(m - mn);
        float p[8];
#pragma unroll
        for (int j = 0; j < 8; ++j) p[j] = __expf(e[j] - mn);
        float ps = 0.f, pa = 0.f;
#pragma unroll
        for (int j = 0; j < 8; ++j) { ps += p[j]; pa += p[j] * hv[j]; }
        s = s * corr + ps;
        acc = acc * corr + pa;
        m = mn;
    }

    float val0 = acc / (s + 1e-16f) + (live ? b2[lane] : 0.f);
    float vmax = live ? val0 : -INFINITY;
#pragma unroll
    for (int msk = 1; msk < 64; msk <<= 1) vmax = fmaxf(vmax, __shfl_xor(vmax, msk, 64));
    float ex = live ? __expf(val0 - vmax) : 0.f;
#pragma unroll
    for (int msk = 1; msk < 64; msk <<= 1) ex += __shfl_xor(ex, msk, 64);
    float res = val0 - vmax - __logf(ex);
    if (live) out[(size_t)wid * NCLASS + lane] = res;
}

// ---------------- launch ----------------
extern "C" void kernel_launch(void* const* d_in, const int* in_sizes, int n_in,
                              void* d_out, int out_size, void* d_ws, size_t ws_size,
                              hipStream_t stream) {
    const float* x    = (const float*)d_in[0];
    const int*   ei   = (const int*)  d_in[1];
    const float* W1   = (const float*)d_in[2];
    const float* attS = (const float*)d_in[3];
    const float* attD = (const float*)d_in[4];
    const float* b1   = (const float*)d_in[5];
    const float* W2   = (const float*)d_in[6];
    const float* a2sw = (const float*)d_in[7];
    const float* a2dw = (const float*)d_in[8];
    const float* b2   = (const float*)d_in[9];

    int n = in_sizes[0] / NFEAT;
    int E = in_sizes[1] / 2;
    const int* srcE = ei;
    const int* dstE = ei + E;
    int nb = (n + 255) / 256;

    char* p = (char*)d_ws;
    auto alloc = [&](size_t bytes) {
        char* r = p;
        p += (bytes + 255) & ~(size_t)255;
        return r;
    };
    ushort* h1b = (ushort*)alloc((size_t)n * HC * 2);
    ushort* hgb = (ushort*)alloc((size_t)n * HC * 2);
    ushort* h2b = (ushort*)alloc((size_t)n * NCLASS * 2);
    float* a1s = (float*)alloc((size_t)n * HEADS * 4);
    float* a1d = (float*)alloc((size_t)n * HEADS * 4);
    float* a2s = (float*)alloc((size_t)n * 4);
    float* a2d = (float*)alloc((size_t)n * 4);
    int* deg  = (int*)alloc((size_t)n * 4);
    int* bsum = (int*)alloc((size_t)nb * 4);
    int* ptr  = (int*)alloc((size_t)(n + 1) * 4);
    int* cur  = (int*)alloc((size_t)n * 4);
    int* srcs = (int*)alloc((size_t)(E + n) * 4);

    k_deg_init<<<(n + 255) / 256, 256, 0, stream>>>(deg, n);
    k_hist<<<(E + 255) / 256, 256, 0, stream>>>(dstE, E, deg);
    k_blocksum<<<nb, 256, 0, stream>>>(deg, n, bsum);
    k_bscan<<<1, 1024, 0, stream>>>(bsum, nb);
    k_mkptr<<<nb, 256, 0, stream>>>(deg, bsum, n, ptr, cur);
    k_scatter<<<(E + n + 255) / 256, 256, 0, stream>>>(srcE, dstE, E, n, cur, srcs);

    k_gemm1<<<(n + 63) / 64, 256, 0, stream>>>(x, W1, attS, attD, n, h1b, a1s, a1d);
    k_agg1<<<(n + 3) / 4, 256, 0, stream>>>(h1b, a1s, a1d, b1, ptr, srcs, n, hgb);
    k_gemm2<<<(n + 255) / 256, 256, 0, stream>>>(hgb, W2, a2sw, a2dw, n, h2b, a2s, a2d);
    k_agg2<<<(n + 3) / 4, 256, 0, stream>>>(h2b, a2s, a2d, b2, ptr, srcs, n, (float*)d_out);
}

// Round 4
// 398.506 us; speedup vs baseline: 1.6716x; 1.1603x over previous
//
#include <hip/hip_runtime.h>
#include <math.h>

#define NFEAT  128
#define HC     256     // HEADS*NHID
#define HEADS  8
#define NHID   32
#define NCLASS 40

typedef unsigned int  uint;
typedef unsigned short ushort;

// bf16 helpers (RNE pack, cheap unpack)
__device__ __forceinline__ uint f2bf1(float f) {
    uint b = __float_as_uint(f);
    b += 0x7FFFu + ((b >> 16) & 1u);
    return b >> 16;
}
__device__ __forceinline__ uint packbf(float lo, float hi) {
    return f2bf1(lo) | (f2bf1(hi) << 16);
}
__device__ __forceinline__ float bflo(uint u) { return __uint_as_float(u << 16); }
__device__ __forceinline__ float bfhi(uint u) { return __uint_as_float(u & 0xFFFF0000u); }

// ---------------- CSR build (dst-sorted, shared by both layers) ----------------

__global__ void k_deg_init(int* deg, int n) {
    int i = blockIdx.x * 256 + threadIdx.x;
    if (i < n) deg[i] = 1;              // self-loop contributes 1 to every node
}

__global__ void k_hist(const int* __restrict__ dst, int E, int* deg) {
    int i = blockIdx.x * 256 + threadIdx.x;
    if (i < E) atomicAdd(&deg[dst[i]], 1);
}

__global__ void k_blocksum(const int* __restrict__ deg, int n, int* bsum) {
    __shared__ int lds[256];
    int b = blockIdx.x, t = threadIdx.x;
    int i = b * 256 + t;
    lds[t] = (i < n) ? deg[i] : 0;
    __syncthreads();
    for (int off = 128; off >= 1; off >>= 1) {
        if (t < off) lds[t] += lds[t + off];
        __syncthreads();
    }
    if (t == 0) bsum[b] = lds[0];
}

__global__ void k_bscan(int* bsum, int nb) {
    __shared__ int lds[1024];
    int t = threadIdx.x;
    int v = (t < nb) ? bsum[t] : 0;
    lds[t] = v;
    __syncthreads();
    for (int off = 1; off < 1024; off <<= 1) {
        int u = (t >= off) ? lds[t - off] : 0;
        __syncthreads();
        lds[t] += u;
        __syncthreads();
    }
    if (t < nb) bsum[t] = lds[t] - v;   // exclusive
}

__global__ void k_mkptr(const int* __restrict__ deg, const int* __restrict__ bsum,
                        int n, int* ptr, int* cur) {
    __shared__ int lds[256];
    int b = blockIdx.x, t = threadIdx.x;
    int i = b * 256 + t;
    int v = (i < n) ? deg[i] : 0;
    lds[t] = v;
    __syncthreads();
    for (int off = 1; off < 256; off <<= 1) {
        int u = (t >= off) ? lds[t - off] : 0;
        __syncthreads();
        lds[t] += u;
        __syncthreads();
    }
    int excl = lds[t] - v + bsum[b];
    if (i < n) {
        ptr[i] = excl;
        cur[i] = excl;
        if (i == n - 1) ptr[n] = excl + v;
    }
}

__global__ void k_scatter(const int* __restrict__ srcE, const int* __restrict__ dstE,
                          int E, int n, int* cur, int* __restrict__ srcs) {
    int i = blockIdx.x * 256 + threadIdx.x;
    int tot = E + n;
    if (i >= tot) return;
    int s, d;
    if (i < E) { s = srcE[i]; d = dstE[i]; }
    else       { s = d = i - E; }       // self-loop
    int pos = atomicAdd(&cur[d], 1);
    srcs[pos] = s;
}

// ---------------- GEMM1: h1 = x @ W1  [N,128]x[128,256], bf16 output ----------------
__global__ __launch_bounds__(256)
void k_gemm1(const float* __restrict__ x, const float* __restrict__ W1,
             const float* __restrict__ attS, const float* __restrict__ attD,
             int n, ushort* __restrict__ h1b,
             float* __restrict__ a1s, float* __restrict__ a1d) {
    __shared__ float Xs[64 * 132];      // 33 KB, pad 132 breaks stride-128 alias
    int t = threadIdx.x;
    int lane = t & 63;
    int n0 = blockIdx.x * 64;

#pragma unroll
    for (int j = 0; j < 8; ++j) {
        int f4 = t + j * 256;
        int node = f4 >> 5;
        int k4 = (f4 & 31) * 4;
        int gn = n0 + node;
        float4 v = make_float4(0.f, 0.f, 0.f, 0.f);
        if (gn < n) v = *(const float4*)(x + (size_t)gn * NFEAT + k4);
        *(float4*)(Xs + node * 132 + k4) = v;
    }
    __syncthreads();

    int wu = __builtin_amdgcn_readfirstlane(t >> 6);   // wave-uniform col slice
    const float* Wc = W1 + wu * 64;

    float acc[64];
#pragma unroll
    for (int c = 0; c < 64; ++c) acc[c] = 0.f;

#pragma unroll 2
    for (int k4 = 0; k4 < 32; ++k4) {
        float4 xv = *(const float4*)(Xs + lane * 132 + k4 * 4);
#pragma unroll
        for (int i = 0; i < 4; ++i) {
            float xi = (i == 0) ? xv.x : (i == 1) ? xv.y : (i == 2) ? xv.z : xv.w;
            const float* Wr = Wc + (size_t)(k4 * 4 + i) * HC;
#pragma unroll
            for (int c4 = 0; c4 < 16; ++c4) {
                float4 wv = *(const float4*)(Wr + c4 * 4);   // uniform -> scalar loads
                acc[c4 * 4 + 0] += xi * wv.x;
                acc[c4 * 4 + 1] += xi * wv.y;
                acc[c4 * 4 + 2] += xi * wv.z;
                acc[c4 * 4 + 3] += xi * wv.w;
            }
        }
    }

    int gn = n0 + lane;
    if (gn < n) {
        ushort* hp = h1b + (size_t)gn * HC + wu * 64;
#pragma unroll
        for (int q = 0; q < 8; ++q) {
            uint4 v;
            v.x = packbf(acc[q * 8 + 0], acc[q * 8 + 1]);
            v.y = packbf(acc[q * 8 + 2], acc[q * 8 + 3]);
            v.z = packbf(acc[q * 8 + 4], acc[q * 8 + 5]);
            v.w = packbf(acc[q * 8 + 6], acc[q * 8 + 7]);
            *(uint4*)(hp + q * 8) = v;
        }
        float as0 = 0.f, ad0 = 0.f, as1 = 0.f, ad1 = 0.f;
#pragma unroll
        for (int c = 0; c < 32; ++c) {
            as0 += acc[c] * attS[wu * 64 + c];
            ad0 += acc[c] * attD[wu * 64 + c];
            as1 += acc[32 + c] * attS[wu * 64 + 32 + c];
            ad1 += acc[32 + c] * attD[wu * 64 + 32 + c];
        }
        a1s[(size_t)gn * HEADS + wu * 2]     = as0;
        a1s[(size_t)gn * HEADS + wu * 2 + 1] = as1;
        a1d[(size_t)gn * HEADS + wu * 2]     = ad0;
        a1d[(size_t)gn * HEADS + wu * 2 + 1] = ad1;
    }
}

// ---------------- Layer-1 aggregation: one wave per dst node, online softmax ----------------
__global__ __launch_bounds__(256)
void k_agg1(const ushort* __restrict__ h1b, const float* __restrict__ a1s,
            const float* __restrict__ a1d, const float* __restrict__ b1,
            const int* __restrict__ ptr, const int* __restrict__ srcs,
            int n, ushort* __restrict__ hgb) {
    int wid = blockIdx.x * 4 + (threadIdx.x >> 6);
    if (wid >= n) return;
    int lane = threadIdx.x & 63;
    int h = lane >> 3;
    float adn = a1d[wid * HEADS + h];
    int beg = __builtin_amdgcn_readfirstlane(ptr[wid]);
    int end = __builtin_amdgcn_readfirstlane(ptr[wid + 1]);
    float m = -INFINITY, s = 0.f;
    float4 acc = make_float4(0.f, 0.f, 0.f, 0.f);

    int i = beg;
    for (; i + 8 <= end; i += 8) {
        int sn[8];
#pragma unroll
        for (int j = 0; j < 8; ++j) sn[j] = __builtin_amdgcn_readfirstlane(srcs[i + j]);
        float av[8];
        uint2 hv[8];
#pragma unroll
        for (int j = 0; j < 8; ++j) av[j] = a1s[sn[j] * HEADS + h];
#pragma unroll
        for (int j = 0; j < 8; ++j)
            hv[j] = *(const uint2*)(h1b + (size_t)sn[j] * HC + lane * 4);
        float e[8];
#pragma unroll
        for (int j = 0; j < 8; ++j) {
            float a = av[j] + adn;
            e[j] = (a > 0.f) ? a : 0.2f * a;
        }
        float mn = m;
#pragma unroll
        for (int j = 0; j < 8; ++j) mn = fmaxf(mn, e[j]);
        float corr = __expf(m - mn);
        float p[8];
#pragma unroll
        for (int j = 0; j < 8; ++j) p[j] = __expf(e[j] - mn);
        float ps = 0.f;
#pragma unroll
        for (int j = 0; j < 8; ++j) ps += p[j];
        s = s * corr + ps;
        float cx = acc.x * corr, cy = acc.y * corr, cz = acc.z * corr, cw = acc.w * corr;
#pragma unroll
        for (int j = 0; j < 8; ++j) {
            cx += p[j] * bflo(hv[j].x);
            cy += p[j] * bfhi(hv[j].x);
            cz += p[j] * bflo(hv[j].y);
            cw += p[j] * bfhi(hv[j].y);
        }
        acc = make_float4(cx, cy, cz, cw);
        m = mn;
    }
    if (i < end) {                       // masked final iteration
        int sn[8];
        bool val[8];
#pragma unroll
        for (int j = 0; j < 8; ++j) {
            int idx = i + j;
            val[j] = idx < end;
            sn[j] = __builtin_amdgcn_readfirstlane(srcs[val[j] ? idx : end - 1]);
        }
        float av[8];
        uint2 hv[8];
#pragma unroll
        for (int j = 0; j < 8; ++j) av[j] = a1s[sn[j] * HEADS + h];
#pragma unroll
        for (int j = 0; j < 8; ++j)
            hv[j] = *(const uint2*)(h1b + (size_t)sn[j] * HC + lane * 4);
        float e[8];
#pragma unroll
        for (int j = 0; j < 8; ++j) {
            float a = av[j] + adn;
            e[j] = val[j] ? ((a > 0.f) ? a : 0.2f * a) : -INFINITY;
        }
        float mn = m;
#pragma unroll
        for (int j = 0; j < 8; ++j) mn = fmaxf(mn, e[j]);
        float corr = __expf(m - mn);
        float p[8];
#pragma unroll
        for (int j = 0; j < 8; ++j) p[j] = __expf(e[j] - mn);
        float ps = 0.f;
#pragma unroll
        for (int j = 0; j < 8; ++j) ps += p[j];
        s = s * corr + ps;
        float cx = acc.x * corr, cy = acc.y * corr, cz = acc.z * corr, cw = acc.w * corr;
#pragma unroll
        for (int j = 0; j < 8; ++j) {
            cx += p[j] * bflo(hv[j].x);
            cy += p[j] * bfhi(hv[j].x);
            cz += p[j] * bflo(hv[j].y);
            cw += p[j] * bfhi(hv[j].y);
        }
        acc = make_float4(cx, cy, cz, cw);
        m = mn;
    }

    float inv = 1.f / (s + 1e-16f);
    float4 bv = *(const float4*)(b1 + lane * 4);
    float4 o;
    o.x = acc.x * inv + bv.x;
    o.y = acc.y * inv + bv.y;
    o.z = acc.z * inv + bv.z;
    o.w = acc.w * inv + bv.w;
    o.x = (o.x > 0.f) ? o.x : (__expf(o.x) - 1.f);
    o.y = (o.y > 0.f) ? o.y : (__expf(o.y) - 1.f);
    o.z = (o.z > 0.f) ? o.z : (__expf(o.z) - 1.f);
    o.w = (o.w > 0.f) ? o.w : (__expf(o.w) - 1.f);
    uint2 ov;
    ov.x = packbf(o.x, o.y);
    ov.y = packbf(o.z, o.w);
    *(uint2*)(hgb + (size_t)wid * HC + lane * 4) = ov;
}

// ---------------- GEMM2: h2 = hg @ W2  [N,256]x[256,40], bf16 in/out ----------------
// 64 nodes/block (782 blocks), lane = node, wave w owns cols [10w,10w+10).
// X tile staged TRANSPOSED in LDS (k-major, node dim padded to 65): inner-loop
// ds_read_b32 Xs[k2*65+lane] is conflict-free. W2 rows wave-uniform -> scalar
// loads. a2 dot spans 4 waves -> LDS cross-wave reduce.
__global__ __launch_bounds__(256)
void k_gemm2(const ushort* __restrict__ hgb, const float* __restrict__ W2,
             const float* __restrict__ a2sw, const float* __restrict__ a2dw,
             int n, ushort* __restrict__ h2b,
             float* __restrict__ a2s, float* __restrict__ a2d) {
    __shared__ uint Xs[128 * 65];       // 33.3 KB, [k2][node] k2=uint pair of bf16
    __shared__ float Ps[4][64];
    __shared__ float Pd[4][64];
    int t = threadIdx.x;
    int lane = t & 63;
    int w = t >> 6;
    int n0 = blockIdx.x * 64;

    // stage: 64 nodes x 128 uints = 2048 uint4 global, 8 per thread, coalesced;
    // scatter into transposed LDS (4 ds_write_b32 each)
#pragma unroll
    for (int j = 0; j < 8; ++j) {
        int g = t + j * 256;
        int node = g >> 5;              // 32 uint4 per node row
        int k2b = (g & 31) * 4;
        int gn = n0 + node;
        uint4 v = make_uint4(0u, 0u, 0u, 0u);
        if (gn < n) v = *(const uint4*)(hgb + (size_t)gn * HC + k2b * 2);
        Xs[(k2b + 0) * 65 + node] = v.x;
        Xs[(k2b + 1) * 65 + node] = v.y;
        Xs[(k2b + 2) * 65 + node] = v.z;
        Xs[(k2b + 3) * 65 + node] = v.w;
    }
    __syncthreads();

    int wu = __builtin_amdgcn_readfirstlane(w);        // wave-uniform col slice
    const float* Wc = W2 + wu * 10;

    float acc[10];
#pragma unroll
    for (int c = 0; c < 10; ++c) acc[c] = 0.f;

#pragma unroll 2
    for (int k2 = 0; k2 < 128; ++k2) {
        uint xp = Xs[k2 * 65 + lane];
        float x0 = bflo(xp), x1 = bfhi(xp);
        const float* Wr0 = Wc + (size_t)(2 * k2) * NCLASS;
        const float* Wr1 = Wr0 + NCLASS;
#pragma unroll
        for (int c = 0; c < 10; ++c) {
            acc[c] += x0 * Wr0[c] + x1 * Wr1[c];       // uniform -> scalar loads
        }
    }

    int gn = n0 + lane;
    float as = 0.f, ad = 0.f;
#pragma unroll
    for (int c = 0; c < 10; ++c) {
        as += acc[c] * a2sw[wu * 10 + c];
        ad += acc[c] * a2dw[wu * 10 + c];
    }
    Ps[w][lane] = as;
    Pd[w][lane] = ad;
    if (gn < n) {
        uint* hp = (uint*)(h2b + (size_t)gn * NCLASS + wu * 10);   // 4B-aligned (20B*wu)
#pragma unroll
        for (int q = 0; q < 5; ++q)
            hp[q] = packbf(acc[q * 2], acc[q * 2 + 1]);
    }
    __syncthreads();
    if (w == 0 && gn < n) {
        a2s[gn] = Ps[0][lane] + Ps[1][lane] + Ps[2][lane] + Ps[3][lane];
        a2d[gn] = Pd[0][lane] + Pd[1][lane] + Pd[2][lane] + Pd[3][lane];
    }
}

// ---------------- Layer-2 aggregation + bias + log_softmax ----------------
__global__ __launch_bounds__(256)
void k_agg2(const ushort* __restrict__ h2b, const float* __restrict__ a2s,
            const float* __restrict__ a2d, const float* __restrict__ b2,
            const int* __restrict__ ptr, const int* __restrict__ srcs,
            int n, float* __restrict__ out) {
    int wid = blockIdx.x * 4 + (threadIdx.x >> 6);
    if (wid >= n) return;
    int lane = threadIdx.x & 63;
    bool live = lane < NCLASS;
    int col = live ? lane : 0;
    float adn = a2d[wid];
    int beg = __builtin_amdgcn_readfirstlane(ptr[wid]);
    int end = __builtin_amdgcn_readfirstlane(ptr[wid + 1]);
    float m = -INFINITY, s = 0.f, acc = 0.f;

    int i = beg;
    for (; i + 8 <= end; i += 8) {
        int sn[8];
#pragma unroll
        for (int j = 0; j < 8; ++j) sn[j] = __builtin_amdgcn_readfirstlane(srcs[i + j]);
        float av[8];
        float hv[8];
#pragma unroll
        for (int j = 0; j < 8; ++j) av[j] = a2s[sn[j]];
#pragma unroll
        for (int j = 0; j < 8; ++j)
            hv[j] = __uint_as_float((uint)h2b[(size_t)sn[j] * NCLASS + col] << 16);
        float e[8];
#pragma unroll
        for (int j = 0; j < 8; ++j) {
            float a = av[j] + adn;
            e[j] = (a > 0.f) ? a : 0.2f * a;
        }
        float mn = m;
#pragma unroll
        for (int j = 0; j < 8; ++j) mn = fmaxf(mn, e[j]);
        float corr = __expf(m - mn);
        float p[8];
#pragma unroll
        for (int j = 0; j < 8; ++j) p[j] = __expf(e[j] - mn);
        float ps = 0.f, pa = 0.f;
#pragma unroll
        for (int j = 0; j < 8; ++j) { ps += p[j]; pa += p[j] * hv[j]; }
        s = s * corr + ps;
        acc = acc * corr + pa;
        m = mn;
    }
    if (i < end) {
        int sn[8];
        bool val[8];
#pragma unroll
        for (int j = 0; j < 8; ++j) {
            int idx = i + j;
            val[j] = idx < end;
            sn[j] = __builtin_amdgcn_readfirstlane(srcs[val[j] ? idx : end - 1]);
        }
        float av[8];
        float hv[8];
#pragma unroll
        for (int j = 0; j < 8; ++j) av[j] = a2s[sn[j]];
#pragma unroll
        for (int j = 0; j < 8; ++j)
            hv[j] = __uint_as_float((uint)h2b[(size_t)sn[j] * NCLASS + col] << 16);
        float e[8];
#pragma unroll
        for (int j = 0; j < 8; ++j) {
            float a = av[j] + adn;
            e[j] = val[j] ? ((a > 0.f) ? a : 0.2f * a) : -INFINITY;
        }
        float mn = m;
#pragma unroll
        for (int j = 0; j < 8; ++j) mn = fmaxf(mn, e[j]);
        float corr = __expf(m - mn);
        float p[8];
#pragma unroll
        for (int j = 0; j < 8; ++j) p[j] = __expf(e[j] - mn);
        float ps = 0.f, pa = 0.f;
#pragma unroll
        for (int j = 0; j < 8; ++j) { ps += p[j]; pa += p[j] * hv[j]; }
        s = s * corr + ps;
        acc = acc * corr + pa;
        m = mn;
    }

    float val0 = acc / (s + 1e-16f) + (live ? b2[lane] : 0.f);
    float vmax = live ? val0 : -INFINITY;
#pragma unroll
    for (int msk = 1; msk < 64; msk <<= 1) vmax = fmaxf(vmax, __shfl_xor(vmax, msk, 64));
    float ex = live ? __expf(val0 - vmax) : 0.f;
#pragma unroll
    for (int msk = 1; msk < 64; msk <<= 1) ex += __shfl_xor(ex, msk, 64);
    float res = val0 - vmax - __logf(ex);
    if (live) out[(size_t)wid * NCLASS + lane] = res;
}

// ---------------- launch ----------------
extern "C" void kernel_launch(void* const* d_in, const int* in_sizes, int n_in,
                              void* d_out, int out_size, void* d_ws, size_t ws_size,
                              hipStream_t stream) {
    const float* x    = (const float*)d_in[0];
    const int*   ei   = (const int*)  d_in[1];
    const float* W1   = (const float*)d_in[2];
    const float* attS = (const float*)d_in[3];
    const float* attD = (const float*)d_in[4];
    const float* b1   = (const float*)d_in[5];
    const float* W2   = (const float*)d_in[6];
    const float* a2sw = (const float*)d_in[7];
    const float* a2dw = (const float*)d_in[8];
    const float* b2   = (const float*)d_in[9];

    int n = in_sizes[0] / NFEAT;
    int E = in_sizes[1] / 2;
    const int* srcE = ei;
    const int* dstE = ei + E;
    int nb = (n + 255) / 256;

    char* p = (char*)d_ws;
    auto alloc = [&](size_t bytes) {
        char* r = p;
        p += (bytes + 255) & ~(size_t)255;
        return r;
    };
    ushort* h1b = (ushort*)alloc((size_t)n * HC * 2);
    ushort* hgb = (ushort*)alloc((size_t)n * HC * 2);
    ushort* h2b = (ushort*)alloc((size_t)n * NCLASS * 2);
    float* a1s = (float*)alloc((size_t)n * HEADS * 4);
    float* a1d = (float*)alloc((size_t)n * HEADS * 4);
    float* a2s = (float*)alloc((size_t)n * 4);
    float* a2d = (float*)alloc((size_t)n * 4);
    int* deg  = (int*)alloc((size_t)n * 4);
    int* bsum = (int*)alloc((size_t)nb * 4);
    int* ptr  = (int*)alloc((size_t)(n + 1) * 4);
    int* cur  = (int*)alloc((size_t)n * 4);
    int* srcs = (int*)alloc((size_t)(E + n) * 4);

    k_deg_init<<<(n + 255) / 256, 256, 0, stream>>>(deg, n);
    k_hist<<<(E + 255) / 256, 256, 0, stream>>>(dstE, E, deg);
    k_blocksum<<<nb, 256, 0, stream>>>(deg, n, bsum);
    k_bscan<<<1, 1024, 0, stream>>>(bsum, nb);
    k_mkptr<<<nb, 256, 0, stream>>>(deg, bsum, n, ptr, cur);
    k_scatter<<<(E + n + 255) / 256, 256, 0, stream>>>(srcE, dstE, E, n, cur, srcs);

    k_gemm1<<<(n + 63) / 64, 256, 0, stream>>>(x, W1, attS, attD, n, h1b, a1s, a1d);
    k_agg1<<<(n + 3) / 4, 256, 0, stream>>>(h1b, a1s, a1d, b1, ptr, srcs, n, hgb);
    k_gemm2<<<(n + 63) / 64, 256, 0, stream>>>(hgb, W2, a2sw, a2dw, n, h2b, a2s, a2d);
    k_agg2<<<(n + 3) / 4, 256, 0, stream>>>(h2b, a2s, a2d, b2, ptr, srcs, n, (float*)d_out);
}

// Round 6
// 386.572 us; speedup vs baseline: 1.7232x; 1.0309x over previous
//
#include <hip/hip_runtime.h>
#include <math.h>

#define NFEAT  128
#define HC     256     // HEADS*NHID
#define HEADS  8
#define NHID   32
#define NCLASS 40

typedef unsigned int  uint;
typedef unsigned short ushort;

typedef __attribute__((ext_vector_type(8))) short bf16x8;
typedef __attribute__((ext_vector_type(4))) float f32x4;

// bf16 helpers (RNE pack, cheap unpack)
__device__ __forceinline__ uint f2bf1(float f) {
    uint b = __float_as_uint(f);
    b += 0x7FFFu + ((b >> 16) & 1u);
    return b >> 16;
}
__device__ __forceinline__ uint packbf(float lo, float hi) {
    return f2bf1(lo) | (f2bf1(hi) << 16);
}
__device__ __forceinline__ float bflo(uint u) { return __uint_as_float(u << 16); }
__device__ __forceinline__ float bfhi(uint u) { return __uint_as_float(u & 0xFFFF0000u); }
__device__ __forceinline__ ushort f2bfu(float f) { return (ushort)f2bf1(f); }

// split f into bf16 hi + bf16 lo residual; returns packed pair for (a,b)
__device__ __forceinline__ void split2(float a, float b, uint& hi, uint& lo) {
    uint ua = f2bf1(a), ub = f2bf1(b);
    float ra = a - __uint_as_float(ua << 16);
    float rb = b - __uint_as_float(ub << 16);
    hi = ua | (ub << 16);
    lo = packbf(ra, rb);
}

// ---------------- CSR build (dst-sorted, shared by both layers) ----------------

__global__ void k_deg_init(int* deg, int n) {
    int i = blockIdx.x * 256 + threadIdx.x;
    if (i < n) deg[i] = 1;              // self-loop contributes 1 to every node
}

__global__ void k_hist(const int* __restrict__ dst, int E, int* deg) {
    int i = blockIdx.x * 256 + threadIdx.x;
    if (i < E) atomicAdd(&deg[dst[i]], 1);
}

__global__ void k_blocksum(const int* __restrict__ deg, int n, int* bsum) {
    __shared__ int lds[256];
    int b = blockIdx.x, t = threadIdx.x;
    int i = b * 256 + t;
    lds[t] = (i < n) ? deg[i] : 0;
    __syncthreads();
    for (int off = 128; off >= 1; off >>= 1) {
        if (t < off) lds[t] += lds[t + off];
        __syncthreads();
    }
    if (t == 0) bsum[b] = lds[0];
}

__global__ void k_bscan(int* bsum, int nb) {
    __shared__ int lds[1024];
    int t = threadIdx.x;
    int v = (t < nb) ? bsum[t] : 0;
    lds[t] = v;
    __syncthreads();
    for (int off = 1; off < 1024; off <<= 1) {
        int u = (t >= off) ? lds[t - off] : 0;
        __syncthreads();
        lds[t] += u;
        __syncthreads();
    }
    if (t < nb) bsum[t] = lds[t] - v;   // exclusive
}

__global__ void k_mkptr(const int* __restrict__ deg, const int* __restrict__ bsum,
                        int n, int* ptr, int* cur) {
    __shared__ int lds[256];
    int b = blockIdx.x, t = threadIdx.x;
    int i = b * 256 + t;
    int v = (i < n) ? deg[i] : 0;
    lds[t] = v;
    __syncthreads();
    for (int off = 1; off < 256; off <<= 1) {
        int u = (t >= off) ? lds[t - off] : 0;
        __syncthreads();
        lds[t] += u;
        __syncthreads();
    }
    int excl = lds[t] - v + bsum[b];
    if (i < n) {
        ptr[i] = excl;
        cur[i] = excl;
        if (i == n - 1) ptr[n] = excl + v;
    }
}

__global__ void k_scatter(const int* __restrict__ srcE, const int* __restrict__ dstE,
                          int E, int n, int* cur, int* __restrict__ srcs) {
    int i = blockIdx.x * 256 + threadIdx.x;
    int tot = E + n;
    if (i >= tot) return;
    int s, d;
    if (i < E) { s = srcE[i]; d = dstE[i]; }
    else       { s = d = i - E; }       // self-loop
    int pos = atomicAdd(&cur[d], 1);
    srcs[pos] = s;
}

// ---------------- MFMA prep: x -> A frags (hi+lo), W1 -> B frags (hi+lo) ----
// frag layout (16x16x32 bf16): lane holds 8 bf16, A[m=lane&15][k=(lane>>4)*8+j].
// index = ((tile*4 + kstep)*64 + lane)*8
__global__ __launch_bounds__(256)
void k_prepx(const float* __restrict__ x, int n, int tiles_pad,
             ushort* __restrict__ xa_hi, ushort* __restrict__ xa_lo) {
    int g = blockIdx.x * 256 + threadIdx.x;        // one 8-elem frag per thread
    int lane = g & 63;
    int step = (g >> 6) & 3;
    int tile = g >> 8;
    if (tile >= tiles_pad) return;
    int node = tile * 16 + (lane & 15);
    int k = step * 32 + (lane >> 4) * 8;
    uint4 ohi = make_uint4(0u, 0u, 0u, 0u);
    uint4 olo = make_uint4(0u, 0u, 0u, 0u);
    if (node < n) {
        const float* xp = x + (size_t)node * NFEAT + k;
        float4 v0 = *(const float4*)(xp);
        float4 v1 = *(const float4*)(xp + 4);
        split2(v0.x, v0.y, ohi.x, olo.x);
        split2(v0.z, v0.w, ohi.y, olo.y);
        split2(v1.x, v1.y, ohi.z, olo.z);
        split2(v1.z, v1.w, ohi.w, olo.w);
    }
    *(uint4*)(xa_hi + (size_t)g * 8) = ohi;
    *(uint4*)(xa_lo + (size_t)g * 8) = olo;
}

// B frag: lane holds B[k=(lane>>4)*8+j][ncol=lane&15], index=((ntile*4+kstep)*64+lane)*8
__global__ __launch_bounds__(256)
void k_prepw(const float* __restrict__ W1,
             ushort* __restrict__ Wb_hi, ushort* __restrict__ Wb_lo) {
    int g = blockIdx.x * 256 + threadIdx.x;        // 16*4*64 = 4096 threads
    int lane = g & 63;
    int step = (g >> 6) & 3;
    int tile = g >> 8;
    int ncol = tile * 16 + (lane & 15);
    int k0 = step * 32 + (lane >> 4) * 8;
    uint4 ohi, olo;
    float f[8];
#pragma unroll
    for (int j = 0; j < 8; ++j) f[j] = W1[(size_t)(k0 + j) * HC + ncol];
    split2(f[0], f[1], ohi.x, olo.x);
    split2(f[2], f[3], ohi.y, olo.y);
    split2(f[4], f[5], ohi.z, olo.z);
    split2(f[6], f[7], ohi.w, olo.w);
    *(uint4*)(Wb_hi + (size_t)g * 8) = ohi;
    *(uint4*)(Wb_lo + (size_t)g * 8) = olo;
}

// ---------------- GEMM1 (MFMA, split-bf16): h1 = x @ W1 ----------------
// 4 waves/block; wave = 16-node M-tile x 256 cols (16 n-tiles) x K=128.
// 3 passes: x_hi@W_hi + x_lo@W_hi + x_hi@W_lo  (~f32-grade accuracy).
// Attention dots from f32 acc via 16-lane butterfly; h1b via LDS bf16 repack.
__global__ __launch_bounds__(256)
void k_gemm1(const ushort* __restrict__ xa_hi, const ushort* __restrict__ xa_lo,
             const ushort* __restrict__ Wb_hi, const ushort* __restrict__ Wb_lo,
             const float* __restrict__ attS, const float* __restrict__ attD,
             int n, ushort* __restrict__ h1b,
             float* __restrict__ a1s, float* __restrict__ a1d) {
    __shared__ ushort Cs[4][16][264];   // 33 KB: [wave][m][col], 528B rows (16B-aligned)
    __shared__ float AttS[HC], AttD[HC];
    int t = threadIdx.x;
    int lane = t & 63;
    int w = t >> 6;

    AttS[t] = attS[t];
    AttD[t] = attD[t];
    __syncthreads();

    int tile_m = blockIdx.x * 4 + w;

    f32x4 acc[16];
#pragma unroll
    for (int i = 0; i < 16; ++i) acc[i] = (f32x4){0.f, 0.f, 0.f, 0.f};

    const bf16x8* Ah = (const bf16x8*)xa_hi;
    const bf16x8* Al = (const bf16x8*)xa_lo;
    const bf16x8* Bh = (const bf16x8*)Wb_hi;
    const bf16x8* Bl = (const bf16x8*)Wb_lo;
#pragma unroll
    for (int ks = 0; ks < 4; ++ks) {
        bf16x8 ah = Ah[(size_t)(tile_m * 4 + ks) * 64 + lane];
        bf16x8 al = Al[(size_t)(tile_m * 4 + ks) * 64 + lane];
#pragma unroll
        for (int nt = 0; nt < 16; ++nt) {
            bf16x8 bh = Bh[(size_t)(nt * 4 + ks) * 64 + lane];
            bf16x8 bl = Bl[(size_t)(nt * 4 + ks) * 64 + lane];
            acc[nt] = __builtin_amdgcn_mfma_f32_16x16x32_bf16(ah, bh, acc[nt], 0, 0, 0);
            acc[nt] = __builtin_amdgcn_mfma_f32_16x16x32_bf16(al, bh, acc[nt], 0, 0, 0);
            acc[nt] = __builtin_amdgcn_mfma_f32_16x16x32_bf16(ah, bl, acc[nt], 0, 0, 0);
        }
    }

    // C layout: col = nt*16 + (lane&15), row = (lane>>4)*4 + reg  [m89-verified]
    int cc = lane & 15;
    int r0 = (lane >> 4) * 4;

    // attention dots from f32 acc: head h = cols h*32..h*32+31 = nt 2h, 2h+1
#pragma unroll
    for (int h = 0; h < HEADS; ++h) {
        float sS0 = AttS[h * 32 + cc],      sS1 = AttS[h * 32 + 16 + cc];
        float sD0 = AttD[h * 32 + cc],      sD1 = AttD[h * 32 + 16 + cc];
#pragma unroll
        for (int r = 0; r < 4; ++r) {
            float ps = acc[2 * h][r] * sS0 + acc[2 * h + 1][r] * sS1;
            float pd = acc[2 * h][r] * sD0 + acc[2 * h + 1][r] * sD1;
#pragma unroll
            for (int msk = 1; msk < 16; msk <<= 1) {
                ps += __shfl_xor(ps, msk, 64);
                pd += __shfl_xor(pd, msk, 64);
            }
            if (cc == 0) {
                int gn = tile_m * 16 + r0 + r;
                if (gn < n) {
                    a1s[(size_t)gn * HEADS + h] = ps;
                    a1d[(size_t)gn * HEADS + h] = pd;
                }
            }
        }
    }

    // bf16 repack into LDS
#pragma unroll
    for (int nt = 0; nt < 16; ++nt) {
#pragma unroll
        for (int r = 0; r < 4; ++r)
            Cs[w][r0 + r][nt * 16 + cc] = f2bfu(acc[nt][r]);
    }
    __syncthreads();

    // coalesced readback: thread t -> node = t>>2, col chunk q = t&3 (64 cols each)
    int node_local = t >> 2;
    int q = t & 3;
    int gn = blockIdx.x * 64 + node_local;
    if (gn < n) {
        const ushort* crow = &Cs[node_local >> 4][node_local & 15][q * 64];
        ushort* hp = h1b + (size_t)gn * HC + q * 64;
#pragma unroll
        for (int i = 0; i < 8; ++i)          // FULL 64-ushort chunk (8 x uint4)
            *(uint4*)(hp + i * 8) = *(const uint4*)(crow + i * 8);
    }
}

// ---------------- Layer-1 aggregation: one wave per dst node, online softmax ----------------
__global__ __launch_bounds__(256)
void k_agg1(const ushort* __restrict__ h1b, const float* __restrict__ a1s,
            const float* __restrict__ a1d, const float* __restrict__ b1,
            const int* __restrict__ ptr, const int* __restrict__ srcs,
            int n, ushort* __restrict__ hgb) {
    int wid = blockIdx.x * 4 + (threadIdx.x >> 6);
    if (wid >= n) return;
    int lane = threadIdx.x & 63;
    int h = lane >> 3;
    float adn = a1d[wid * HEADS + h];
    int beg = __builtin_amdgcn_readfirstlane(ptr[wid]);
    int end = __builtin_amdgcn_readfirstlane(ptr[wid + 1]);
    float m = -INFINITY, s = 0.f;
    float4 acc = make_float4(0.f, 0.f, 0.f, 0.f);

    int i = beg;
    for (; i + 8 <= end; i += 8) {
        int sn[8];
#pragma unroll
        for (int j = 0; j < 8; ++j) sn[j] = __builtin_amdgcn_readfirstlane(srcs[i + j]);
        float av[8];
        uint2 hv[8];
#pragma unroll
        for (int j = 0; j < 8; ++j) av[j] = a1s[sn[j] * HEADS + h];
#pragma unroll
        for (int j = 0; j < 8; ++j)
            hv[j] = *(const uint2*)(h1b + (size_t)sn[j] * HC + lane * 4);
        float e[8];
#pragma unroll
        for (int j = 0; j < 8; ++j) {
            float a = av[j] + adn;
            e[j] = (a > 0.f) ? a : 0.2f * a;
        }
        float mn = m;
#pragma unroll
        for (int j = 0; j < 8; ++j) mn = fmaxf(mn, e[j]);
        float corr = __expf(m - mn);
        float p[8];
#pragma unroll
        for (int j = 0; j < 8; ++j) p[j] = __expf(e[j] - mn);
        float ps = 0.f;
#pragma unroll
        for (int j = 0; j < 8; ++j) ps += p[j];
        s = s * corr + ps;
        float cx = acc.x * corr, cy = acc.y * corr, cz = acc.z * corr, cw = acc.w * corr;
#pragma unroll
        for (int j = 0; j < 8; ++j) {
            cx += p[j] * bflo(hv[j].x);
            cy += p[j] * bfhi(hv[j].x);
            cz += p[j] * bflo(hv[j].y);
            cw += p[j] * bfhi(hv[j].y);
        }
        acc = make_float4(cx, cy, cz, cw);
        m = mn;
    }
    if (i < end) {                       // masked final iteration
        int sn[8];
        bool val[8];
#pragma unroll
        for (int j = 0; j < 8; ++j) {
            int idx = i + j;
            val[j] = idx < end;
            sn[j] = __builtin_amdgcn_readfirstlane(srcs[val[j] ? idx : end - 1]);
        }
        float av[8];
        uint2 hv[8];
#pragma unroll
        for (int j = 0; j < 8; ++j) av[j] = a1s[sn[j] * HEADS + h];
#pragma unroll
        for (int j = 0; j < 8; ++j)
            hv[j] = *(const uint2*)(h1b + (size_t)sn[j] * HC + lane * 4);
        float e[8];
#pragma unroll
        for (int j = 0; j < 8; ++j) {
            float a = av[j] + adn;
            e[j] = val[j] ? ((a > 0.f) ? a : 0.2f * a) : -INFINITY;
        }
        float mn = m;
#pragma unroll
        for (int j = 0; j < 8; ++j) mn = fmaxf(mn, e[j]);
        float corr = __expf(m - mn);
        float p[8];
#pragma unroll
        for (int j = 0; j < 8; ++j) p[j] = __expf(e[j] - mn);
        float ps = 0.f;
#pragma unroll
        for (int j = 0; j < 8; ++j) ps += p[j];
        s = s * corr + ps;
        float cx = acc.x * corr, cy = acc.y * corr, cz = acc.z * corr, cw = acc.w * corr;
#pragma unroll
        for (int j = 0; j < 8; ++j) {
            cx += p[j] * bflo(hv[j].x);
            cy += p[j] * bfhi(hv[j].x);
            cz += p[j] * bflo(hv[j].y);
            cw += p[j] * bfhi(hv[j].y);
        }
        acc = make_float4(cx, cy, cz, cw);
        m = mn;
    }

    float inv = 1.f / (s + 1e-16f);
    float4 bv = *(const float4*)(b1 + lane * 4);
    float4 o;
    o.x = acc.x * inv + bv.x;
    o.y = acc.y * inv + bv.y;
    o.z = acc.z * inv + bv.z;
    o.w = acc.w * inv + bv.w;
    o.x = (o.x > 0.f) ? o.x : (__expf(o.x) - 1.f);
    o.y = (o.y > 0.f) ? o.y : (__expf(o.y) - 1.f);
    o.z = (o.z > 0.f) ? o.z : (__expf(o.z) - 1.f);
    o.w = (o.w > 0.f) ? o.w : (__expf(o.w) - 1.f);
    uint2 ov;
    ov.x = packbf(o.x, o.y);
    ov.y = packbf(o.z, o.w);
    *(uint2*)(hgb + (size_t)wid * HC + lane * 4) = ov;
}

// ---------------- GEMM2: h2 = hg @ W2  [N,256]x[256,40], bf16 in/out ----------------
__global__ __launch_bounds__(256)
void k_gemm2(const ushort* __restrict__ hgb, const float* __restrict__ W2,
             const float* __restrict__ a2sw, const float* __restrict__ a2dw,
             int n, ushort* __restrict__ h2b,
             float* __restrict__ a2s, float* __restrict__ a2d) {
    __shared__ uint Xs[128 * 65];       // 33.3 KB, [k2][node]
    __shared__ float Ps[4][64];
    __shared__ float Pd[4][64];
    int t = threadIdx.x;
    int lane = t & 63;
    int w = t >> 6;
    int n0 = blockIdx.x * 64;

#pragma unroll
    for (int j = 0; j < 8; ++j) {
        int g = t + j * 256;
        int node = g >> 5;
        int k2b = (g & 31) * 4;
        int gn = n0 + node;
        uint4 v = make_uint4(0u, 0u, 0u, 0u);
        if (gn < n) v = *(const uint4*)(hgb + (size_t)gn * HC + k2b * 2);
        Xs[(k2b + 0) * 65 + node] = v.x;
        Xs[(k2b + 1) * 65 + node] = v.y;
        Xs[(k2b + 2) * 65 + node] = v.z;
        Xs[(k2b + 3) * 65 + node] = v.w;
    }
    __syncthreads();

    int wu = __builtin_amdgcn_readfirstlane(w);
    const float* Wc = W2 + wu * 10;

    float acc[10];
#pragma unroll
    for (int c = 0; c < 10; ++c) acc[c] = 0.f;

#pragma unroll 2
    for (int k2 = 0; k2 < 128; ++k2) {
        uint xp = Xs[k2 * 65 + lane];
        float x0 = bflo(xp), x1 = bfhi(xp);
        const float* Wr0 = Wc + (size_t)(2 * k2) * NCLASS;
        const float* Wr1 = Wr0 + NCLASS;
#pragma unroll
        for (int c = 0; c < 10; ++c) {
            acc[c] += x0 * Wr0[c] + x1 * Wr1[c];
        }
    }

    int gn = n0 + lane;
    float as = 0.f, ad = 0.f;
#pragma unroll
    for (int c = 0; c < 10; ++c) {
        as += acc[c] * a2sw[wu * 10 + c];
        ad += acc[c] * a2dw[wu * 10 + c];
    }
    Ps[w][lane] = as;
    Pd[w][lane] = ad;
    if (gn < n) {
        uint* hp = (uint*)(h2b + (size_t)gn * NCLASS + wu * 10);
#pragma unroll
        for (int q = 0; q < 5; ++q)
            hp[q] = packbf(acc[q * 2], acc[q * 2 + 1]);
    }
    __syncthreads();
    if (w == 0 && gn < n) {
        a2s[gn] = Ps[0][lane] + Ps[1][lane] + Ps[2][lane] + Ps[3][lane];
        a2d[gn] = Pd[0][lane] + Pd[1][lane] + Pd[2][lane] + Pd[3][lane];
    }
}

// ---------------- Layer-2 aggregation + bias + log_softmax ----------------
__global__ __launch_bounds__(256)
void k_agg2(const ushort* __restrict__ h2b, const float* __restrict__ a2s,
            const float* __restrict__ a2d, const float* __restrict__ b2,
            const int* __restrict__ ptr, const int* __restrict__ srcs,
            int n, float* __restrict__ out) {
    int wid = blockIdx.x * 4 + (threadIdx.x >> 6);
    if (wid >= n) return;
    int lane = threadIdx.x & 63;
    bool live = lane < NCLASS;
    int col = live ? lane : 0;
    float adn = a2d[wid];
    int beg = __builtin_amdgcn_readfirstlane(ptr[wid]);
    int end = __builtin_amdgcn_readfirstlane(ptr[wid + 1]);
    float m = -INFINITY, s = 0.f, acc = 0.f;

    int i = beg;
    for (; i + 8 <= end; i += 8) {
        int sn[8];
#pragma unroll
        for (int j = 0; j < 8; ++j) sn[j] = __builtin_amdgcn_readfirstlane(srcs[i + j]);
        float av[8];
        float hv[8];
#pragma unroll
        for (int j = 0; j < 8; ++j) av[j] = a2s[sn[j]];
#pragma unroll
        for (int j = 0; j < 8; ++j)
            hv[j] = __uint_as_float((uint)h2b[(size_t)sn[j] * NCLASS + col] << 16);
        float e[8];
#pragma unroll
        for (int j = 0; j < 8; ++j) {
            float a = av[j] + adn;
            e[j] = (a > 0.f) ? a : 0.2f * a;
        }
        float mn = m;
#pragma unroll
        for (int j = 0; j < 8; ++j) mn = fmaxf(mn, e[j]);
        float corr = __expf(m - mn);
        float p[8];
#pragma unroll
        for (int j = 0; j < 8; ++j) p[j] = __expf(e[j] - mn);
        float ps = 0.f, pa = 0.f;
#pragma unroll
        for (int j = 0; j < 8; ++j) { ps += p[j]; pa += p[j] * hv[j]; }
        s = s * corr + ps;
        acc = acc * corr + pa;
        m = mn;
    }
    if (i < end) {
        int sn[8];
        bool val[8];
#pragma unroll
        for (int j = 0; j < 8; ++j) {
            int idx = i + j;
            val[j] = idx < end;
            sn[j] = __builtin_amdgcn_readfirstlane(srcs[val[j] ? idx : end - 1]);
        }
        float av[8];
        float hv[8];
#pragma unroll
        for (int j = 0; j < 8; ++j) av[j] = a2s[sn[j]];
#pragma unroll
        for (int j = 0; j < 8; ++j)
            hv[j] = __uint_as_float((uint)h2b[(size_t)sn[j] * NCLASS + col] << 16);
        float e[8];
#pragma unroll
        for (int j = 0; j < 8; ++j) {
            float a = av[j] + adn;
            e[j] = val[j] ? ((a > 0.f) ? a : 0.2f * a) : -INFINITY;
        }
        float mn = m;
#pragma unroll
        for (int j = 0; j < 8; ++j) mn = fmaxf(mn, e[j]);
        float corr = __expf(m - mn);
        float p[8];
#pragma unroll
        for (int j = 0; j < 8; ++j) p[j] = __expf(e[j] - mn);
        float ps = 0.f, pa = 0.f;
#pragma unroll
        for (int j = 0; j < 8; ++j) { ps += p[j]; pa += p[j] * hv[j]; }
        s = s * corr + ps;
        acc = acc * corr + pa;
        m = mn;
    }

    float val0 = acc / (s + 1e-16f) + (live ? b2[lane] : 0.f);
    float vmax = live ? val0 : -INFINITY;
#pragma unroll
    for (int msk = 1; msk < 64; msk <<= 1) vmax = fmaxf(vmax, __shfl_xor(vmax, msk, 64));
    float ex = live ? __expf(val0 - vmax) : 0.f;
#pragma unroll
    for (int msk = 1; msk < 64; msk <<= 1) ex += __shfl_xor(ex, msk, 64);
    float res = val0 - vmax - __logf(ex);
    if (live) out[(size_t)wid * NCLASS + lane] = res;
}

// ---------------- launch ----------------
extern "C" void kernel_launch(void* const* d_in, const int* in_sizes, int n_in,
                              void* d_out, int out_size, void* d_ws, size_t ws_size,
                              hipStream_t stream) {
    const float* x    = (const float*)d_in[0];
    const int*   ei   = (const int*)  d_in[1];
    const float* W1   = (const float*)d_in[2];
    const float* attS = (const float*)d_in[3];
    const float* attD = (const float*)d_in[4];
    const float* b1   = (const float*)d_in[5];
    const float* W2   = (const float*)d_in[6];
    const float* a2sw = (const float*)d_in[7];
    const float* a2dw = (const float*)d_in[8];
    const float* b2   = (const float*)d_in[9];

    int n = in_sizes[0] / NFEAT;
    int E = in_sizes[1] / 2;
    const int* srcE = ei;
    const int* dstE = ei + E;
    int nb = (n + 255) / 256;
    int mblocks = (n + 63) / 64;              // gemm1 blocks (64 nodes each)
    int tiles_pad = mblocks * 4;              // 16-node M-tiles, padded

    char* p = (char*)d_ws;
    auto alloc = [&](size_t bytes) {
        char* r = p;
        p += (bytes + 255) & ~(size_t)255;
        return r;
    };
    ushort* h1b  = (ushort*)alloc((size_t)n * HC * 2);
    ushort* hgb  = (ushort*)alloc((size_t)n * HC * 2);
    ushort* h2b  = (ushort*)alloc((size_t)n * NCLASS * 2);
    ushort* xa_h = (ushort*)alloc((size_t)tiles_pad * 4 * 64 * 8 * 2);
    ushort* xa_l = (ushort*)alloc((size_t)tiles_pad * 4 * 64 * 8 * 2);
    ushort* Wb_h = (ushort*)alloc((size_t)16 * 4 * 64 * 8 * 2);
    ushort* Wb_l = (ushort*)alloc((size_t)16 * 4 * 64 * 8 * 2);
    float* a1s = (float*)alloc((size_t)n * HEADS * 4);
    float* a1d = (float*)alloc((size_t)n * HEADS * 4);
    float* a2s = (float*)alloc((size_t)n * 4);
    float* a2d = (float*)alloc((size_t)n * 4);
    int* deg  = (int*)alloc((size_t)n * 4);
    int* bsum = (int*)alloc((size_t)nb * 4);
    int* ptr  = (int*)alloc((size_t)(n + 1) * 4);
    int* cur  = (int*)alloc((size_t)n * 4);
    int* srcs = (int*)alloc((size_t)(E + n) * 4);

    k_deg_init<<<(n + 255) / 256, 256, 0, stream>>>(deg, n);
    k_hist<<<(E + 255) / 256, 256, 0, stream>>>(dstE, E, deg);
    k_blocksum<<<nb, 256, 0, stream>>>(deg, n, bsum);
    k_bscan<<<1, 1024, 0, stream>>>(bsum, nb);
    k_mkptr<<<nb, 256, 0, stream>>>(deg, bsum, n, ptr, cur);
    k_scatter<<<(E + n + 255) / 256, 256, 0, stream>>>(srcE, dstE, E, n, cur, srcs);

    k_prepx<<<tiles_pad, 256, 0, stream>>>(x, n, tiles_pad, xa_h, xa_l);
    k_prepw<<<16, 256, 0, stream>>>(W1, Wb_h, Wb_l);
    k_gemm1<<<mblocks, 256, 0, stream>>>(xa_h, xa_l, Wb_h, Wb_l, attS, attD,
                                         n, h1b, a1s, a1d);
    k_agg1<<<(n + 3) / 4, 256, 0, stream>>>(h1b, a1s, a1d, b1, ptr, srcs, n, hgb);
    k_gemm2<<<(n + 63) / 64, 256, 0, stream>>>(hgb, W2, a2sw, a2dw, n, h2b, a2s, a2d);
    k_agg2<<<(n + 3) / 4, 256, 0, stream>>>(h2b, a2s, a2d, b2, ptr, srcs, n, (float*)d_out);
}

// Round 7
// 350.753 us; speedup vs baseline: 1.8992x; 1.1021x over previous
//
#include <hip/hip_runtime.h>
#include <math.h>

#define NFEAT  128
#define HC     256     // HEADS*NHID
#define HEADS  8
#define NHID   32
#define NCLASS 40

typedef unsigned int  uint;
typedef unsigned short ushort;
typedef unsigned char uchar;

typedef __attribute__((ext_vector_type(8))) short bf16x8;
typedef __attribute__((ext_vector_type(4))) float f32x4;

// bf16 helpers (RNE pack, cheap unpack)
__device__ __forceinline__ uint f2bf1(float f) {
    uint b = __float_as_uint(f);
    b += 0x7FFFu + ((b >> 16) & 1u);
    return b >> 16;
}
__device__ __forceinline__ uint packbf(float lo, float hi) {
    return f2bf1(lo) | (f2bf1(hi) << 16);
}
__device__ __forceinline__ float bflo(uint u) { return __uint_as_float(u << 16); }
__device__ __forceinline__ float bfhi(uint u) { return __uint_as_float(u & 0xFFFF0000u); }

// fp8 e4m3 (OCP) via HW converts
__device__ __forceinline__ uchar f2fp8(float v) {
    return (uchar)(__builtin_amdgcn_cvt_pk_fp8_f32(v, v, 0, false) & 0xFF);
}

// split f into bf16 hi + bf16 lo residual
__device__ __forceinline__ void split2(float a, float b, uint& hi, uint& lo) {
    uint ua = f2bf1(a), ub = f2bf1(b);
    float ra = a - __uint_as_float(ua << 16);
    float rb = b - __uint_as_float(ub << 16);
    hi = ua | (ub << 16);
    lo = packbf(ra, rb);
}

// ---------------- CSR build (dst-sorted, shared by both layers) ----------------

__global__ void k_hist(const int* __restrict__ dst, int E, int* deg) {
    int i = blockIdx.x * 256 + threadIdx.x;
    if (i < E) atomicAdd(&deg[dst[i]], 1);
}

// per-block sums of (deg+1)  [+1 = self-loop]
__global__ void k_blocksum(const int* __restrict__ deg, int n, int* bsum) {
    __shared__ int lds[256];
    int b = blockIdx.x, t = threadIdx.x;
    int i = b * 256 + t;
    lds[t] = (i < n) ? deg[i] + 1 : 0;
    __syncthreads();
    for (int off = 128; off >= 1; off >>= 1) {
        if (t < off) lds[t] += lds[t + off];
        __syncthreads();
    }
    if (t == 0) bsum[b] = lds[0];
}

// fused: per-block parallel reduce of bsum[0..b) + local scan -> ptr/cur
__global__ void k_mkptr(const int* __restrict__ deg, const int* __restrict__ bsum,
                        int n, int* ptr, int* cur) {
    __shared__ int lds[256];
    __shared__ int base_s;
    int b = blockIdx.x, t = threadIdx.x;
    int p = 0;
    for (int i = t; i < b; i += 256) p += bsum[i];
    lds[t] = p;
    __syncthreads();
    for (int off = 128; off >= 1; off >>= 1) {
        if (t < off) lds[t] += lds[t + off];
        __syncthreads();
    }
    if (t == 0) base_s = lds[0];
    __syncthreads();
    int i = b * 256 + t;
    int v = (i < n) ? deg[i] + 1 : 0;   // +1 self-loop
    lds[t] = v;
    __syncthreads();
    for (int off = 1; off < 256; off <<= 1) {
        int u = (t >= off) ? lds[t - off] : 0;
        __syncthreads();
        lds[t] += u;
        __syncthreads();
    }
    int excl = lds[t] - v + base_s;
    if (i < n) {
        ptr[i] = excl;
        cur[i] = excl;
        if (i == n - 1) ptr[n] = excl + v;
    }
}

__global__ void k_scatter(const int* __restrict__ srcE, const int* __restrict__ dstE,
                          int E, int n, int* cur, int* __restrict__ srcs) {
    int i = blockIdx.x * 256 + threadIdx.x;
    int tot = E + n;
    if (i >= tot) return;
    int s, d;
    if (i < E) { s = srcE[i]; d = dstE[i]; }
    else       { s = d = i - E; }       // self-loop
    int pos = atomicAdd(&cur[d], 1);
    srcs[pos] = s;
}

// ---------------- fused MFMA prep: x -> A frags (hi+lo), W1 -> B frags (hi+lo) ----
// frag layout (16x16x32 bf16): lane holds 8 bf16, A[m=lane&15][k=(lane>>4)*8+j].
// index = ((tile*4 + kstep)*64 + lane)*8
__global__ __launch_bounds__(256)
void k_prep(const float* __restrict__ x, const float* __restrict__ W1,
            int n, int tiles_pad,
            ushort* __restrict__ xa_hi, ushort* __restrict__ xa_lo,
            ushort* __restrict__ Wb_hi, ushort* __restrict__ Wb_lo) {
    int blk = blockIdx.x;
    if (blk < tiles_pad) {
        int g = blk * 256 + threadIdx.x;
        int lane = g & 63;
        int step = (g >> 6) & 3;
        int tile = g >> 8;
        int node = tile * 16 + (lane & 15);
        int k = step * 32 + (lane >> 4) * 8;
        uint4 ohi = make_uint4(0u, 0u, 0u, 0u);
        uint4 olo = make_uint4(0u, 0u, 0u, 0u);
        if (node < n) {
            const float* xp = x + (size_t)node * NFEAT + k;
            float4 v0 = *(const float4*)(xp);
            float4 v1 = *(const float4*)(xp + 4);
            split2(v0.x, v0.y, ohi.x, olo.x);
            split2(v0.z, v0.w, ohi.y, olo.y);
            split2(v1.x, v1.y, ohi.z, olo.z);
            split2(v1.z, v1.w, ohi.w, olo.w);
        }
        *(uint4*)(xa_hi + (size_t)g * 8) = ohi;
        *(uint4*)(xa_lo + (size_t)g * 8) = olo;
    } else {
        int g = (blk - tiles_pad) * 256 + threadIdx.x;   // 16*256 = 4096 threads
        int lane = g & 63;
        int step = (g >> 6) & 3;
        int tile = g >> 8;
        int ncol = tile * 16 + (lane & 15);
        int k0 = step * 32 + (lane >> 4) * 8;
        uint4 ohi, olo;
        float f[8];
#pragma unroll
        for (int j = 0; j < 8; ++j) f[j] = W1[(size_t)(k0 + j) * HC + ncol];
        split2(f[0], f[1], ohi.x, olo.x);
        split2(f[2], f[3], ohi.y, olo.y);
        split2(f[4], f[5], ohi.z, olo.z);
        split2(f[6], f[7], ohi.w, olo.w);
        *(uint4*)(Wb_hi + (size_t)g * 8) = ohi;
        *(uint4*)(Wb_lo + (size_t)g * 8) = olo;
    }
}

// ---------------- GEMM1 (MFMA, split-bf16): h1 = x @ W1, fp8 h1 out ----------------
// 4 waves/block; wave = 16-node M-tile x 256 cols (16 n-tiles) x K=128.
// 3 passes: x_hi@W_hi + x_lo@W_hi + x_hi@W_lo  (~f32-grade accuracy).
// Attention dots from f32 acc (16-lane butterfly); h1 stored fp8-e4m3 via LDS repack.
__global__ __launch_bounds__(256)
void k_gemm1(const ushort* __restrict__ xa_hi, const ushort* __restrict__ xa_lo,
             const ushort* __restrict__ Wb_hi, const ushort* __restrict__ Wb_lo,
             const float* __restrict__ attS, const float* __restrict__ attD,
             int n, uchar* __restrict__ h1f8,
             float* __restrict__ a1s, float* __restrict__ a1d) {
    __shared__ uchar Cs[4][16][272];    // 17.4 KB, 272B rows (16B-aligned)
    __shared__ float AttS[HC], AttD[HC];
    int t = threadIdx.x;
    int lane = t & 63;
    int w = t >> 6;

    AttS[t] = attS[t];
    AttD[t] = attD[t];
    __syncthreads();

    int tile_m = blockIdx.x * 4 + w;

    f32x4 acc[16];
#pragma unroll
    for (int i = 0; i < 16; ++i) acc[i] = (f32x4){0.f, 0.f, 0.f, 0.f};

    const bf16x8* Ah = (const bf16x8*)xa_hi;
    const bf16x8* Al = (const bf16x8*)xa_lo;
    const bf16x8* Bh = (const bf16x8*)Wb_hi;
    const bf16x8* Bl = (const bf16x8*)Wb_lo;
#pragma unroll
    for (int ks = 0; ks < 4; ++ks) {
        bf16x8 ah = Ah[(size_t)(tile_m * 4 + ks) * 64 + lane];
        bf16x8 al = Al[(size_t)(tile_m * 4 + ks) * 64 + lane];
#pragma unroll
        for (int nt = 0; nt < 16; ++nt) {
            bf16x8 bh = Bh[(size_t)(nt * 4 + ks) * 64 + lane];
            bf16x8 bl = Bl[(size_t)(nt * 4 + ks) * 64 + lane];
            acc[nt] = __builtin_amdgcn_mfma_f32_16x16x32_bf16(ah, bh, acc[nt], 0, 0, 0);
            acc[nt] = __builtin_amdgcn_mfma_f32_16x16x32_bf16(al, bh, acc[nt], 0, 0, 0);
            acc[nt] = __builtin_amdgcn_mfma_f32_16x16x32_bf16(ah, bl, acc[nt], 0, 0, 0);
        }
    }

    // C layout: col = nt*16 + (lane&15), row = (lane>>4)*4 + reg  [m89-verified]
    int cc = lane & 15;
    int r0 = (lane >> 4) * 4;

    // attention dots from f32 acc: head h = cols h*32..h*32+31 = nt 2h, 2h+1
#pragma unroll
    for (int h = 0; h < HEADS; ++h) {
        float sS0 = AttS[h * 32 + cc],      sS1 = AttS[h * 32 + 16 + cc];
        float sD0 = AttD[h * 32 + cc],      sD1 = AttD[h * 32 + 16 + cc];
#pragma unroll
        for (int r = 0; r < 4; ++r) {
            float ps = acc[2 * h][r] * sS0 + acc[2 * h + 1][r] * sS1;
            float pd = acc[2 * h][r] * sD0 + acc[2 * h + 1][r] * sD1;
#pragma unroll
            for (int msk = 1; msk < 16; msk <<= 1) {
                ps += __shfl_xor(ps, msk, 64);
                pd += __shfl_xor(pd, msk, 64);
            }
            if (cc == 0) {
                int gn = tile_m * 16 + r0 + r;
                if (gn < n) {
                    a1s[(size_t)gn * HEADS + h] = ps;
                    a1d[(size_t)gn * HEADS + h] = pd;
                }
            }
        }
    }

    // fp8 repack into LDS
#pragma unroll
    for (int nt = 0; nt < 16; ++nt) {
#pragma unroll
        for (int r = 0; r < 4; ++r)
            Cs[w][r0 + r][nt * 16 + cc] = f2fp8(acc[nt][r]);
    }
    __syncthreads();

    // coalesced readback: thread t -> node = t>>2, 64-byte chunk q = t&3
    int node_local = t >> 2;
    int q = t & 3;
    int gn = blockIdx.x * 64 + node_local;
    if (gn < n) {
        const uchar* crow = &Cs[node_local >> 4][node_local & 15][q * 64];
        uchar* hp = h1f8 + (size_t)gn * HC + q * 64;
#pragma unroll
        for (int i = 0; i < 4; ++i)
            *(uint4*)(hp + i * 16) = *(const uint4*)(crow + i * 16);
    }
}

// ---------------- Layer-1 aggregation: one wave per dst node, online softmax ----------------
// fp8 h1 gather (256B/edge), 8-wide unroll + masked tail, scalarized edge indices.
__global__ __launch_bounds__(256)
void k_agg1(const uint* __restrict__ h1u, const float* __restrict__ a1s,
            const float* __restrict__ a1d, const float* __restrict__ b1,
            const int* __restrict__ ptr, const int* __restrict__ srcs,
            int n, ushort* __restrict__ hgb) {
    int wid = blockIdx.x * 4 + (threadIdx.x >> 6);
    if (wid >= n) return;
    int lane = threadIdx.x & 63;
    int h = lane >> 3;
    float adn = a1d[wid * HEADS + h];
    int beg = __builtin_amdgcn_readfirstlane(ptr[wid]);
    int end = __builtin_amdgcn_readfirstlane(ptr[wid + 1]);
    float m = -INFINITY, s = 0.f;
    float4 acc = make_float4(0.f, 0.f, 0.f, 0.f);

    int i = beg;
    for (; i + 8 <= end; i += 8) {
        int sn[8];
#pragma unroll
        for (int j = 0; j < 8; ++j) sn[j] = __builtin_amdgcn_readfirstlane(srcs[i + j]);
        float av[8];
        uint hv[8];
#pragma unroll
        for (int j = 0; j < 8; ++j) av[j] = a1s[sn[j] * HEADS + h];
#pragma unroll
        for (int j = 0; j < 8; ++j)
            hv[j] = h1u[(size_t)sn[j] * 64 + lane];
        float e[8];
#pragma unroll
        for (int j = 0; j < 8; ++j) {
            float a = av[j] + adn;
            e[j] = (a > 0.f) ? a : 0.2f * a;
        }
        float mn = m;
#pragma unroll
        for (int j = 0; j < 8; ++j) mn = fmaxf(mn, e[j]);
        float corr = __expf(m - mn);
        float p[8];
#pragma unroll
        for (int j = 0; j < 8; ++j) p[j] = __expf(e[j] - mn);
        float ps = 0.f;
#pragma unroll
        for (int j = 0; j < 8; ++j) ps += p[j];
        s = s * corr + ps;
        float cx = acc.x * corr, cy = acc.y * corr, cz = acc.z * corr, cw = acc.w * corr;
#pragma unroll
        for (int j = 0; j < 8; ++j) {
            auto lo = __builtin_amdgcn_cvt_pk_f32_fp8((int)hv[j], false);
            auto hi = __builtin_amdgcn_cvt_pk_f32_fp8((int)hv[j], true);
            cx += p[j] * lo[0];
            cy += p[j] * lo[1];
            cz += p[j] * hi[0];
            cw += p[j] * hi[1];
        }
        acc = make_float4(cx, cy, cz, cw);
        m = mn;
    }
    if (i < end) {                       // masked final iteration
        int sn[8];
        bool val[8];
#pragma unroll
        for (int j = 0; j < 8; ++j) {
            int idx = i + j;
            val[j] = idx < end;
            sn[j] = __builtin_amdgcn_readfirstlane(srcs[val[j] ? idx : end - 1]);
        }
        float av[8];
        uint hv[8];
#pragma unroll
        for (int j = 0; j < 8; ++j) av[j] = a1s[sn[j] * HEADS + h];
#pragma unroll
        for (int j = 0; j < 8; ++j)
            hv[j] = h1u[(size_t)sn[j] * 64 + lane];
        float e[8];
#pragma unroll
        for (int j = 0; j < 8; ++j) {
            float a = av[j] + adn;
            e[j] = val[j] ? ((a > 0.f) ? a : 0.2f * a) : -INFINITY;
        }
        float mn = m;
#pragma unroll
        for (int j = 0; j < 8; ++j) mn = fmaxf(mn, e[j]);
        float corr = __expf(m - mn);
        float p[8];
#pragma unroll
        for (int j = 0; j < 8; ++j) p[j] = __expf(e[j] - mn);
        float ps = 0.f;
#pragma unroll
        for (int j = 0; j < 8; ++j) ps += p[j];
        s = s * corr + ps;
        float cx = acc.x * corr, cy = acc.y * corr, cz = acc.z * corr, cw = acc.w * corr;
#pragma unroll
        for (int j = 0; j < 8; ++j) {
            auto lo = __builtin_amdgcn_cvt_pk_f32_fp8((int)hv[j], false);
            auto hi = __builtin_amdgcn_cvt_pk_f32_fp8((int)hv[j], true);
            cx += p[j] * lo[0];
            cy += p[j] * lo[1];
            cz += p[j] * hi[0];
            cw += p[j] * hi[1];
        }
        acc = make_float4(cx, cy, cz, cw);
        m = mn;
    }

    float inv = 1.f / (s + 1e-16f);
    float4 bv = *(const float4*)(b1 + lane * 4);
    float4 o;
    o.x = acc.x * inv + bv.x;
    o.y = acc.y * inv + bv.y;
    o.z = acc.z * inv + bv.z;
    o.w = acc.w * inv + bv.w;
    o.x = (o.x > 0.f) ? o.x : (__expf(o.x) - 1.f);
    o.y = (o.y > 0.f) ? o.y : (__expf(o.y) - 1.f);
    o.z = (o.z > 0.f) ? o.z : (__expf(o.z) - 1.f);
    o.w = (o.w > 0.f) ? o.w : (__expf(o.w) - 1.f);
    uint2 ov;
    ov.x = packbf(o.x, o.y);
    ov.y = packbf(o.z, o.w);
    *(uint2*)(hgb + (size_t)wid * HC + lane * 4) = ov;
}

// ---------------- GEMM2: h2 = hg @ W2  [N,256]x[256,40], bf16 in/out ----------------
__global__ __launch_bounds__(256)
void k_gemm2(const ushort* __restrict__ hgb, const float* __restrict__ W2,
             const float* __restrict__ a2sw, const float* __restrict__ a2dw,
             int n, ushort* __restrict__ h2b,
             float* __restrict__ a2s, float* __restrict__ a2d) {
    __shared__ uint Xs[128 * 65];       // 33.3 KB, [k2][node]
    __shared__ float Ps[4][64];
    __shared__ float Pd[4][64];
    int t = threadIdx.x;
    int lane = t & 63;
    int w = t >> 6;
    int n0 = blockIdx.x * 64;

#pragma unroll
    for (int j = 0; j < 8; ++j) {
        int g = t + j * 256;
        int node = g >> 5;
        int k2b = (g & 31) * 4;
        int gn = n0 + node;
        uint4 v = make_uint4(0u, 0u, 0u, 0u);
        if (gn < n) v = *(const uint4*)(hgb + (size_t)gn * HC + k2b * 2);
        Xs[(k2b + 0) * 65 + node] = v.x;
        Xs[(k2b + 1) * 65 + node] = v.y;
        Xs[(k2b + 2) * 65 + node] = v.z;
        Xs[(k2b + 3) * 65 + node] = v.w;
    }
    __syncthreads();

    int wu = __builtin_amdgcn_readfirstlane(w);
    const float* Wc = W2 + wu * 10;

    float acc[10];
#pragma unroll
    for (int c = 0; c < 10; ++c) acc[c] = 0.f;

#pragma unroll 2
    for (int k2 = 0; k2 < 128; ++k2) {
        uint xp = Xs[k2 * 65 + lane];
        float x0 = bflo(xp), x1 = bfhi(xp);
        const float* Wr0 = Wc + (size_t)(2 * k2) * NCLASS;
        const float* Wr1 = Wr0 + NCLASS;
#pragma unroll
        for (int c = 0; c < 10; ++c) {
            acc[c] += x0 * Wr0[c] + x1 * Wr1[c];
        }
    }

    int gn = n0 + lane;
    float as = 0.f, ad = 0.f;
#pragma unroll
    for (int c = 0; c < 10; ++c) {
        as += acc[c] * a2sw[wu * 10 + c];
        ad += acc[c] * a2dw[wu * 10 + c];
    }
    Ps[w][lane] = as;
    Pd[w][lane] = ad;
    if (gn < n) {
        uint* hp = (uint*)(h2b + (size_t)gn * NCLASS + wu * 10);
#pragma unroll
        for (int q = 0; q < 5; ++q)
            hp[q] = packbf(acc[q * 2], acc[q * 2 + 1]);
    }
    __syncthreads();
    if (w == 0 && gn < n) {
        a2s[gn] = Ps[0][lane] + Ps[1][lane] + Ps[2][lane] + Ps[3][lane];
        a2d[gn] = Pd[0][lane] + Pd[1][lane] + Pd[2][lane] + Pd[3][lane];
    }
}

// ---------------- Layer-2 aggregation + bias + log_softmax ----------------
__global__ __launch_bounds__(256)
void k_agg2(const ushort* __restrict__ h2b, const float* __restrict__ a2s,
            const float* __restrict__ a2d, const float* __restrict__ b2,
            const int* __restrict__ ptr, const int* __restrict__ srcs,
            int n, float* __restrict__ out) {
    int wid = blockIdx.x * 4 + (threadIdx.x >> 6);
    if (wid >= n) return;
    int lane = threadIdx.x & 63;
    bool live = lane < NCLASS;
    int col = live ? lane : 0;
    float adn = a2d[wid];
    int beg = __builtin_amdgcn_readfirstlane(ptr[wid]);
    int end = __builtin_amdgcn_readfirstlane(ptr[wid + 1]);
    float m = -INFINITY, s = 0.f, acc = 0.f;

    int i = beg;
    for (; i + 8 <= end; i += 8) {
        int sn[8];
#pragma unroll
        for (int j = 0; j < 8; ++j) sn[j] = __builtin_amdgcn_readfirstlane(srcs[i + j]);
        float av[8];
        float hv[8];
#pragma unroll
        for (int j = 0; j < 8; ++j) av[j] = a2s[sn[j]];
#pragma unroll
        for (int j = 0; j < 8; ++j)
            hv[j] = __uint_as_float((uint)h2b[(size_t)sn[j] * NCLASS + col] << 16);
        float e[8];
#pragma unroll
        for (int j = 0; j < 8; ++j) {
            float a = av[j] + adn;
            e[j] = (a > 0.f) ? a : 0.2f * a;
        }
        float mn = m;
#pragma unroll
        for (int j = 0; j < 8; ++j) mn = fmaxf(mn, e[j]);
        float corr = __expf(m - mn);
        float p[8];
#pragma unroll
        for (int j = 0; j < 8; ++j) p[j] = __expf(e[j] - mn);
        float ps = 0.f, pa = 0.f;
#pragma unroll
        for (int j = 0; j < 8; ++j) { ps += p[j]; pa += p[j] * hv[j]; }
        s = s * corr + ps;
        acc = acc * corr + pa;
        m = mn;
    }
    if (i < end) {
        int sn[8];
        bool val[8];
#pragma unroll
        for (int j = 0; j < 8; ++j) {
            int idx = i + j;
            val[j] = idx < end;
            sn[j] = __builtin_amdgcn_readfirstlane(srcs[val[j] ? idx : end - 1]);
        }
        float av[8];
        float hv[8];
#pragma unroll
        for (int j = 0; j < 8; ++j) av[j] = a2s[sn[j]];
#pragma unroll
        for (int j = 0; j < 8; ++j)
            hv[j] = __uint_as_float((uint)h2b[(size_t)sn[j] * NCLASS + col] << 16);
        float e[8];
#pragma unroll
        for (int j = 0; j < 8; ++j) {
            float a = av[j] + adn;
            e[j] = val[j] ? ((a > 0.f) ? a : 0.2f * a) : -INFINITY;
        }
        float mn = m;
#pragma unroll
        for (int j = 0; j < 8; ++j) mn = fmaxf(mn, e[j]);
        float corr = __expf(m - mn);
        float p[8];
#pragma unroll
        for (int j = 0; j < 8; ++j) p[j] = __expf(e[j] - mn);
        float ps = 0.f, pa = 0.f;
#pragma unroll
        for (int j = 0; j < 8; ++j) { ps += p[j]; pa += p[j] * hv[j]; }
        s = s * corr + ps;
        acc = acc * corr + pa;
        m = mn;
    }

    float val0 = acc / (s + 1e-16f) + (live ? b2[lane] : 0.f);
    float vmax = live ? val0 : -INFINITY;
#pragma unroll
    for (int msk = 1; msk < 64; msk <<= 1) vmax = fmaxf(vmax, __shfl_xor(vmax, msk, 64));
    float ex = live ? __expf(val0 - vmax) : 0.f;
#pragma unroll
    for (int msk = 1; msk < 64; msk <<= 1) ex += __shfl_xor(ex, msk, 64);
    float res = val0 - vmax - __logf(ex);
    if (live) out[(size_t)wid * NCLASS + lane] = res;
}

// ---------------- launch ----------------
extern "C" void kernel_launch(void* const* d_in, const int* in_sizes, int n_in,
                              void* d_out, int out_size, void* d_ws, size_t ws_size,
                              hipStream_t stream) {
    const float* x    = (const float*)d_in[0];
    const int*   ei   = (const int*)  d_in[1];
    const float* W1   = (const float*)d_in[2];
    const float* attS = (const float*)d_in[3];
    const float* attD = (const float*)d_in[4];
    const float* b1   = (const float*)d_in[5];
    const float* W2   = (const float*)d_in[6];
    const float* a2sw = (const float*)d_in[7];
    const float* a2dw = (const float*)d_in[8];
    const float* b2   = (const float*)d_in[9];

    int n = in_sizes[0] / NFEAT;
    int E = in_sizes[1] / 2;
    const int* srcE = ei;
    const int* dstE = ei + E;
    int nb = (n + 255) / 256;
    int mblocks = (n + 63) / 64;              // gemm1 blocks (64 nodes each)
    int tiles_pad = mblocks * 4;              // 16-node M-tiles, padded

    char* p = (char*)d_ws;
    auto alloc = [&](size_t bytes) {
        char* r = p;
        p += (bytes + 255) & ~(size_t)255;
        return r;
    };
    uchar*  h1f8 = (uchar*)alloc((size_t)n * HC);
    ushort* hgb  = (ushort*)alloc((size_t)n * HC * 2);
    ushort* h2b  = (ushort*)alloc((size_t)n * NCLASS * 2);
    ushort* xa_h = (ushort*)alloc((size_t)tiles_pad * 4 * 64 * 8 * 2);
    ushort* xa_l = (ushort*)alloc((size_t)tiles_pad * 4 * 64 * 8 * 2);
    ushort* Wb_h = (ushort*)alloc((size_t)16 * 4 * 64 * 8 * 2);
    ushort* Wb_l = (ushort*)alloc((size_t)16 * 4 * 64 * 8 * 2);
    float* a1s = (float*)alloc((size_t)n * HEADS * 4);
    float* a1d = (float*)alloc((size_t)n * HEADS * 4);
    float* a2s = (float*)alloc((size_t)n * 4);
    float* a2d = (float*)alloc((size_t)n * 4);
    int* deg  = (int*)alloc((size_t)n * 4);
    int* bsum = (int*)alloc((size_t)nb * 4);
    int* ptr  = (int*)alloc((size_t)(n + 1) * 4);
    int* cur  = (int*)alloc((size_t)n * 4);
    int* srcs = (int*)alloc((size_t)(E + n) * 4);

    hipMemsetAsync(deg, 0, (size_t)n * 4, stream);
    k_hist<<<(E + 255) / 256, 256, 0, stream>>>(dstE, E, deg);
    k_blocksum<<<nb, 256, 0, stream>>>(deg, n, bsum);
    k_mkptr<<<nb, 256, 0, stream>>>(deg, bsum, n, ptr, cur);
    k_scatter<<<(E + n + 255) / 256, 256, 0, stream>>>(srcE, dstE, E, n, cur, srcs);

    k_prep<<<tiles_pad + 16, 256, 0, stream>>>(x, W1, n, tiles_pad,
                                               xa_h, xa_l, Wb_h, Wb_l);
    k_gemm1<<<mblocks, 256, 0, stream>>>(xa_h, xa_l, Wb_h, Wb_l, attS, attD,
                                         n, h1f8, a1s, a1d);
    k_agg1<<<(n + 3) / 4, 256, 0, stream>>>((const uint*)h1f8, a1s, a1d, b1,
                                            ptr, srcs, n, hgb);
    k_gemm2<<<(n + 63) / 64, 256, 0, stream>>>(hgb, W2, a2sw, a2dw, n, h2b, a2s, a2d);
    k_agg2<<<(n + 3) / 4, 256, 0, stream>>>(h2b, a2s, a2d, b2, ptr, srcs, n, (float*)d_out);
}

// Round 8
// 336.395 us; speedup vs baseline: 1.9803x; 1.0427x over previous
//
#include <hip/hip_runtime.h>
#include <math.h>

#define NFEAT  128
#define HC     256     // HEADS*NHID
#define HEADS  8
#define NHID   32
#define NCLASS 40

typedef unsigned int  uint;
typedef unsigned short ushort;
typedef unsigned char uchar;

typedef __attribute__((ext_vector_type(8))) short bf16x8;
typedef __attribute__((ext_vector_type(4))) float f32x4;

union U8 { uint4 u; bf16x8 v; };

// bf16 helpers (RNE pack, cheap unpack)
__device__ __forceinline__ uint f2bf1(float f) {
    uint b = __float_as_uint(f);
    b += 0x7FFFu + ((b >> 16) & 1u);
    return b >> 16;
}
__device__ __forceinline__ uint packbf(float lo, float hi) {
    return f2bf1(lo) | (f2bf1(hi) << 16);
}
__device__ __forceinline__ float bflo(uint u) { return __uint_as_float(u << 16); }
__device__ __forceinline__ float bfhi(uint u) { return __uint_as_float(u & 0xFFFF0000u); }

// fp8 e4m3 (OCP) via HW converts
__device__ __forceinline__ uchar f2fp8(float v) {
    return (uchar)(__builtin_amdgcn_cvt_pk_fp8_f32(v, v, 0, false) & 0xFF);
}

// split f into bf16 hi + bf16 lo residual
__device__ __forceinline__ void split2(float a, float b, uint& hi, uint& lo) {
    uint ua = f2bf1(a), ub = f2bf1(b);
    float ra = a - __uint_as_float(ua << 16);
    float rb = b - __uint_as_float(ub << 16);
    hi = ua | (ub << 16);
    lo = packbf(ra, rb);
}

// ---------------- CSR build (dst-sorted, shared by both layers) ----------------

#define HU 4
__global__ void k_hist(const int* __restrict__ dst, int E, int* deg) {
    int tid = blockIdx.x * 256 + threadIdx.x;
    int stride = gridDim.x * 256;
#pragma unroll
    for (int j = 0; j < HU; ++j) {
        int i = tid + j * stride;
        if (i < E) atomicAdd(&deg[dst[i]], 1);
    }
}

// per-block sums of (deg+1)  [+1 = self-loop]
__global__ void k_blocksum(const int* __restrict__ deg, int n, int* bsum) {
    __shared__ int lds[256];
    int b = blockIdx.x, t = threadIdx.x;
    int i = b * 256 + t;
    lds[t] = (i < n) ? deg[i] + 1 : 0;
    __syncthreads();
    for (int off = 128; off >= 1; off >>= 1) {
        if (t < off) lds[t] += lds[t + off];
        __syncthreads();
    }
    if (t == 0) bsum[b] = lds[0];
}

// fused: per-block parallel reduce of bsum[0..b) + local scan -> ptr/cur
__global__ void k_mkptr(const int* __restrict__ deg, const int* __restrict__ bsum,
                        int n, int* ptr, int* cur) {
    __shared__ int lds[256];
    __shared__ int base_s;
    int b = blockIdx.x, t = threadIdx.x;
    int p = 0;
    for (int i = t; i < b; i += 256) p += bsum[i];
    lds[t] = p;
    __syncthreads();
    for (int off = 128; off >= 1; off >>= 1) {
        if (t < off) lds[t] += lds[t + off];
        __syncthreads();
    }
    if (t == 0) base_s = lds[0];
    __syncthreads();
    int i = b * 256 + t;
    int v = (i < n) ? deg[i] + 1 : 0;   // +1 self-loop
    lds[t] = v;
    __syncthreads();
    for (int off = 1; off < 256; off <<= 1) {
        int u = (t >= off) ? lds[t - off] : 0;
        __syncthreads();
        lds[t] += u;
        __syncthreads();
    }
    int excl = lds[t] - v + base_s;
    if (i < n) {
        ptr[i] = excl;
        cur[i] = excl;
        if (i == n - 1) ptr[n] = excl + v;
    }
}

// scatter, 8 independent atomic chains per thread (latency hiding)
#define SU 8
__global__ void k_scatter(const int* __restrict__ srcE, const int* __restrict__ dstE,
                          int E, int n, int* cur, int* __restrict__ srcs) {
    int tid = blockIdx.x * 256 + threadIdx.x;
    int stride = gridDim.x * 256;
    int tot = E + n;
    int s[SU], d[SU], pos[SU];
    bool v[SU];
#pragma unroll
    for (int j = 0; j < SU; ++j) {
        int i = tid + j * stride;
        v[j] = i < tot;
        s[j] = 0; d[j] = 0;
        if (v[j]) {
            if (i < E) { s[j] = srcE[i]; d[j] = dstE[i]; }
            else       { s[j] = d[j] = i - E; }          // self-loop
        }
    }
#pragma unroll
    for (int j = 0; j < SU; ++j)
        if (v[j]) pos[j] = atomicAdd(&cur[d[j]], 1);
#pragma unroll
    for (int j = 0; j < SU; ++j)
        if (v[j]) srcs[pos[j]] = s[j];
}

// ---------------- MFMA prep: W1 -> B frags (hi+lo) ----
// B frag: lane holds B[k=(lane>>4)*8+j][ncol=lane&15], index=((ntile*4+kstep)*64+lane)*8
__global__ __launch_bounds__(256)
void k_prepw(const float* __restrict__ W1,
             ushort* __restrict__ Wb_hi, ushort* __restrict__ Wb_lo) {
    int g = blockIdx.x * 256 + threadIdx.x;        // 16*256 = 4096 threads
    int lane = g & 63;
    int step = (g >> 6) & 3;
    int tile = g >> 8;
    int ncol = tile * 16 + (lane & 15);
    int k0 = step * 32 + (lane >> 4) * 8;
    uint4 ohi, olo;
    float f[8];
#pragma unroll
    for (int j = 0; j < 8; ++j) f[j] = W1[(size_t)(k0 + j) * HC + ncol];
    split2(f[0], f[1], ohi.x, olo.x);
    split2(f[2], f[3], ohi.y, olo.y);
    split2(f[4], f[5], ohi.z, olo.z);
    split2(f[6], f[7], ohi.w, olo.w);
    *(uint4*)(Wb_hi + (size_t)g * 8) = ohi;
    *(uint4*)(Wb_lo + (size_t)g * 8) = olo;
}

// ---------------- GEMM1 (MFMA, split-bf16): h1 = x @ W1, fp8 h1 out ----------------
// x staged in LDS (f32), A frags built in-register (hi/lo split); 3-pass MFMA:
// x_hi@W_hi + x_lo@W_hi + x_hi@W_lo. Attention dots from f32 acc (16-lane
// butterfly). fp8 C-repack buffer ALIASES the x LDS (barrier-separated).
__global__ __launch_bounds__(256)
void k_gemm1(const float* __restrict__ x,
             const ushort* __restrict__ Wb_hi, const ushort* __restrict__ Wb_lo,
             const float* __restrict__ attS, const float* __restrict__ attD,
             int n, uchar* __restrict__ h1f8,
             float* __restrict__ a1s, float* __restrict__ a1d) {
    __shared__ float Xs[64 * 132];      // 33.8 KB; later aliased as Cs[64][272]B (17.4 KB)
    __shared__ float AttS[HC], AttD[HC];
    int t = threadIdx.x;
    int lane = t & 63;
    int w = t >> 6;
    int n0 = blockIdx.x * 64;

    AttS[t] = attS[t];
    AttD[t] = attD[t];

    // stage x: 64 nodes x 128 feats = 2048 float4, 8/thread, coalesced
#pragma unroll
    for (int j = 0; j < 8; ++j) {
        int f4 = t + j * 256;
        int node = f4 >> 5;
        int k4 = (f4 & 31) * 4;
        int gn = n0 + node;
        float4 v = make_float4(0.f, 0.f, 0.f, 0.f);
        if (gn < n) v = *(const float4*)(x + (size_t)gn * NFEAT + k4);
        *(float4*)(Xs + node * 132 + k4) = v;
    }
    __syncthreads();

    // build A frags (hi/lo) in registers: A[m=lane&15][k=(lane>>4)*8+j]
    int m = lane & 15;
    int koff = (lane >> 4) * 8;
    bf16x8 Ahf[4], Alf[4];
#pragma unroll
    for (int ks = 0; ks < 4; ++ks) {
        const float* xp = Xs + (w * 16 + m) * 132 + ks * 32 + koff;
        float4 v0 = *(const float4*)(xp);
        float4 v1 = *(const float4*)(xp + 4);
        U8 ah, al;
        split2(v0.x, v0.y, ah.u.x, al.u.x);
        split2(v0.z, v0.w, ah.u.y, al.u.y);
        split2(v1.x, v1.y, ah.u.z, al.u.z);
        split2(v1.z, v1.w, ah.u.w, al.u.w);
        Ahf[ks] = ah.v;
        Alf[ks] = al.v;
    }
    __syncthreads();                    // all waves done reading Xs before Cs alias

    f32x4 acc[16];
#pragma unroll
    for (int i = 0; i < 16; ++i) acc[i] = (f32x4){0.f, 0.f, 0.f, 0.f};

    const bf16x8* Bh = (const bf16x8*)Wb_hi;
    const bf16x8* Bl = (const bf16x8*)Wb_lo;
#pragma unroll
    for (int ks = 0; ks < 4; ++ks) {
#pragma unroll
        for (int nt = 0; nt < 16; ++nt) {
            bf16x8 bh = Bh[(size_t)(nt * 4 + ks) * 64 + lane];
            bf16x8 bl = Bl[(size_t)(nt * 4 + ks) * 64 + lane];
            acc[nt] = __builtin_amdgcn_mfma_f32_16x16x32_bf16(Ahf[ks], bh, acc[nt], 0, 0, 0);
            acc[nt] = __builtin_amdgcn_mfma_f32_16x16x32_bf16(Alf[ks], bh, acc[nt], 0, 0, 0);
            acc[nt] = __builtin_amdgcn_mfma_f32_16x16x32_bf16(Ahf[ks], bl, acc[nt], 0, 0, 0);
        }
    }

    // C layout: col = nt*16 + (lane&15), row = (lane>>4)*4 + reg  [m89-verified]
    int cc = lane & 15;
    int r0 = (lane >> 4) * 4;

    // attention dots from f32 acc: head h = cols h*32..h*32+31 = nt 2h, 2h+1
#pragma unroll
    for (int h = 0; h < HEADS; ++h) {
        float sS0 = AttS[h * 32 + cc],      sS1 = AttS[h * 32 + 16 + cc];
        float sD0 = AttD[h * 32 + cc],      sD1 = AttD[h * 32 + 16 + cc];
#pragma unroll
        for (int r = 0; r < 4; ++r) {
            float ps = acc[2 * h][r] * sS0 + acc[2 * h + 1][r] * sS1;
            float pd = acc[2 * h][r] * sD0 + acc[2 * h + 1][r] * sD1;
#pragma unroll
            for (int msk = 1; msk < 16; msk <<= 1) {
                ps += __shfl_xor(ps, msk, 64);
                pd += __shfl_xor(pd, msk, 64);
            }
            if (cc == 0) {
                int gn = n0 + w * 16 + r0 + r;
                if (gn < n) {
                    a1s[(size_t)gn * HEADS + h] = ps;
                    a1d[(size_t)gn * HEADS + h] = pd;
                }
            }
        }
    }

    // fp8 repack into Cs (aliased on Xs): Cs[node_local][272]
    uchar* CsB = (uchar*)Xs;
#pragma unroll
    for (int nt = 0; nt < 16; ++nt) {
#pragma unroll
        for (int r = 0; r < 4; ++r)
            CsB[(w * 16 + r0 + r) * 272 + nt * 16 + cc] = f2fp8(acc[nt][r]);
    }
    __syncthreads();

    // coalesced readback: thread t -> node = t>>2, 64-byte chunk q = t&3
    int node_local = t >> 2;
    int q = t & 3;
    int gn = n0 + node_local;
    if (gn < n) {
        const uchar* crow = CsB + node_local * 272 + q * 64;
        uchar* hp = h1f8 + (size_t)gn * HC + q * 64;
#pragma unroll
        for (int i = 0; i < 4; ++i)
            *(uint4*)(hp + i * 16) = *(const uint4*)(crow + i * 16);
    }
}

// ---------------- Layer-1 aggregation: one wave per dst node, online softmax ----------------
// fp8 h1 gather (256B/edge), 8-wide unroll + masked tail, scalarized edge indices.
__global__ __launch_bounds__(256)
void k_agg1(const uint* __restrict__ h1u, const float* __restrict__ a1s,
            const float* __restrict__ a1d, const float* __restrict__ b1,
            const int* __restrict__ ptr, const int* __restrict__ srcs,
            int n, ushort* __restrict__ hgb) {
    int wid = blockIdx.x * 4 + (threadIdx.x >> 6);
    if (wid >= n) return;
    int lane = threadIdx.x & 63;
    int h = lane >> 3;
    float adn = a1d[wid * HEADS + h];
    int beg = __builtin_amdgcn_readfirstlane(ptr[wid]);
    int end = __builtin_amdgcn_readfirstlane(ptr[wid + 1]);
    float m = -INFINITY, s = 0.f;
    float4 acc = make_float4(0.f, 0.f, 0.f, 0.f);

    int i = beg;
    for (; i + 8 <= end; i += 8) {
        int sn[8];
#pragma unroll
        for (int j = 0; j < 8; ++j) sn[j] = __builtin_amdgcn_readfirstlane(srcs[i + j]);
        float av[8];
        uint hv[8];
#pragma unroll
        for (int j = 0; j < 8; ++j) av[j] = a1s[sn[j] * HEADS + h];
#pragma unroll
        for (int j = 0; j < 8; ++j)
            hv[j] = h1u[(size_t)sn[j] * 64 + lane];
        float e[8];
#pragma unroll
        for (int j = 0; j < 8; ++j) {
            float a = av[j] + adn;
            e[j] = (a > 0.f) ? a : 0.2f * a;
        }
        float mn = m;
#pragma unroll
        for (int j = 0; j < 8; ++j) mn = fmaxf(mn, e[j]);
        float corr = __expf(m - mn);
        float p[8];
#pragma unroll
        for (int j = 0; j < 8; ++j) p[j] = __expf(e[j] - mn);
        float ps = 0.f;
#pragma unroll
        for (int j = 0; j < 8; ++j) ps += p[j];
        s = s * corr + ps;
        float cx = acc.x * corr, cy = acc.y * corr, cz = acc.z * corr, cw = acc.w * corr;
#pragma unroll
        for (int j = 0; j < 8; ++j) {
            auto lo = __builtin_amdgcn_cvt_pk_f32_fp8((int)hv[j], false);
            auto hi = __builtin_amdgcn_cvt_pk_f32_fp8((int)hv[j], true);
            cx += p[j] * lo[0];
            cy += p[j] * lo[1];
            cz += p[j] * hi[0];
            cw += p[j] * hi[1];
        }
        acc = make_float4(cx, cy, cz, cw);
        m = mn;
    }
    if (i < end) {                       // masked final iteration
        int sn[8];
        bool val[8];
#pragma unroll
        for (int j = 0; j < 8; ++j) {
            int idx = i + j;
            val[j] = idx < end;
            sn[j] = __builtin_amdgcn_readfirstlane(srcs[val[j] ? idx : end - 1]);
        }
        float av[8];
        uint hv[8];
#pragma unroll
        for (int j = 0; j < 8; ++j) av[j] = a1s[sn[j] * HEADS + h];
#pragma unroll
        for (int j = 0; j < 8; ++j)
            hv[j] = h1u[(size_t)sn[j] * 64 + lane];
        float e[8];
#pragma unroll
        for (int j = 0; j < 8; ++j) {
            float a = av[j] + adn;
            e[j] = val[j] ? ((a > 0.f) ? a : 0.2f * a) : -INFINITY;
        }
        float mn = m;
#pragma unroll
        for (int j = 0; j < 8; ++j) mn = fmaxf(mn, e[j]);
        float corr = __expf(m - mn);
        float p[8];
#pragma unroll
        for (int j = 0; j < 8; ++j) p[j] = __expf(e[j] - mn);
        float ps = 0.f;
#pragma unroll
        for (int j = 0; j < 8; ++j) ps += p[j];
        s = s * corr + ps;
        float cx = acc.x * corr, cy = acc.y * corr, cz = acc.z * corr, cw = acc.w * corr;
#pragma unroll
        for (int j = 0; j < 8; ++j) {
            auto lo = __builtin_amdgcn_cvt_pk_f32_fp8((int)hv[j], false);
            auto hi = __builtin_amdgcn_cvt_pk_f32_fp8((int)hv[j], true);
            cx += p[j] * lo[0];
            cy += p[j] * lo[1];
            cz += p[j] * hi[0];
            cw += p[j] * hi[1];
        }
        acc = make_float4(cx, cy, cz, cw);
        m = mn;
    }

    float inv = 1.f / (s + 1e-16f);
    float4 bv = *(const float4*)(b1 + lane * 4);
    float4 o;
    o.x = acc.x * inv + bv.x;
    o.y = acc.y * inv + bv.y;
    o.z = acc.z * inv + bv.z;
    o.w = acc.w * inv + bv.w;
    o.x = (o.x > 0.f) ? o.x : (__expf(o.x) - 1.f);
    o.y = (o.y > 0.f) ? o.y : (__expf(o.y) - 1.f);
    o.z = (o.z > 0.f) ? o.z : (__expf(o.z) - 1.f);
    o.w = (o.w > 0.f) ? o.w : (__expf(o.w) - 1.f);
    uint2 ov;
    ov.x = packbf(o.x, o.y);
    ov.y = packbf(o.z, o.w);
    *(uint2*)(hgb + (size_t)wid * HC + lane * 4) = ov;
}

// ---------------- GEMM2: h2 = hg @ W2  [N,256]x[256,40], bf16 in/out ----------------
__global__ __launch_bounds__(256)
void k_gemm2(const ushort* __restrict__ hgb, const float* __restrict__ W2,
             const float* __restrict__ a2sw, const float* __restrict__ a2dw,
             int n, ushort* __restrict__ h2b,
             float* __restrict__ a2s, float* __restrict__ a2d) {
    __shared__ uint Xs[128 * 65];       // 33.3 KB, [k2][node]
    __shared__ float Ps[4][64];
    __shared__ float Pd[4][64];
    int t = threadIdx.x;
    int lane = t & 63;
    int w = t >> 6;
    int n0 = blockIdx.x * 64;

#pragma unroll
    for (int j = 0; j < 8; ++j) {
        int g = t + j * 256;
        int node = g >> 5;
        int k2b = (g & 31) * 4;
        int gn = n0 + node;
        uint4 v = make_uint4(0u, 0u, 0u, 0u);
        if (gn < n) v = *(const uint4*)(hgb + (size_t)gn * HC + k2b * 2);
        Xs[(k2b + 0) * 65 + node] = v.x;
        Xs[(k2b + 1) * 65 + node] = v.y;
        Xs[(k2b + 2) * 65 + node] = v.z;
        Xs[(k2b + 3) * 65 + node] = v.w;
    }
    __syncthreads();

    int wu = __builtin_amdgcn_readfirstlane(w);
    const float* Wc = W2 + wu * 10;

    float acc[10];
#pragma unroll
    for (int c = 0; c < 10; ++c) acc[c] = 0.f;

#pragma unroll 2
    for (int k2 = 0; k2 < 128; ++k2) {
        uint xp = Xs[k2 * 65 + lane];
        float x0 = bflo(xp), x1 = bfhi(xp);
        const float* Wr0 = Wc + (size_t)(2 * k2) * NCLASS;
        const float* Wr1 = Wr0 + NCLASS;
#pragma unroll
        for (int c = 0; c < 10; ++c) {
            acc[c] += x0 * Wr0[c] + x1 * Wr1[c];
        }
    }

    int gn = n0 + lane;
    float as = 0.f, ad = 0.f;
#pragma unroll
    for (int c = 0; c < 10; ++c) {
        as += acc[c] * a2sw[wu * 10 + c];
        ad += acc[c] * a2dw[wu * 10 + c];
    }
    Ps[w][lane] = as;
    Pd[w][lane] = ad;
    if (gn < n) {
        uint* hp = (uint*)(h2b + (size_t)gn * NCLASS + wu * 10);
#pragma unroll
        for (int q = 0; q < 5; ++q)
            hp[q] = packbf(acc[q * 2], acc[q * 2 + 1]);
    }
    __syncthreads();
    if (w == 0 && gn < n) {
        a2s[gn] = Ps[0][lane] + Ps[1][lane] + Ps[2][lane] + Ps[3][lane];
        a2d[gn] = Pd[0][lane] + Pd[1][lane] + Pd[2][lane] + Pd[3][lane];
    }
}

// ---------------- Layer-2 aggregation + bias + log_softmax ----------------
__global__ __launch_bounds__(256)
void k_agg2(const ushort* __restrict__ h2b, const float* __restrict__ a2s,
            const float* __restrict__ a2d, const float* __restrict__ b2,
            const int* __restrict__ ptr, const int* __restrict__ srcs,
            int n, float* __restrict__ out) {
    int wid = blockIdx.x * 4 + (threadIdx.x >> 6);
    if (wid >= n) return;
    int lane = threadIdx.x & 63;
    bool live = lane < NCLASS;
    int col = live ? lane : 0;
    float adn = a2d[wid];
    int beg = __builtin_amdgcn_readfirstlane(ptr[wid]);
    int end = __builtin_amdgcn_readfirstlane(ptr[wid + 1]);
    float m = -INFINITY, s = 0.f, acc = 0.f;

    int i = beg;
    for (; i + 8 <= end; i += 8) {
        int sn[8];
#pragma unroll
        for (int j = 0; j < 8; ++j) sn[j] = __builtin_amdgcn_readfirstlane(srcs[i + j]);
        float av[8];
        float hv[8];
#pragma unroll
        for (int j = 0; j < 8; ++j) av[j] = a2s[sn[j]];
#pragma unroll
        for (int j = 0; j < 8; ++j)
            hv[j] = __uint_as_float((uint)h2b[(size_t)sn[j] * NCLASS + col] << 16);
        float e[8];
#pragma unroll
        for (int j = 0; j < 8; ++j) {
            float a = av[j] + adn;
            e[j] = (a > 0.f) ? a : 0.2f * a;
        }
        float mn = m;
#pragma unroll
        for (int j = 0; j < 8; ++j) mn = fmaxf(mn, e[j]);
        float corr = __expf(m - mn);
        float p[8];
#pragma unroll
        for (int j = 0; j < 8; ++j) p[j] = __expf(e[j] - mn);
        float ps = 0.f, pa = 0.f;
#pragma unroll
        for (int j = 0; j < 8; ++j) { ps += p[j]; pa += p[j] * hv[j]; }
        s = s * corr + ps;
        acc = acc * corr + pa;
        m = mn;
    }
    if (i < end) {
        int sn[8];
        bool val[8];
#pragma unroll
        for (int j = 0; j < 8; ++j) {
            int idx = i + j;
            val[j] = idx < end;
            sn[j] = __builtin_amdgcn_readfirstlane(srcs[val[j] ? idx : end - 1]);
        }
        float av[8];
        float hv[8];
#pragma unroll
        for (int j = 0; j < 8; ++j) av[j] = a2s[sn[j]];
#pragma unroll
        for (int j = 0; j < 8; ++j)
            hv[j] = __uint_as_float((uint)h2b[(size_t)sn[j] * NCLASS + col] << 16);
        float e[8];
#pragma unroll
        for (int j = 0; j < 8; ++j) {
            float a = av[j] + adn;
            e[j] = val[j] ? ((a > 0.f) ? a : 0.2f * a) : -INFINITY;
        }
        float mn = m;
#pragma unroll
        for (int j = 0; j < 8; ++j) mn = fmaxf(mn, e[j]);
        float corr = __expf(m - mn);
        float p[8];
#pragma unroll
        for (int j = 0; j < 8; ++j) p[j] = __expf(e[j] - mn);
        float ps = 0.f, pa = 0.f;
#pragma unroll
        for (int j = 0; j < 8; ++j) { ps += p[j]; pa += p[j] * hv[j]; }
        s = s * corr + ps;
        acc = acc * corr + pa;
        m = mn;
    }

    float val0 = acc / (s + 1e-16f) + (live ? b2[lane] : 0.f);
    float vmax = live ? val0 : -INFINITY;
#pragma unroll
    for (int msk = 1; msk < 64; msk <<= 1) vmax = fmaxf(vmax, __shfl_xor(vmax, msk, 64));
    float ex = live ? __expf(val0 - vmax) : 0.f;
#pragma unroll
    for (int msk = 1; msk < 64; msk <<= 1) ex += __shfl_xor(ex, msk, 64);
    float res = val0 - vmax - __logf(ex);
    if (live) out[(size_t)wid * NCLASS + lane] = res;
}

// ---------------- launch ----------------
extern "C" void kernel_launch(void* const* d_in, const int* in_sizes, int n_in,
                              void* d_out, int out_size, void* d_ws, size_t ws_size,
                              hipStream_t stream) {
    const float* x    = (const float*)d_in[0];
    const int*   ei   = (const int*)  d_in[1];
    const float* W1   = (const float*)d_in[2];
    const float* attS = (const float*)d_in[3];
    const float* attD = (const float*)d_in[4];
    const float* b1   = (const float*)d_in[5];
    const float* W2   = (const float*)d_in[6];
    const float* a2sw = (const float*)d_in[7];
    const float* a2dw = (const float*)d_in[8];
    const float* b2   = (const float*)d_in[9];

    int n = in_sizes[0] / NFEAT;
    int E = in_sizes[1] / 2;
    const int* srcE = ei;
    const int* dstE = ei + E;
    int nb = (n + 255) / 256;
    int mblocks = (n + 63) / 64;              // gemm1 blocks (64 nodes each)

    char* p = (char*)d_ws;
    auto alloc = [&](size_t bytes) {
        char* r = p;
        p += (bytes + 255) & ~(size_t)255;
        return r;
    };
    uchar*  h1f8 = (uchar*)alloc((size_t)n * HC);
    ushort* hgb  = (ushort*)alloc((size_t)n * HC * 2);
    ushort* h2b  = (ushort*)alloc((size_t)n * NCLASS * 2);
    ushort* Wb_h = (ushort*)alloc((size_t)16 * 4 * 64 * 8 * 2);
    ushort* Wb_l = (ushort*)alloc((size_t)16 * 4 * 64 * 8 * 2);
    float* a1s = (float*)alloc((size_t)n * HEADS * 4);
    float* a1d = (float*)alloc((size_t)n * HEADS * 4);
    float* a2s = (float*)alloc((size_t)n * 4);
    float* a2d = (float*)alloc((size_t)n * 4);
    int* deg  = (int*)alloc((size_t)n * 4);
    int* bsum = (int*)alloc((size_t)nb * 4);
    int* ptr  = (int*)alloc((size_t)(n + 1) * 4);
    int* cur  = (int*)alloc((size_t)n * 4);
    int* srcs = (int*)alloc((size_t)(E + n) * 4);

    int tot = E + n;
    hipMemsetAsync(deg, 0, (size_t)n * 4, stream);
    k_hist<<<(E + 256 * HU - 1) / (256 * HU), 256, 0, stream>>>(dstE, E, deg);
    k_blocksum<<<nb, 256, 0, stream>>>(deg, n, bsum);
    k_mkptr<<<nb, 256, 0, stream>>>(deg, bsum, n, ptr, cur);
    k_scatter<<<(tot + 256 * SU - 1) / (256 * SU), 256, 0, stream>>>(srcE, dstE, E, n, cur, srcs);

    k_prepw<<<16, 256, 0, stream>>>(W1, Wb_h, Wb_l);
    k_gemm1<<<mblocks, 256, 0, stream>>>(x, Wb_h, Wb_l, attS, attD, n, h1f8, a1s, a1d);
    k_agg1<<<(n + 3) / 4, 256, 0, stream>>>((const uint*)h1f8, a1s, a1d, b1,
                                            ptr, srcs, n, hgb);
    k_gemm2<<<(n + 63) / 64, 256, 0, stream>>>(hgb, W2, a2sw, a2dw, n, h2b, a2s, a2d);
    k_agg2<<<(n + 3) / 4, 256, 0, stream>>>(h2b, a2s, a2d, b2, ptr, srcs, n, (float*)d_out);
}

// Round 10
// 334.218 us; speedup vs baseline: 1.9932x; 1.0065x over previous
//
#include <hip/hip_runtime.h>
#include <math.h>

#define NFEAT  128
#define HC     256     // HEADS*NHID
#define HEADS  8
#define NHID   32
#define NCLASS 40

typedef unsigned int  uint;
typedef unsigned short ushort;
typedef unsigned char uchar;

typedef __attribute__((ext_vector_type(8))) short bf16x8;
typedef __attribute__((ext_vector_type(4))) float f32x4;

union U8 { uint4 u; bf16x8 v; };

// bf16 helpers (RNE pack, cheap unpack)
__device__ __forceinline__ uint f2bf1(float f) {
    uint b = __float_as_uint(f);
    b += 0x7FFFu + ((b >> 16) & 1u);
    return b >> 16;
}
__device__ __forceinline__ uint packbf(float lo, float hi) {
    return f2bf1(lo) | (f2bf1(hi) << 16);
}
__device__ __forceinline__ float bflo(uint u) { return __uint_as_float(u << 16); }
__device__ __forceinline__ float bfhi(uint u) { return __uint_as_float(u & 0xFFFF0000u); }

// fp8 e4m3 (OCP) via HW converts
__device__ __forceinline__ uchar f2fp8(float v) {
    return (uchar)(__builtin_amdgcn_cvt_pk_fp8_f32(v, v, 0, false) & 0xFF);
}

// ---------------- CSR build (dst-sorted, shared by both layers) ----------------

#define HU 4
__global__ void k_hist(const int* __restrict__ dst, int E, int* deg) {
    int tid = blockIdx.x * 256 + threadIdx.x;
    int stride = gridDim.x * 256;
#pragma unroll
    for (int j = 0; j < HU; ++j) {
        int i = tid + j * stride;
        if (i < E) atomicAdd(&deg[dst[i]], 1);
    }
}

// per-block sums of (deg+1)  [+1 = self-loop]
__global__ void k_blocksum(const int* __restrict__ deg, int n, int* bsum) {
    __shared__ int lds[256];
    int b = blockIdx.x, t = threadIdx.x;
    int i = b * 256 + t;
    lds[t] = (i < n) ? deg[i] + 1 : 0;
    __syncthreads();
    for (int off = 128; off >= 1; off >>= 1) {
        if (t < off) lds[t] += lds[t + off];
        __syncthreads();
    }
    if (t == 0) bsum[b] = lds[0];
}

// fused: per-block parallel reduce of bsum[0..b) + local scan -> ptr/cur
__global__ void k_mkptr(const int* __restrict__ deg, const int* __restrict__ bsum,
                        int n, int* ptr, int* cur) {
    __shared__ int lds[256];
    __shared__ int base_s;
    int b = blockIdx.x, t = threadIdx.x;
    int p = 0;
    for (int i = t; i < b; i += 256) p += bsum[i];
    lds[t] = p;
    __syncthreads();
    for (int off = 128; off >= 1; off >>= 1) {
        if (t < off) lds[t] += lds[t + off];
        __syncthreads();
    }
    if (t == 0) base_s = lds[0];
    __syncthreads();
    int i = b * 256 + t;
    int v = (i < n) ? deg[i] + 1 : 0;   // +1 self-loop
    lds[t] = v;
    __syncthreads();
    for (int off = 1; off < 256; off <<= 1) {
        int u = (t >= off) ? lds[t - off] : 0;
        __syncthreads();
        lds[t] += u;
        __syncthreads();
    }
    int excl = lds[t] - v + base_s;
    if (i < n) {
        ptr[i] = excl;
        cur[i] = excl;
        if (i == n - 1) ptr[n] = excl + v;
    }
}

// scatter, 8 independent atomic chains per thread (latency hiding)
#define SU 8
__global__ void k_scatter(const int* __restrict__ srcE, const int* __restrict__ dstE,
                          int E, int n, int* cur, int* __restrict__ srcs) {
    int tid = blockIdx.x * 256 + threadIdx.x;
    int stride = gridDim.x * 256;
    int tot = E + n;
    int s[SU], d[SU], pos[SU];
    bool v[SU];
#pragma unroll
    for (int j = 0; j < SU; ++j) {
        int i = tid + j * stride;
        v[j] = i < tot;
        s[j] = 0; d[j] = 0;
        if (v[j]) {
            if (i < E) { s[j] = srcE[i]; d[j] = dstE[i]; }
            else       { s[j] = d[j] = i - E; }          // self-loop
        }
    }
#pragma unroll
    for (int j = 0; j < SU; ++j)
        if (v[j]) pos[j] = atomicAdd(&cur[d[j]], 1);
#pragma unroll
    for (int j = 0; j < SU; ++j)
        if (v[j]) srcs[pos[j]] = s[j];
}

// ---------------- MFMA prep: W1 -> B frags (bf16) ----
// B frag: lane holds B[k=(lane>>4)*8+j][ncol=lane&15], index=((ntile*4+kstep)*64+lane)*8
__global__ __launch_bounds__(256)
void k_prepw(const float* __restrict__ W1, ushort* __restrict__ Wb) {
    int g = blockIdx.x * 256 + threadIdx.x;        // 16*256 = 4096 threads
    int lane = g & 63;
    int step = (g >> 6) & 3;
    int tile = g >> 8;
    int ncol = tile * 16 + (lane & 15);
    int k0 = step * 32 + (lane >> 4) * 8;
    float f[8];
#pragma unroll
    for (int j = 0; j < 8; ++j) f[j] = W1[(size_t)(k0 + j) * HC + ncol];
    uint4 o;
    o.x = packbf(f[0], f[1]);
    o.y = packbf(f[2], f[3]);
    o.z = packbf(f[4], f[5]);
    o.w = packbf(f[6], f[7]);
    *(uint4*)(Wb + (size_t)g * 8) = o;
}

// ---------------- GEMM1 (MFMA bf16): h1 = x @ W1, fp8 h1 out ----------------
// x staged in LDS as PACKED bf16 (64 rows x 136 ushorts = 272B rows, 17.4 KB);
// A frags = single ds_read_b128. Single-pass bf16 MFMA (fp8 h1 storage
// dominates error budget; split-bf16 correction was over-engineering).
// Attention dots from f32 acc (16-lane butterfly). fp8 C-repack ALIASES Xs.
__global__ __launch_bounds__(256)
void k_gemm1(const float* __restrict__ x,
             const ushort* __restrict__ Wb,
             const float* __restrict__ attS, const float* __restrict__ attD,
             int n, uchar* __restrict__ h1f8,
             float* __restrict__ a1s, float* __restrict__ a1d) {
    __shared__ uint Xs[64 * 68];        // 17.4 KB; aliased as Cs[64][272]B later
    __shared__ float AttS[HC], AttD[HC];
    int t = threadIdx.x;
    int lane = t & 63;
    int w = t >> 6;
    int n0 = blockIdx.x * 64;

    AttS[t] = attS[t];
    AttD[t] = attD[t];

    // stage x -> packed bf16: 64 nodes x 32 float4, 8/thread, coalesced
#pragma unroll
    for (int j = 0; j < 8; ++j) {
        int f4 = t + j * 256;
        int node = f4 >> 5;
        int k4 = (f4 & 31) * 4;            // float index within row
        int gn = n0 + node;
        float4 v = make_float4(0.f, 0.f, 0.f, 0.f);
        if (gn < n) v = *(const float4*)(x + (size_t)gn * NFEAT + k4);
        uint2 pk;
        pk.x = packbf(v.x, v.y);
        pk.y = packbf(v.z, v.w);
        *(uint2*)(Xs + node * 68 + (k4 >> 1)) = pk;
    }
    __syncthreads();

    // A frags: lane holds A[m=lane&15][k=(lane>>4)*8+j] -> one b128 per kstep
    int m = lane & 15;
    int q4 = (lane >> 4) * 4;              // uint offset of 8-bf16 group
    bf16x8 Af[4];
#pragma unroll
    for (int ks = 0; ks < 4; ++ks) {
        U8 a;
        a.u = *(const uint4*)(Xs + (w * 16 + m) * 68 + ks * 16 + q4);
        Af[ks] = a.v;
    }
    __syncthreads();                       // done reading Xs before Cs alias

    f32x4 acc[16];
#pragma unroll
    for (int i = 0; i < 16; ++i) acc[i] = (f32x4){0.f, 0.f, 0.f, 0.f};

    const bf16x8* Bf = (const bf16x8*)Wb;
#pragma unroll
    for (int ks = 0; ks < 4; ++ks) {
#pragma unroll
        for (int nt = 0; nt < 16; ++nt) {
            bf16x8 bv = Bf[(size_t)(nt * 4 + ks) * 64 + lane];
            acc[nt] = __builtin_amdgcn_mfma_f32_16x16x32_bf16(Af[ks], bv, acc[nt], 0, 0, 0);
        }
    }

    // C layout: col = nt*16 + (lane&15), row = (lane>>4)*4 + reg  [m89-verified]
    int cc = lane & 15;
    int r0 = (lane >> 4) * 4;

    // attention dots from f32 acc: head h = cols h*32..h*32+31 = nt 2h, 2h+1
#pragma unroll
    for (int h = 0; h < HEADS; ++h) {
        float sS0 = AttS[h * 32 + cc],      sS1 = AttS[h * 32 + 16 + cc];
        float sD0 = AttD[h * 32 + cc],      sD1 = AttD[h * 32 + 16 + cc];
#pragma unroll
        for (int r = 0; r < 4; ++r) {
            float ps = acc[2 * h][r] * sS0 + acc[2 * h + 1][r] * sS1;
            float pd = acc[2 * h][r] * sD0 + acc[2 * h + 1][r] * sD1;
#pragma unroll
            for (int msk = 1; msk < 16; msk <<= 1) {
                ps += __shfl_xor(ps, msk, 64);
                pd += __shfl_xor(pd, msk, 64);
            }
            if (cc == 0) {
                int gn = n0 + w * 16 + r0 + r;
                if (gn < n) {
                    a1s[(size_t)gn * HEADS + h] = ps;
                    a1d[(size_t)gn * HEADS + h] = pd;
                }
            }
        }
    }

    // fp8 repack into Cs (aliased on Xs): row stride 272 B (same as Xs rows)
    uchar* CsB = (uchar*)Xs;
#pragma unroll
    for (int nt = 0; nt < 16; ++nt) {
#pragma unroll
        for (int r = 0; r < 4; ++r)
            CsB[(w * 16 + r0 + r) * 272 + nt * 16 + cc] = f2fp8(acc[nt][r]);
    }
    __syncthreads();

    // coalesced readback: thread t -> node = t>>2, 64-byte chunk q = t&3
    int node_local = t >> 2;
    int q = t & 3;
    int gn = n0 + node_local;
    if (gn < n) {
        const uchar* crow = CsB + node_local * 272 + q * 64;
        uchar* hp = h1f8 + (size_t)gn * HC + q * 64;
#pragma unroll
        for (int i = 0; i < 4; ++i)
            *(uint4*)(hp + i * 16) = *(const uint4*)(crow + i * 16);
    }
}

// ---------------- Layer-1 aggregation: one wave per dst node, online softmax ----------------
// fp8 h1 gather (256B/edge), 8-wide unroll + masked tail, scalarized edge indices.
__global__ __launch_bounds__(256)
void k_agg1(const uint* __restrict__ h1u, const float* __restrict__ a1s,
            const float* __restrict__ a1d, const float* __restrict__ b1,
            const int* __restrict__ ptr, const int* __restrict__ srcs,
            int n, ushort* __restrict__ hgb) {
    int wid = blockIdx.x * 4 + (threadIdx.x >> 6);
    if (wid >= n) return;
    int lane = threadIdx.x & 63;
    int h = lane >> 3;
    float adn = a1d[wid * HEADS + h];
    int beg = __builtin_amdgcn_readfirstlane(ptr[wid]);
    int end = __builtin_amdgcn_readfirstlane(ptr[wid + 1]);
    float m = -INFINITY, s = 0.f;
    float4 acc = make_float4(0.f, 0.f, 0.f, 0.f);

    int i = beg;
    for (; i + 8 <= end; i += 8) {
        int sn[8];
#pragma unroll
        for (int j = 0; j < 8; ++j) sn[j] = __builtin_amdgcn_readfirstlane(srcs[i + j]);
        float av[8];
        uint hv[8];
#pragma unroll
        for (int j = 0; j < 8; ++j) av[j] = a1s[sn[j] * HEADS + h];
#pragma unroll
        for (int j = 0; j < 8; ++j)
            hv[j] = h1u[(size_t)sn[j] * 64 + lane];
        float e[8];
#pragma unroll
        for (int j = 0; j < 8; ++j) {
            float a = av[j] + adn;
            e[j] = (a > 0.f) ? a : 0.2f * a;
        }
        float mn = m;
#pragma unroll
        for (int j = 0; j < 8; ++j) mn = fmaxf(mn, e[j]);
        float corr = __expf(m - mn);
        float p[8];
#pragma unroll
        for (int j = 0; j < 8; ++j) p[j] = __expf(e[j] - mn);
        float ps = 0.f;
#pragma unroll
        for (int j = 0; j < 8; ++j) ps += p[j];
        s = s * corr + ps;
        float cx = acc.x * corr, cy = acc.y * corr, cz = acc.z * corr, cw = acc.w * corr;
#pragma unroll
        for (int j = 0; j < 8; ++j) {
            auto lo = __builtin_amdgcn_cvt_pk_f32_fp8((int)hv[j], false);
            auto hi = __builtin_amdgcn_cvt_pk_f32_fp8((int)hv[j], true);
            cx += p[j] * lo[0];
            cy += p[j] * lo[1];
            cz += p[j] * hi[0];
            cw += p[j] * hi[1];
        }
        acc = make_float4(cx, cy, cz, cw);
        m = mn;
    }
    if (i < end) {                       // masked final iteration
        int sn[8];
        bool val[8];
#pragma unroll
        for (int j = 0; j < 8; ++j) {
            int idx = i + j;
            val[j] = idx < end;
            sn[j] = __builtin_amdgcn_readfirstlane(srcs[val[j] ? idx : end - 1]);
        }
        float av[8];
        uint hv[8];
#pragma unroll
        for (int j = 0; j < 8; ++j) av[j] = a1s[sn[j] * HEADS + h];
#pragma unroll
        for (int j = 0; j < 8; ++j)
            hv[j] = h1u[(size_t)sn[j] * 64 + lane];
        float e[8];
#pragma unroll
        for (int j = 0; j < 8; ++j) {
            float a = av[j] + adn;
            e[j] = val[j] ? ((a > 0.f) ? a : 0.2f * a) : -INFINITY;
        }
        float mn = m;
#pragma unroll
        for (int j = 0; j < 8; ++j) mn = fmaxf(mn, e[j]);
        float corr = __expf(m - mn);
        float p[8];
#pragma unroll
        for (int j = 0; j < 8; ++j) p[j] = __expf(e[j] - mn);
        float ps = 0.f;
#pragma unroll
        for (int j = 0; j < 8; ++j) ps += p[j];
        s = s * corr + ps;
        float cx = acc.x * corr, cy = acc.y * corr, cz = acc.z * corr, cw = acc.w * corr;
#pragma unroll
        for (int j = 0; j < 8; ++j) {
            auto lo = __builtin_amdgcn_cvt_pk_f32_fp8((int)hv[j], false);
            auto hi = __builtin_amdgcn_cvt_pk_f32_fp8((int)hv[j], true);
            cx += p[j] * lo[0];
            cy += p[j] * lo[1];
            cz += p[j] * hi[0];
            cw += p[j] * hi[1];
        }
        acc = make_float4(cx, cy, cz, cw);
        m = mn;
    }

    float inv = 1.f / (s + 1e-16f);
    float4 bv = *(const float4*)(b1 + lane * 4);
    float4 o;
    o.x = acc.x * inv + bv.x;
    o.y = acc.y * inv + bv.y;
    o.z = acc.z * inv + bv.z;
    o.w = acc.w * inv + bv.w;
    o.x = (o.x > 0.f) ? o.x : (__expf(o.x) - 1.f);
    o.y = (o.y > 0.f) ? o.y : (__expf(o.y) - 1.f);
    o.z = (o.z > 0.f) ? o.z : (__expf(o.z) - 1.f);
    o.w = (o.w > 0.f) ? o.w : (__expf(o.w) - 1.f);
    uint2 ov;
    ov.x = packbf(o.x, o.y);
    ov.y = packbf(o.z, o.w);
    *(uint2*)(hgb + (size_t)wid * HC + lane * 4) = ov;
}

// ---------------- GEMM2: h2 = hg @ W2  [N,256]x[256,40], bf16 in/out ----------------
__global__ __launch_bounds__(256)
void k_gemm2(const ushort* __restrict__ hgb, const float* __restrict__ W2,
             const float* __restrict__ a2sw, const float* __restrict__ a2dw,
             int n, ushort* __restrict__ h2b,
             float* __restrict__ a2s, float* __restrict__ a2d) {
    __shared__ uint Xs[128 * 65];       // 33.3 KB, [k2][node]
    __shared__ float Ps[4][64];
    __shared__ float Pd[4][64];
    int t = threadIdx.x;
    int lane = t & 63;
    int w = t >> 6;
    int n0 = blockIdx.x * 64;

#pragma unroll
    for (int j = 0; j < 8; ++j) {
        int g = t + j * 256;
        int node = g >> 5;
        int k2b = (g & 31) * 4;
        int gn = n0 + node;
        uint4 v = make_uint4(0u, 0u, 0u, 0u);
        if (gn < n) v = *(const uint4*)(hgb + (size_t)gn * HC + k2b * 2);
        Xs[(k2b + 0) * 65 + node] = v.x;
        Xs[(k2b + 1) * 65 + node] = v.y;
        Xs[(k2b + 2) * 65 + node] = v.z;
        Xs[(k2b + 3) * 65 + node] = v.w;
    }
    __syncthreads();

    int wu = __builtin_amdgcn_readfirstlane(w);
    const float* Wc = W2 + wu * 10;

    float acc[10];
#pragma unroll
    for (int c = 0; c < 10; ++c) acc[c] = 0.f;

#pragma unroll 2
    for (int k2 = 0; k2 < 128; ++k2) {
        uint xp = Xs[k2 * 65 + lane];
        float x0 = bflo(xp), x1 = bfhi(xp);
        const float* Wr0 = Wc + (size_t)(2 * k2) * NCLASS;
        const float* Wr1 = Wr0 + NCLASS;
#pragma unroll
        for (int c = 0; c < 10; ++c) {
            acc[c] += x0 * Wr0[c] + x1 * Wr1[c];
        }
    }

    int gn = n0 + lane;
    float as = 0.f, ad = 0.f;
#pragma unroll
    for (int c = 0; c < 10; ++c) {
        as += acc[c] * a2sw[wu * 10 + c];
        ad += acc[c] * a2dw[wu * 10 + c];
    }
    Ps[w][lane] = as;
    Pd[w][lane] = ad;
    if (gn < n) {
        uint* hp = (uint*)(h2b + (size_t)gn * NCLASS + wu * 10);
#pragma unroll
        for (int q = 0; q < 5; ++q)
            hp[q] = packbf(acc[q * 2], acc[q * 2 + 1]);
    }
    __syncthreads();
    if (w == 0 && gn < n) {
        a2s[gn] = Ps[0][lane] + Ps[1][lane] + Ps[2][lane] + Ps[3][lane];
        a2d[gn] = Pd[0][lane] + Pd[1][lane] + Pd[2][lane] + Pd[3][lane];
    }
}

// ---------------- Layer-2 aggregation + bias + log_softmax ----------------
__global__ __launch_bounds__(256)
void k_agg2(const ushort* __restrict__ h2b, const float* __restrict__ a2s,
            const float* __restrict__ a2d, const float* __restrict__ b2,
            const int* __restrict__ ptr, const int* __restrict__ srcs,
            int n, float* __restrict__ out) {
    int wid = blockIdx.x * 4 + (threadIdx.x >> 6);
    if (wid >= n) return;
    int lane = threadIdx.x & 63;
    bool live = lane < NCLASS;
    int col = live ? lane : 0;
    float adn = a2d[wid];
    int beg = __builtin_amdgcn_readfirstlane(ptr[wid]);
    int end = __builtin_amdgcn_readfirstlane(ptr[wid + 1]);
    float m = -INFINITY, s = 0.f, acc = 0.f;

    int i = beg;
    for (; i + 8 <= end; i += 8) {
        int sn[8];
#pragma unroll
        for (int j = 0; j < 8; ++j) sn[j] = __builtin_amdgcn_readfirstlane(srcs[i + j]);
        float av[8];
        float hv[8];
#pragma unroll
        for (int j = 0; j < 8; ++j) av[j] = a2s[sn[j]];
#pragma unroll
        for (int j = 0; j < 8; ++j)
            hv[j] = __uint_as_float((uint)h2b[(size_t)sn[j] * NCLASS + col] << 16);
        float e[8];
#pragma unroll
        for (int j = 0; j < 8; ++j) {
            float a = av[j] + adn;
            e[j] = (a > 0.f) ? a : 0.2f * a;
        }
        float mn = m;
#pragma unroll
        for (int j = 0; j < 8; ++j) mn = fmaxf(mn, e[j]);
        float corr = __expf(m - mn);
        float p[8];
#pragma unroll
        for (int j = 0; j < 8; ++j) p[j] = __expf(e[j] - mn);
        float ps = 0.f, pa = 0.f;
#pragma unroll
        for (int j = 0; j < 8; ++j) { ps += p[j]; pa += p[j] * hv[j]; }
        s = s * corr + ps;
        acc = acc * corr + pa;
        m = mn;
    }
    if (i < end) {
        int sn[8];
        bool val[8];
#pragma unroll
        for (int j = 0; j < 8; ++j) {
            int idx = i + j;
            val[j] = idx < end;
            sn[j] = __builtin_amdgcn_readfirstlane(srcs[val[j] ? idx : end - 1]);
        }
        float av[8];
        float hv[8];
#pragma unroll
        for (int j = 0; j < 8; ++j) av[j] = a2s[sn[j]];
#pragma unroll
        for (int j = 0; j < 8; ++j)
            hv[j] = __uint_as_float((uint)h2b[(size_t)sn[j] * NCLASS + col] << 16);
        float e[8];
#pragma unroll
        for (int j = 0; j < 8; ++j) {
            float a = av[j] + adn;
            e[j] = val[j] ? ((a > 0.f) ? a : 0.2f * a) : -INFINITY;
        }
        float mn = m;
#pragma unroll
        for (int j = 0; j < 8; ++j) mn = fmaxf(mn, e[j]);
        float corr = __expf(m - mn);
        float p[8];
#pragma unroll
        for (int j = 0; j < 8; ++j) p[j] = __expf(e[j] - mn);
        float ps = 0.f, pa = 0.f;
#pragma unroll
        for (int j = 0; j < 8; ++j) { ps += p[j]; pa += p[j] * hv[j]; }
        s = s * corr + ps;
        acc = acc * corr + pa;
        m = mn;
    }

    float val0 = acc / (s + 1e-16f) + (live ? b2[lane] : 0.f);
    float vmax = live ? val0 : -INFINITY;
#pragma unroll
    for (int msk = 1; msk < 64; msk <<= 1) vmax = fmaxf(vmax, __shfl_xor(vmax, msk, 64));
    float ex = live ? __expf(val0 - vmax) : 0.f;
#pragma unroll
    for (int msk = 1; msk < 64; msk <<= 1) ex += __shfl_xor(ex, msk, 64);
    float res = val0 - vmax - __logf(ex);
    if (live) out[(size_t)wid * NCLASS + lane] = res;
}

// ---------------- launch ----------------
extern "C" void kernel_launch(void* const* d_in, const int* in_sizes, int n_in,
                              void* d_out, int out_size, void* d_ws, size_t ws_size,
                              hipStream_t stream) {
    const float* x    = (const float*)d_in[0];
    const int*   ei   = (const int*)  d_in[1];
    const float* W1   = (const float*)d_in[2];
    const float* attS = (const float*)d_in[3];
    const float* attD = (const float*)d_in[4];
    const float* b1   = (const float*)d_in[5];
    const float* W2   = (const float*)d_in[6];
    const float* a2sw = (const float*)d_in[7];
    const float* a2dw = (const float*)d_in[8];
    const float* b2   = (const float*)d_in[9];

    int n = in_sizes[0] / NFEAT;
    int E = in_sizes[1] / 2;
    const int* srcE = ei;
    const int* dstE = ei + E;
    int nb = (n + 255) / 256;
    int mblocks = (n + 63) / 64;              // gemm1 blocks (64 nodes each)

    char* p = (char*)d_ws;
    auto alloc = [&](size_t bytes) {
        char* r = p;
        p += (bytes + 255) & ~(size_t)255;
        return r;
    };
    uchar*  h1f8 = (uchar*)alloc((size_t)n * HC);
    ushort* hgb  = (ushort*)alloc((size_t)n * HC * 2);
    ushort* h2b  = (ushort*)alloc((size_t)n * NCLASS * 2);
    ushort* Wb   = (ushort*)alloc((size_t)16 * 4 * 64 * 8 * 2);
    float* a1s = (float*)alloc((size_t)n * HEADS * 4);
    float* a1d = (float*)alloc((size_t)n * HEADS * 4);
    float* a2s = (float*)alloc((size_t)n * 4);
    float* a2d = (float*)alloc((size_t)n * 4);
    int* deg  = (int*)alloc((size_t)n * 4);
    int* bsum = (int*)alloc((size_t)nb * 4);
    int* ptr  = (int*)alloc((size_t)(n + 1) * 4);
    int* cur  = (int*)alloc((size_t)n * 4);
    int* srcs = (int*)alloc((size_t)(E + n) * 4);

    int tot = E + n;
    hipMemsetAsync(deg, 0, (size_t)n * 4, stream);
    k_hist<<<(E + 256 * HU - 1) / (256 * HU), 256, 0, stream>>>(dstE, E, deg);
    k_blocksum<<<nb, 256, 0, stream>>>(deg, n, bsum);
    k_mkptr<<<nb, 256, 0, stream>>>(deg, bsum, n, ptr, cur);
    k_scatter<<<(tot + 256 * SU - 1) / (256 * SU), 256, 0, stream>>>(srcE, dstE, E, n, cur, srcs);

    k_prepw<<<16, 256, 0, stream>>>(W1, Wb);
    k_gemm1<<<mblocks, 256, 0, stream>>>(x, Wb, attS, attD, n, h1f8, a1s, a1d);
    k_agg1<<<(n + 3) / 4, 256, 0, stream>>>((const uint*)h1f8, a1s, a1d, b1,
                                            ptr, srcs, n, hgb);
    k_gemm2<<<(n + 63) / 64, 256, 0, stream>>>(hgb, W2, a2sw, a2dw, n, h2b, a2s, a2d);
    k_agg2<<<(n + 3) / 4, 256, 0, stream>>>(h2b, a2s, a2d, b2, ptr, srcs, n, (float*)d_out);
}

// Round 11
// 327.862 us; speedup vs baseline: 2.0318x; 1.0194x over previous
//
#include <hip/hip_runtime.h>
#include <math.h>

#define NFEAT  128
#define HC     256     // HEADS*NHID
#define HEADS  8
#define NHID   32
#define NCLASS 40

typedef unsigned int  uint;
typedef unsigned short ushort;
typedef unsigned char uchar;

typedef __attribute__((ext_vector_type(8))) short bf16x8;
typedef __attribute__((ext_vector_type(4))) float f32x4;

union U8 { uint4 u; bf16x8 v; };

// bf16 helpers (RNE pack, cheap unpack)
__device__ __forceinline__ uint f2bf1(float f) {
    uint b = __float_as_uint(f);
    b += 0x7FFFu + ((b >> 16) & 1u);
    return b >> 16;
}
__device__ __forceinline__ uint packbf(float lo, float hi) {
    return f2bf1(lo) | (f2bf1(hi) << 16);
}
__device__ __forceinline__ float bflo(uint u) { return __uint_as_float(u << 16); }
__device__ __forceinline__ float bfhi(uint u) { return __uint_as_float(u & 0xFFFF0000u); }

// fp8 e4m3 (OCP) via HW converts
__device__ __forceinline__ uchar f2fp8(float v) {
    return (uchar)(__builtin_amdgcn_cvt_pk_fp8_f32(v, v, 0, false) & 0xFF);
}

// ---------------- CSR build (dst-sorted, shared by both layers) ----------------

#define HU 4
__global__ void k_hist(const int* __restrict__ dst, int E, int* deg) {
    int tid = blockIdx.x * 256 + threadIdx.x;
    int stride = gridDim.x * 256;
#pragma unroll
    for (int j = 0; j < HU; ++j) {
        int i = tid + j * stride;
        if (i < E) atomicAdd(&deg[dst[i]], 1);
    }
}

// per-block sums of (deg+1)  [+1 = self-loop]
__global__ void k_blocksum(const int* __restrict__ deg, int n, int* bsum) {
    __shared__ int lds[256];
    int b = blockIdx.x, t = threadIdx.x;
    int i = b * 256 + t;
    lds[t] = (i < n) ? deg[i] + 1 : 0;
    __syncthreads();
    for (int off = 128; off >= 1; off >>= 1) {
        if (t < off) lds[t] += lds[t + off];
        __syncthreads();
    }
    if (t == 0) bsum[b] = lds[0];
}

// fused: per-block parallel reduce of bsum[0..b) + local scan -> ptr/cur
__global__ void k_mkptr(const int* __restrict__ deg, const int* __restrict__ bsum,
                        int n, int* ptr, int* cur) {
    __shared__ int lds[256];
    __shared__ int base_s;
    int b = blockIdx.x, t = threadIdx.x;
    int p = 0;
    for (int i = t; i < b; i += 256) p += bsum[i];
    lds[t] = p;
    __syncthreads();
    for (int off = 128; off >= 1; off >>= 1) {
        if (t < off) lds[t] += lds[t + off];
        __syncthreads();
    }
    if (t == 0) base_s = lds[0];
    __syncthreads();
    int i = b * 256 + t;
    int v = (i < n) ? deg[i] + 1 : 0;   // +1 self-loop
    lds[t] = v;
    __syncthreads();
    for (int off = 1; off < 256; off <<= 1) {
        int u = (t >= off) ? lds[t - off] : 0;
        __syncthreads();
        lds[t] += u;
        __syncthreads();
    }
    int excl = lds[t] - v + base_s;
    if (i < n) {
        ptr[i] = excl;
        cur[i] = excl;
        if (i == n - 1) ptr[n] = excl + v;
    }
}

// scatter, 8 independent atomic chains per thread (latency hiding)
#define SU 8
__global__ void k_scatter(const int* __restrict__ srcE, const int* __restrict__ dstE,
                          int E, int n, int* cur, int* __restrict__ srcs) {
    int tid = blockIdx.x * 256 + threadIdx.x;
    int stride = gridDim.x * 256;
    int tot = E + n;
    int s[SU], d[SU], pos[SU];
    bool v[SU];
#pragma unroll
    for (int j = 0; j < SU; ++j) {
        int i = tid + j * stride;
        v[j] = i < tot;
        s[j] = 0; d[j] = 0;
        if (v[j]) {
            if (i < E) { s[j] = srcE[i]; d[j] = dstE[i]; }
            else       { s[j] = d[j] = i - E; }          // self-loop
        }
    }
#pragma unroll
    for (int j = 0; j < SU; ++j)
        if (v[j]) pos[j] = atomicAdd(&cur[d[j]], 1);
#pragma unroll
    for (int j = 0; j < SU; ++j)
        if (v[j]) srcs[pos[j]] = s[j];
}

// ---------------- MFMA prep: W1 -> B frags (bf16), tiles 0..15 = W1 cols,
// tile 16 = attention tile: col c<8 -> Was[k,h=c] = sum_c' W1[k,h*32+c']*attS[h,c'],
//                            col c>=8 -> Wad[k,h=c-8] (same with attD).
// B frag: lane holds B[k=(lane>>4)*8+j][ncol=lane&15], index=((ntile*4+kstep)*64+lane)*8
__global__ __launch_bounds__(256)
void k_prepw(const float* __restrict__ W1,
             const float* __restrict__ attS, const float* __restrict__ attD,
             ushort* __restrict__ Wb) {
    int g = blockIdx.x * 256 + threadIdx.x;        // 17*256 threads
    int lane = g & 63;
    int step = (g >> 6) & 3;
    int tile = g >> 8;
    int k0 = step * 32 + (lane >> 4) * 8;
    float f[8];
    if (tile < 16) {
        int ncol = tile * 16 + (lane & 15);
#pragma unroll
        for (int j = 0; j < 8; ++j) f[j] = W1[(size_t)(k0 + j) * HC + ncol];
    } else {
        int cc = lane & 15;
        int h = cc & 7;
        const float* av = (cc < 8) ? attS : attD;
#pragma unroll
        for (int j = 0; j < 8; ++j) {
            const float* wr = W1 + (size_t)(k0 + j) * HC + h * 32;
            float s = 0.f;
#pragma unroll
            for (int c = 0; c < 32; ++c) s += wr[c] * av[h * 32 + c];
            f[j] = s;
        }
    }
    uint4 o;
    o.x = packbf(f[0], f[1]);
    o.y = packbf(f[2], f[3]);
    o.z = packbf(f[4], f[5]);
    o.w = packbf(f[6], f[7]);
    *(uint4*)(Wb + (size_t)g * 8) = o;
}

// ---------------- GEMM1 (MFMA bf16): h1 = x @ W1, fp8 h1 out ----------------
// x staged in LDS as PACKED bf16 (64 rows x 136 ushorts = 272B rows, 17.4 KB);
// A frags = single ds_read_b128. 17 n-tiles: 16 for h1 cols + 1 attention tile
// (a1_src/a1_dst folded into the GEMM via Was/Wad -- NO shuffle reductions).
// fp8 C-repack ALIASES Xs.
__global__ __launch_bounds__(256)
void k_gemm1(const float* __restrict__ x,
             const ushort* __restrict__ Wb,
             int n, uchar* __restrict__ h1f8,
             float* __restrict__ a1x) {
    __shared__ uint Xs[64 * 68];        // 17.4 KB; aliased as Cs[64][272]B later
    int t = threadIdx.x;
    int lane = t & 63;
    int w = t >> 6;
    int n0 = blockIdx.x * 64;

    // stage x -> packed bf16: 64 nodes x 32 float4, 8/thread, coalesced
#pragma unroll
    for (int j = 0; j < 8; ++j) {
        int f4 = t + j * 256;
        int node = f4 >> 5;
        int k4 = (f4 & 31) * 4;            // float index within row
        int gn = n0 + node;
        float4 v = make_float4(0.f, 0.f, 0.f, 0.f);
        if (gn < n) v = *(const float4*)(x + (size_t)gn * NFEAT + k4);
        uint2 pk;
        pk.x = packbf(v.x, v.y);
        pk.y = packbf(v.z, v.w);
        *(uint2*)(Xs + node * 68 + (k4 >> 1)) = pk;
    }
    __syncthreads();

    // A frags: lane holds A[m=lane&15][k=(lane>>4)*8+j] -> one b128 per kstep
    int m = lane & 15;
    int q4 = (lane >> 4) * 4;              // uint offset of 8-bf16 group
    bf16x8 Af[4];
#pragma unroll
    for (int ks = 0; ks < 4; ++ks) {
        U8 a;
        a.u = *(const uint4*)(Xs + (w * 16 + m) * 68 + ks * 16 + q4);
        Af[ks] = a.v;
    }
    __syncthreads();                       // done reading Xs before Cs alias

    f32x4 acc[17];
#pragma unroll
    for (int i = 0; i < 17; ++i) acc[i] = (f32x4){0.f, 0.f, 0.f, 0.f};

    const bf16x8* Bf = (const bf16x8*)Wb;
#pragma unroll
    for (int ks = 0; ks < 4; ++ks) {
#pragma unroll
        for (int nt = 0; nt < 17; ++nt) {
            bf16x8 bv = Bf[(size_t)(nt * 4 + ks) * 64 + lane];
            acc[nt] = __builtin_amdgcn_mfma_f32_16x16x32_bf16(Af[ks], bv, acc[nt], 0, 0, 0);
        }
    }

    // C layout: col = nt*16 + (lane&15), row = (lane>>4)*4 + reg  [m89-verified]
    int cc = lane & 15;
    int r0 = (lane >> 4) * 4;

    // attention tile (nt=16): col cc -> a1x[gn*16+cc] (0..7 src heads, 8..15 dst)
#pragma unroll
    for (int r = 0; r < 4; ++r) {
        int gn = n0 + w * 16 + r0 + r;
        if (gn < n) a1x[(size_t)gn * 16 + cc] = acc[16][r];
    }

    // fp8 repack into Cs (aliased on Xs): row stride 272 B (same as Xs rows)
    uchar* CsB = (uchar*)Xs;
#pragma unroll
    for (int nt = 0; nt < 16; ++nt) {
#pragma unroll
        for (int r = 0; r < 4; ++r)
            CsB[(w * 16 + r0 + r) * 272 + nt * 16 + cc] = f2fp8(acc[nt][r]);
    }
    __syncthreads();

    // coalesced readback: thread t -> node = t>>2, 64-byte chunk q = t&3
    int node_local = t >> 2;
    int q = t & 3;
    int gn = n0 + node_local;
    if (gn < n) {
        const uchar* crow = CsB + node_local * 272 + q * 64;
        uchar* hp = h1f8 + (size_t)gn * HC + q * 64;
#pragma unroll
        for (int i = 0; i < 4; ++i)
            *(uint4*)(hp + i * 16) = *(const uint4*)(crow + i * 16);
    }
}

// ---------------- Layer-1 aggregation: one wave per dst node, online softmax ----------------
// fp8 h1 gather (256B/edge), 8-wide unroll + masked tail, scalarized edge indices.
// a1x[n][16]: cols 0..7 = a_src per head, 8..15 = a_dst per head.
__global__ __launch_bounds__(256)
void k_agg1(const uint* __restrict__ h1u, const float* __restrict__ a1x,
            const float* __restrict__ b1,
            const int* __restrict__ ptr, const int* __restrict__ srcs,
            int n, ushort* __restrict__ hgb) {
    int wid = blockIdx.x * 4 + (threadIdx.x >> 6);
    if (wid >= n) return;
    int lane = threadIdx.x & 63;
    int h = lane >> 3;
    float adn = a1x[(size_t)wid * 16 + 8 + h];
    int beg = __builtin_amdgcn_readfirstlane(ptr[wid]);
    int end = __builtin_amdgcn_readfirstlane(ptr[wid + 1]);
    float m = -INFINITY, s = 0.f;
    float4 acc = make_float4(0.f, 0.f, 0.f, 0.f);

    int i = beg;
    for (; i + 8 <= end; i += 8) {
        int sn[8];
#pragma unroll
        for (int j = 0; j < 8; ++j) sn[j] = __builtin_amdgcn_readfirstlane(srcs[i + j]);
        float av[8];
        uint hv[8];
#pragma unroll
        for (int j = 0; j < 8; ++j) av[j] = a1x[(size_t)sn[j] * 16 + h];
#pragma unroll
        for (int j = 0; j < 8; ++j)
            hv[j] = h1u[(size_t)sn[j] * 64 + lane];
        float e[8];
#pragma unroll
        for (int j = 0; j < 8; ++j) {
            float a = av[j] + adn;
            e[j] = (a > 0.f) ? a : 0.2f * a;
        }
        float mn = m;
#pragma unroll
        for (int j = 0; j < 8; ++j) mn = fmaxf(mn, e[j]);
        float corr = __expf(m - mn);
        float p[8];
#pragma unroll
        for (int j = 0; j < 8; ++j) p[j] = __expf(e[j] - mn);
        float ps = 0.f;
#pragma unroll
        for (int j = 0; j < 8; ++j) ps += p[j];
        s = s * corr + ps;
        float cx = acc.x * corr, cy = acc.y * corr, cz = acc.z * corr, cw = acc.w * corr;
#pragma unroll
        for (int j = 0; j < 8; ++j) {
            auto lo = __builtin_amdgcn_cvt_pk_f32_fp8((int)hv[j], false);
            auto hi = __builtin_amdgcn_cvt_pk_f32_fp8((int)hv[j], true);
            cx += p[j] * lo[0];
            cy += p[j] * lo[1];
            cz += p[j] * hi[0];
            cw += p[j] * hi[1];
        }
        acc = make_float4(cx, cy, cz, cw);
        m = mn;
    }
    if (i < end) {                       // masked final iteration
        int sn[8];
        bool val[8];
#pragma unroll
        for (int j = 0; j < 8; ++j) {
            int idx = i + j;
            val[j] = idx < end;
            sn[j] = __builtin_amdgcn_readfirstlane(srcs[val[j] ? idx : end - 1]);
        }
        float av[8];
        uint hv[8];
#pragma unroll
        for (int j = 0; j < 8; ++j) av[j] = a1x[(size_t)sn[j] * 16 + h];
#pragma unroll
        for (int j = 0; j < 8; ++j)
            hv[j] = h1u[(size_t)sn[j] * 64 + lane];
        float e[8];
#pragma unroll
        for (int j = 0; j < 8; ++j) {
            float a = av[j] + adn;
            e[j] = val[j] ? ((a > 0.f) ? a : 0.2f * a) : -INFINITY;
        }
        float mn = m;
#pragma unroll
        for (int j = 0; j < 8; ++j) mn = fmaxf(mn, e[j]);
        float corr = __expf(m - mn);
        float p[8];
#pragma unroll
        for (int j = 0; j < 8; ++j) p[j] = __expf(e[j] - mn);
        float ps = 0.f;
#pragma unroll
        for (int j = 0; j < 8; ++j) ps += p[j];
        s = s * corr + ps;
        float cx = acc.x * corr, cy = acc.y * corr, cz = acc.z * corr, cw = acc.w * corr;
#pragma unroll
        for (int j = 0; j < 8; ++j) {
            auto lo = __builtin_amdgcn_cvt_pk_f32_fp8((int)hv[j], false);
            auto hi = __builtin_amdgcn_cvt_pk_f32_fp8((int)hv[j], true);
            cx += p[j] * lo[0];
            cy += p[j] * lo[1];
            cz += p[j] * hi[0];
            cw += p[j] * hi[1];
        }
        acc = make_float4(cx, cy, cz, cw);
        m = mn;
    }

    float inv = 1.f / (s + 1e-16f);
    float4 bv = *(const float4*)(b1 + lane * 4);
    float4 o;
    o.x = acc.x * inv + bv.x;
    o.y = acc.y * inv + bv.y;
    o.z = acc.z * inv + bv.z;
    o.w = acc.w * inv + bv.w;
    o.x = (o.x > 0.f) ? o.x : (__expf(o.x) - 1.f);
    o.y = (o.y > 0.f) ? o.y : (__expf(o.y) - 1.f);
    o.z = (o.z > 0.f) ? o.z : (__expf(o.z) - 1.f);
    o.w = (o.w > 0.f) ? o.w : (__expf(o.w) - 1.f);
    uint2 ov;
    ov.x = packbf(o.x, o.y);
    ov.y = packbf(o.z, o.w);
    *(uint2*)(hgb + (size_t)wid * HC + lane * 4) = ov;
}

// ---------------- GEMM2: h2 = hg @ W2  [N,256]x[256,40], bf16 in/out ----------------
__global__ __launch_bounds__(256)
void k_gemm2(const ushort* __restrict__ hgb, const float* __restrict__ W2,
             const float* __restrict__ a2sw, const float* __restrict__ a2dw,
             int n, ushort* __restrict__ h2b,
             float* __restrict__ a2s, float* __restrict__ a2d) {
    __shared__ uint Xs[128 * 65];       // 33.3 KB, [k2][node]
    __shared__ float Ps[4][64];
    __shared__ float Pd[4][64];
    int t = threadIdx.x;
    int lane = t & 63;
    int w = t >> 6;
    int n0 = blockIdx.x * 64;

#pragma unroll
    for (int j = 0; j < 8; ++j) {
        int g = t + j * 256;
        int node = g >> 5;
        int k2b = (g & 31) * 4;
        int gn = n0 + node;
        uint4 v = make_uint4(0u, 0u, 0u, 0u);
        if (gn < n) v = *(const uint4*)(hgb + (size_t)gn * HC + k2b * 2);
        Xs[(k2b + 0) * 65 + node] = v.x;
        Xs[(k2b + 1) * 65 + node] = v.y;
        Xs[(k2b + 2) * 65 + node] = v.z;
        Xs[(k2b + 3) * 65 + node] = v.w;
    }
    __syncthreads();

    int wu = __builtin_amdgcn_readfirstlane(w);
    const float* Wc = W2 + wu * 10;

    float acc[10];
#pragma unroll
    for (int c = 0; c < 10; ++c) acc[c] = 0.f;

#pragma unroll 2
    for (int k2 = 0; k2 < 128; ++k2) {
        uint xp = Xs[k2 * 65 + lane];
        float x0 = bflo(xp), x1 = bfhi(xp);
        const float* Wr0 = Wc + (size_t)(2 * k2) * NCLASS;
        const float* Wr1 = Wr0 + NCLASS;
#pragma unroll
        for (int c = 0; c < 10; ++c) {
            acc[c] += x0 * Wr0[c] + x1 * Wr1[c];
        }
    }

    int gn = n0 + lane;
    float as = 0.f, ad = 0.f;
#pragma unroll
    for (int c = 0; c < 10; ++c) {
        as += acc[c] * a2sw[wu * 10 + c];
        ad += acc[c] * a2dw[wu * 10 + c];
    }
    Ps[w][lane] = as;
    Pd[w][lane] = ad;
    if (gn < n) {
        uint* hp = (uint*)(h2b + (size_t)gn * NCLASS + wu * 10);
#pragma unroll
        for (int q = 0; q < 5; ++q)
            hp[q] = packbf(acc[q * 2], acc[q * 2 + 1]);
    }
    __syncthreads();
    if (w == 0 && gn < n) {
        a2s[gn] = Ps[0][lane] + Ps[1][lane] + Ps[2][lane] + Ps[3][lane];
        a2d[gn] = Pd[0][lane] + Pd[1][lane] + Pd[2][lane] + Pd[3][lane];
    }
}

// ---------------- Layer-2 aggregation + bias + log_softmax ----------------
__global__ __launch_bounds__(256)
void k_agg2(const ushort* __restrict__ h2b, const float* __restrict__ a2s,
            const float* __restrict__ a2d, const float* __restrict__ b2,
            const int* __restrict__ ptr, const int* __restrict__ srcs,
            int n, float* __restrict__ out) {
    int wid = blockIdx.x * 4 + (threadIdx.x >> 6);
    if (wid >= n) return;
    int lane = threadIdx.x & 63;
    bool live = lane < NCLASS;
    int col = live ? lane : 0;
    float adn = a2d[wid];
    int beg = __builtin_amdgcn_readfirstlane(ptr[wid]);
    int end = __builtin_amdgcn_readfirstlane(ptr[wid + 1]);
    float m = -INFINITY, s = 0.f, acc = 0.f;

    int i = beg;
    for (; i + 8 <= end; i += 8) {
        int sn[8];
#pragma unroll
        for (int j = 0; j < 8; ++j) sn[j] = __builtin_amdgcn_readfirstlane(srcs[i + j]);
        float av[8];
        float hv[8];
#pragma unroll
        for (int j = 0; j < 8; ++j) av[j] = a2s[sn[j]];
#pragma unroll
        for (int j = 0; j < 8; ++j)
            hv[j] = __uint_as_float((uint)h2b[(size_t)sn[j] * NCLASS + col] << 16);
        float e[8];
#pragma unroll
        for (int j = 0; j < 8; ++j) {
            float a = av[j] + adn;
            e[j] = (a > 0.f) ? a : 0.2f * a;
        }
        float mn = m;
#pragma unroll
        for (int j = 0; j < 8; ++j) mn = fmaxf(mn, e[j]);
        float corr = __expf(m - mn);
        float p[8];
#pragma unroll
        for (int j = 0; j < 8; ++j) p[j] = __expf(e[j] - mn);
        float ps = 0.f, pa = 0.f;
#pragma unroll
        for (int j = 0; j < 8; ++j) { ps += p[j]; pa += p[j] * hv[j]; }
        s = s * corr + ps;
        acc = acc * corr + pa;
        m = mn;
    }
    if (i < end) {
        int sn[8];
        bool val[8];
#pragma unroll
        for (int j = 0; j < 8; ++j) {
            int idx = i + j;
            val[j] = idx < end;
            sn[j] = __builtin_amdgcn_readfirstlane(srcs[val[j] ? idx : end - 1]);
        }
        float av[8];
        float hv[8];
#pragma unroll
        for (int j = 0; j < 8; ++j) av[j] = a2s[sn[j]];
#pragma unroll
        for (int j = 0; j < 8; ++j)
            hv[j] = __uint_as_float((uint)h2b[(size_t)sn[j] * NCLASS + col] << 16);
        float e[8];
#pragma unroll
        for (int j = 0; j < 8; ++j) {
            float a = av[j] + adn;
            e[j] = val[j] ? ((a > 0.f) ? a : 0.2f * a) : -INFINITY;
        }
        float mn = m;
#pragma unroll
        for (int j = 0; j < 8; ++j) mn = fmaxf(mn, e[j]);
        float corr = __expf(m - mn);
        float p[8];
#pragma unroll
        for (int j = 0; j < 8; ++j) p[j] = __expf(e[j] - mn);
        float ps = 0.f, pa = 0.f;
#pragma unroll
        for (int j = 0; j < 8; ++j) { ps += p[j]; pa += p[j] * hv[j]; }
        s = s * corr + ps;
        acc = acc * corr + pa;
        m = mn;
    }

    float val0 = acc / (s + 1e-16f) + (live ? b2[lane] : 0.f);
    float vmax = live ? val0 : -INFINITY;
#pragma unroll
    for (int msk = 1; msk < 64; msk <<= 1) vmax = fmaxf(vmax, __shfl_xor(vmax, msk, 64));
    float ex = live ? __expf(val0 - vmax) : 0.f;
#pragma unroll
    for (int msk = 1; msk < 64; msk <<= 1) ex += __shfl_xor(ex, msk, 64);
    float res = val0 - vmax - __logf(ex);
    if (live) out[(size_t)wid * NCLASS + lane] = res;
}

// ---------------- launch ----------------
extern "C" void kernel_launch(void* const* d_in, const int* in_sizes, int n_in,
                              void* d_out, int out_size, void* d_ws, size_t ws_size,
                              hipStream_t stream) {
    const float* x    = (const float*)d_in[0];
    const int*   ei   = (const int*)  d_in[1];
    const float* W1   = (const float*)d_in[2];
    const float* attS = (const float*)d_in[3];
    const float* attD = (const float*)d_in[4];
    const float* b1   = (const float*)d_in[5];
    const float* W2   = (const float*)d_in[6];
    const float* a2sw = (const float*)d_in[7];
    const float* a2dw = (const float*)d_in[8];
    const float* b2   = (const float*)d_in[9];

    int n = in_sizes[0] / NFEAT;
    int E = in_sizes[1] / 2;
    const int* srcE = ei;
    const int* dstE = ei + E;
    int nb = (n + 255) / 256;
    int mblocks = (n + 63) / 64;              // gemm1 blocks (64 nodes each)

    char* p = (char*)d_ws;
    auto alloc = [&](size_t bytes) {
        char* r = p;
        p += (bytes + 255) & ~(size_t)255;
        return r;
    };
    uchar*  h1f8 = (uchar*)alloc((size_t)n * HC);
    ushort* hgb  = (ushort*)alloc((size_t)n * HC * 2);
    ushort* h2b  = (ushort*)alloc((size_t)n * NCLASS * 2);
    ushort* Wb   = (ushort*)alloc((size_t)17 * 4 * 64 * 8 * 2);
    float* a1x = (float*)alloc((size_t)n * 16 * 4);
    float* a2s = (float*)alloc((size_t)n * 4);
    float* a2d = (float*)alloc((size_t)n * 4);
    int* deg  = (int*)alloc((size_t)n * 4);
    int* bsum = (int*)alloc((size_t)nb * 4);
    int* ptr  = (int*)alloc((size_t)(n + 1) * 4);
    int* cur  = (int*)alloc((size_t)n * 4);
    int* srcs = (int*)alloc((size_t)(E + n) * 4);

    int tot = E + n;
    hipMemsetAsync(deg, 0, (size_t)n * 4, stream);
    k_hist<<<(E + 256 * HU - 1) / (256 * HU), 256, 0, stream>>>(dstE, E, deg);
    k_blocksum<<<nb, 256, 0, stream>>>(deg, n, bsum);
    k_mkptr<<<nb, 256, 0, stream>>>(deg, bsum, n, ptr, cur);
    k_scatter<<<(tot + 256 * SU - 1) / (256 * SU), 256, 0, stream>>>(srcE, dstE, E, n, cur, srcs);

    k_prepw<<<17, 256, 0, stream>>>(W1, attS, attD, Wb);
    k_gemm1<<<mblocks, 256, 0, stream>>>(x, Wb, n, h1f8, a1x);
    k_agg1<<<(n + 3) / 4, 256, 0, stream>>>((const uint*)h1f8, a1x, b1,
                                            ptr, srcs, n, hgb);
    k_gemm2<<<(n + 63) / 64, 256, 0, stream>>>(hgb, W2, a2sw, a2dw, n, h2b, a2s, a2d);
    k_agg2<<<(n + 3) / 4, 256, 0, stream>>>(h2b, a2s, a2d, b2, ptr, srcs, n, (float*)d_out);
}